// Round 1
// baseline (1013.522 us; speedup 1.0000x reference)
//
#include <hip/hip_runtime.h>

struct Seg { const float* A; const float* W; int K; };

// ---------------- CSR build ----------------

__global__ void hist_kernel(const int* __restrict__ dst, int E, int* __restrict__ cnt) {
  int i = blockIdx.x * 256 + threadIdx.x;
  if (i < E) atomicAdd(&cnt[dst[i]], 1);
}

// single-block exclusive scan (n <= ~64k), 1024 threads
__global__ void exscan_kernel(const int* __restrict__ cnt, int* __restrict__ starts, int n) {
  __shared__ int wsum[16];
  __shared__ int wpre[16];
  __shared__ int tot_s;
  __shared__ int carry_s;
  int tid = threadIdx.x, lane = tid & 63, wv = tid >> 6;
  if (tid == 0) carry_s = 0;
  for (int base = 0; base < n; base += 1024) {
    __syncthreads();
    int carry = carry_s;
    int i = base + tid;
    int v = (i < n) ? cnt[i] : 0;
    int inc = v;
#pragma unroll
    for (int off = 1; off < 64; off <<= 1) {
      int t = __shfl_up(inc, off, 64);
      if (lane >= off) inc += t;
    }
    if (lane == 63) wsum[wv] = inc;
    __syncthreads();
    if (tid < 16) {
      int x = wsum[tid];
      int p = x;
#pragma unroll
      for (int off = 1; off < 16; off <<= 1) {
        int t = __shfl_up(p, off, 64);
        if (tid >= off) p += t;
      }
      wpre[tid] = p - x;
      if (tid == 15) tot_s = p;
    }
    __syncthreads();
    if (i < n) starts[i] = carry + wpre[wv] + (inc - v);
    if (tid == 0) carry_s = carry + tot_s;
  }
  __syncthreads();
  if (tid == 0) starts[n] = carry_s;
}

__global__ void scatter_kernel(const int* __restrict__ src, const int* __restrict__ dst, int E,
                               const int* __restrict__ starts, int* __restrict__ cur,
                               int* __restrict__ eidx) {
  int i = blockIdx.x * 256 + threadIdx.x;
  if (i >= E) return;
  int d = dst[i];
  int p = starts[d] + atomicAdd(&cur[d], 1);
  eidx[p] = src[i];
}

// ---------------- aggregation: one wave per dst node ----------------

template <int D>
__global__ void aggregate_kernel(const float* __restrict__ xsrc, const int* __restrict__ eidx,
                                 const int* __restrict__ starts, int n_dst,
                                 float* __restrict__ agg) {
  int w = blockIdx.x * 4 + (threadIdx.x >> 6);
  int lane = threadIdx.x & 63;
  if (w >= n_dst) return;
  int s0 = starts[w], s1 = starts[w + 1];
  int c = s1 - s0;
  float inv = 1.0f / (float)(c > 0 ? c : 1);
  if constexpr (D == 128) {
    const float2* x2 = (const float2*)xsrc;
    float ax = 0.f, ay = 0.f;
    for (int e = s0; e < s1; ++e) {
      int s = eidx[e];
      float2 v = x2[(size_t)s * 64 + lane];
      ax += v.x; ay += v.y;
    }
    float2 r; r.x = ax * inv; r.y = ay * inv;
    ((float2*)agg)[(size_t)w * 64 + lane] = r;
  } else {  // D == 64
    float a = 0.f;
    for (int e = s0; e < s1; ++e) {
      int s = eidx[e];
      a += xsrc[(size_t)s * 64 + lane];
    }
    agg[(size_t)w * 64 + lane] = a * inv;
  }
}

// ---------------- fused dense: out = act(sum_seg A_i @ W_i + b0 (+b1)) ----------------

__device__ __forceinline__ void gemm_seg(const float* __restrict__ A, const float* __restrict__ W,
                                         int K, int ldo, int N, int m0, int n0,
                                         int tid, int tx, int ty,
                                         float (*At)[36], float (*Bt)[64], float acc[4][4]) {
  for (int k0 = 0; k0 < K; k0 += 32) {
#pragma unroll
    for (int i = 0; i < 2; ++i) {
      int fid = tid * 2 + i;
      int row = fid >> 3, q = fid & 7;
      int gr = m0 + row;
      if (gr > N - 1) gr = N - 1;
      float4 v = *(const float4*)(A + (size_t)gr * K + k0 + q * 4);
      *(float4*)&At[row][q * 4] = v;
    }
#pragma unroll
    for (int i = 0; i < 2; ++i) {
      int fid = tid * 2 + i;
      int kr = fid >> 4, q = fid & 15;
      float4 v = *(const float4*)(W + (size_t)(k0 + kr) * ldo + n0 + q * 4);
      *(float4*)&Bt[kr][q * 4] = v;
    }
    __syncthreads();
#pragma unroll
    for (int kk = 0; kk < 32; ++kk) {
      float4 b4 = *(const float4*)&Bt[kk][tx * 4];
      float a0 = At[ty * 4 + 0][kk];
      float a1 = At[ty * 4 + 1][kk];
      float a2 = At[ty * 4 + 2][kk];
      float a3 = At[ty * 4 + 3][kk];
      acc[0][0] += a0 * b4.x; acc[0][1] += a0 * b4.y; acc[0][2] += a0 * b4.z; acc[0][3] += a0 * b4.w;
      acc[1][0] += a1 * b4.x; acc[1][1] += a1 * b4.y; acc[1][2] += a1 * b4.z; acc[1][3] += a1 * b4.w;
      acc[2][0] += a2 * b4.x; acc[2][1] += a2 * b4.y; acc[2][2] += a2 * b4.z; acc[2][3] += a2 * b4.w;
      acc[3][0] += a3 * b4.x; acc[3][1] += a3 * b4.y; acc[3][2] += a3 * b4.z; acc[3][3] += a3 * b4.w;
    }
    __syncthreads();
  }
}

__global__ __launch_bounds__(256) void dense_kernel(
    Seg s0, Seg s1, Seg s2, Seg s3, int nseg,
    const float* __restrict__ bias0, const float* __restrict__ bias1,
    float* __restrict__ out, int N, int ldo, int relu) {
  __shared__ float At[64][36];
  __shared__ float Bt[32][64];
  int tid = threadIdx.x;
  int tx = tid & 15, ty = tid >> 4;
  int m0 = blockIdx.x * 64;
  int n0 = blockIdx.y * 64;
  float acc[4][4] = {};
  gemm_seg(s0.A, s0.W, s0.K, ldo, N, m0, n0, tid, tx, ty, At, Bt, acc);
  if (nseg > 1) gemm_seg(s1.A, s1.W, s1.K, ldo, N, m0, n0, tid, tx, ty, At, Bt, acc);
  if (nseg > 2) gemm_seg(s2.A, s2.W, s2.K, ldo, N, m0, n0, tid, tx, ty, At, Bt, acc);
  if (nseg > 3) gemm_seg(s3.A, s3.W, s3.K, ldo, N, m0, n0, tid, tx, ty, At, Bt, acc);

  float bb[4];
#pragma unroll
  for (int j = 0; j < 4; ++j) {
    int cidx = n0 + tx * 4 + j;
    float b = bias0 ? bias0[cidx] : 0.f;
    if (bias1) b += bias1[cidx];
    bb[j] = b;
  }
#pragma unroll
  for (int i = 0; i < 4; ++i) {
    int gr = m0 + ty * 4 + i;
    if (gr < N) {
      float4 r;
      r.x = acc[i][0] + bb[0];
      r.y = acc[i][1] + bb[1];
      r.z = acc[i][2] + bb[2];
      r.w = acc[i][3] + bb[3];
      if (relu) {
        r.x = fmaxf(r.x, 0.f); r.y = fmaxf(r.y, 0.f);
        r.z = fmaxf(r.z, 0.f); r.w = fmaxf(r.w, 0.f);
      }
      *(float4*)(out + (size_t)gr * ldo + n0 + tx * 4) = r;
    }
  }
}

// ---------------- launch ----------------

extern "C" void kernel_launch(void* const* d_in, const int* in_sizes, int n_in,
                              void* d_out, int out_size, void* d_ws, size_t ws_size,
                              hipStream_t stream) {
  const float* x_user  = (const float*)d_in[0];
  const float* x_job   = (const float*)d_in[1];
  const float* x_skill = (const float*)d_in[2];

  const float* l1_uj_Wl = (const float*)d_in[3];
  const float* l1_uj_bl = (const float*)d_in[4];
  const float* l1_uj_Wr = (const float*)d_in[5];
  const float* l2_uj_Wl = (const float*)d_in[6];
  const float* l2_uj_bl = (const float*)d_in[7];
  const float* l2_uj_Wr = (const float*)d_in[8];

  const float* l1_ju_Wl = (const float*)d_in[9];
  const float* l1_ju_bl = (const float*)d_in[10];
  const float* l1_ju_Wr = (const float*)d_in[11];
  const float* l2_ju_Wl = (const float*)d_in[12];
  const float* l2_ju_bl = (const float*)d_in[13];
  const float* l2_ju_Wr = (const float*)d_in[14];

  const float* l1_js_Wl = (const float*)d_in[15];
  const float* l1_js_bl = (const float*)d_in[16];
  const float* l1_js_Wr = (const float*)d_in[17];
  const float* l2_js_Wl = (const float*)d_in[18];
  const float* l2_js_bl = (const float*)d_in[19];
  const float* l2_js_Wr = (const float*)d_in[20];

  const float* l1_sj_Wl = (const float*)d_in[21];
  const float* l1_sj_bl = (const float*)d_in[22];
  const float* l1_sj_Wr = (const float*)d_in[23];
  const float* l2_sj_Wl = (const float*)d_in[24];
  const float* l2_sj_bl = (const float*)d_in[25];
  const float* l2_sj_Wr = (const float*)d_in[26];

  const int* e1_src = (const int*)d_in[27];
  const int* e1_dst = (const int*)d_in[28];
  const int* e2_src = (const int*)d_in[29];
  const int* e2_dst = (const int*)d_in[30];
  const int* e3_src = (const int*)d_in[31];
  const int* e3_dst = (const int*)d_in[32];
  const int* e4_src = (const int*)d_in[33];
  const int* e4_dst = (const int*)d_in[34];

  const int N_U = in_sizes[0] / 128;
  const int N_J = in_sizes[1] / 128;
  const int N_S = in_sizes[2] / 64;
  const int E1 = in_sizes[27], E2 = in_sizes[29], E3 = in_sizes[31], E4 = in_sizes[33];

  char* wsp = (char*)d_ws;
  size_t off = 0;
  auto alloc = [&](size_t bytes) -> void* {
    void* p = wsp + off;
    off += (bytes + 255) & ~(size_t)255;
    return p;
  };

  int* starts1 = (int*)alloc((size_t)(N_J + 1) * 4);
  int* starts2 = (int*)alloc((size_t)(N_U + 1) * 4);
  int* starts3 = (int*)alloc((size_t)(N_S + 1) * 4);
  int* starts4 = (int*)alloc((size_t)(N_J + 1) * 4);
  int* idx1 = (int*)alloc((size_t)E1 * 4);
  int* idx2 = (int*)alloc((size_t)E2 * 4);
  int* idx3 = (int*)alloc((size_t)E3 * 4);
  int* idx4 = (int*)alloc((size_t)E4 * 4);
  int* cur  = (int*)alloc((size_t)N_U * 4);

  float* h_u  = (float*)alloc((size_t)N_U * 128 * 4);
  float* h_j  = (float*)alloc((size_t)N_J * 128 * 4);
  float* h_s  = (float*)alloc((size_t)N_S * 128 * 4);
  float* aggA = (float*)alloc((size_t)N_U * 128 * 4);  // ju aggregations (dst=user)
  float* aggB = (float*)alloc((size_t)N_J * 128 * 4);  // uj aggregations (dst=job)
  float* aggC = (float*)alloc((size_t)N_J * 128 * 4);  // sj aggregations (dst=job)
  float* aggD = (float*)alloc((size_t)N_S * 128 * 4);  // js aggregations (dst=skill)

  float* o_u = (float*)d_out;
  float* o_j = o_u + (size_t)N_U * 64;
  float* o_s = o_j + (size_t)N_J * 64;

  auto build_csr = [&](const int* esrc, const int* edst, int E, int Nd, int* starts, int* eidx) {
    hipMemsetAsync(cur, 0, (size_t)Nd * 4, stream);
    hist_kernel<<<(E + 255) / 256, 256, 0, stream>>>(edst, E, cur);
    exscan_kernel<<<1, 1024, 0, stream>>>(cur, starts, Nd);
    hipMemsetAsync(cur, 0, (size_t)Nd * 4, stream);
    scatter_kernel<<<(E + 255) / 256, 256, 0, stream>>>(esrc, edst, E, starts, cur, eidx);
  };
  build_csr(e1_src, e1_dst, E1, N_J, starts1, idx1);
  build_csr(e2_src, e2_dst, E2, N_U, starts2, idx2);
  build_csr(e3_src, e3_dst, E3, N_S, starts3, idx3);
  build_csr(e4_src, e4_dst, E4, N_J, starts4, idx4);

  // ---- layer 1 aggregations ----
  aggregate_kernel<128><<<(N_J + 3) / 4, 256, 0, stream>>>(x_user, idx1, starts1, N_J, aggB);
  aggregate_kernel<128><<<(N_U + 3) / 4, 256, 0, stream>>>(x_job, idx2, starts2, N_U, aggA);
  aggregate_kernel<128><<<(N_S + 3) / 4, 256, 0, stream>>>(x_job, idx3, starts3, N_S, aggD);
  aggregate_kernel<64><<<(N_J + 3) / 4, 256, 0, stream>>>(x_skill, idx4, starts4, N_J, aggC);

  Seg z{nullptr, nullptr, 0};

  // ---- layer 1 dense (+ReLU), DOUT=128 ----
  dense_kernel<<<dim3((N_U + 63) / 64, 2), 256, 0, stream>>>(
      Seg{aggA, l1_ju_Wl, 128}, Seg{x_user, l1_ju_Wr, 128}, z, z, 2,
      l1_ju_bl, nullptr, h_u, N_U, 128, 1);
  dense_kernel<<<dim3((N_J + 63) / 64, 2), 256, 0, stream>>>(
      Seg{aggB, l1_uj_Wl, 128}, Seg{aggC, l1_sj_Wl, 64},
      Seg{x_job, l1_uj_Wr, 128}, Seg{x_job, l1_sj_Wr, 128}, 4,
      l1_uj_bl, l1_sj_bl, h_j, N_J, 128, 1);
  dense_kernel<<<dim3((N_S + 63) / 64, 2), 256, 0, stream>>>(
      Seg{aggD, l1_js_Wl, 128}, Seg{x_skill, l1_js_Wr, 64}, z, z, 2,
      l1_js_bl, nullptr, h_s, N_S, 128, 1);

  // ---- layer 2 aggregations (same CSR, hidden features) ----
  aggregate_kernel<128><<<(N_J + 3) / 4, 256, 0, stream>>>(h_u, idx1, starts1, N_J, aggB);
  aggregate_kernel<128><<<(N_U + 3) / 4, 256, 0, stream>>>(h_j, idx2, starts2, N_U, aggA);
  aggregate_kernel<128><<<(N_S + 3) / 4, 256, 0, stream>>>(h_j, idx3, starts3, N_S, aggD);
  aggregate_kernel<128><<<(N_J + 3) / 4, 256, 0, stream>>>(h_s, idx4, starts4, N_J, aggC);

  // ---- layer 2 dense, DOUT=64, no ReLU ----
  dense_kernel<<<dim3((N_U + 63) / 64, 1), 256, 0, stream>>>(
      Seg{aggA, l2_ju_Wl, 128}, Seg{h_u, l2_ju_Wr, 128}, z, z, 2,
      l2_ju_bl, nullptr, o_u, N_U, 64, 0);
  dense_kernel<<<dim3((N_J + 63) / 64, 1), 256, 0, stream>>>(
      Seg{aggB, l2_uj_Wl, 128}, Seg{aggC, l2_sj_Wl, 128},
      Seg{h_j, l2_uj_Wr, 128}, Seg{h_j, l2_sj_Wr, 128}, 4,
      l2_uj_bl, l2_sj_bl, o_j, N_J, 64, 0);
  dense_kernel<<<dim3((N_S + 63) / 64, 1), 256, 0, stream>>>(
      Seg{aggD, l2_js_Wl, 128}, Seg{h_s, l2_js_Wr, 128}, z, z, 2,
      l2_js_bl, nullptr, o_s, N_S, 64, 0);
}

// Round 2
// 780.100 us; speedup vs baseline: 1.2992x; 1.2992x over previous
//
#include <hip/hip_runtime.h>

struct Seg { const float* A; const float* W; int K; };

// ---------------- CSR build ----------------

__global__ void hist_kernel(const int* __restrict__ dst, int E, int* __restrict__ cnt) {
  int i = blockIdx.x * 256 + threadIdx.x;
  if (i < E) atomicAdd(&cnt[dst[i]], 1);
}

// single-block exclusive scan (n <= ~64k), 1024 threads
__global__ void exscan_kernel(const int* __restrict__ cnt, int* __restrict__ starts, int n) {
  __shared__ int wsum[16];
  __shared__ int wpre[16];
  __shared__ int tot_s;
  __shared__ int carry_s;
  int tid = threadIdx.x, lane = tid & 63, wv = tid >> 6;
  if (tid == 0) carry_s = 0;
  for (int base = 0; base < n; base += 1024) {
    __syncthreads();
    int carry = carry_s;
    int i = base + tid;
    int v = (i < n) ? cnt[i] : 0;
    int inc = v;
#pragma unroll
    for (int off = 1; off < 64; off <<= 1) {
      int t = __shfl_up(inc, off, 64);
      if (lane >= off) inc += t;
    }
    if (lane == 63) wsum[wv] = inc;
    __syncthreads();
    if (tid < 16) {
      int x = wsum[tid];
      int p = x;
#pragma unroll
      for (int off = 1; off < 16; off <<= 1) {
        int t = __shfl_up(p, off, 64);
        if (tid >= off) p += t;
      }
      wpre[tid] = p - x;
      if (tid == 15) tot_s = p;
    }
    __syncthreads();
    if (i < n) starts[i] = carry + wpre[wv] + (inc - v);
    if (tid == 0) carry_s = carry + tot_s;
  }
  __syncthreads();
  if (tid == 0) starts[n] = carry_s;
}

__global__ void scatter_kernel(const int* __restrict__ src, const int* __restrict__ dst, int E,
                               const int* __restrict__ starts, int* __restrict__ cur,
                               int* __restrict__ eidx) {
  int i = blockIdx.x * 256 + threadIdx.x;
  if (i >= E) return;
  int d = dst[i];
  int p = starts[d] + atomicAdd(&cur[d], 1);
  eidx[p] = src[i];
}

__global__ void addmat_kernel(const float* __restrict__ a, const float* __restrict__ b,
                              float* __restrict__ o, int n) {
  int i = blockIdx.x * 256 + threadIdx.x;
  if (i < n) o[i] = a[i] + b[i];
}

// ---------------- aggregation: one wave per dst node, edge loop unrolled x4 ----------------

template <int D>
__global__ __launch_bounds__(256) void aggregate_kernel(
    const float* __restrict__ xsrc, const int* __restrict__ eidx,
    const int* __restrict__ starts, int n_dst, float* __restrict__ agg) {
  int w = blockIdx.x * 4 + (threadIdx.x >> 6);
  int lane = threadIdx.x & 63;
  if (w >= n_dst) return;
  int s0 = starts[w], s1 = starts[w + 1];
  int c = s1 - s0;
  float inv = 1.0f / (float)(c > 0 ? c : 1);
  if constexpr (D == 128) {
    const float2* x2 = (const float2*)xsrc;
    float ax0 = 0.f, ay0 = 0.f, ax1 = 0.f, ay1 = 0.f;
    float ax2 = 0.f, ay2 = 0.f, ax3 = 0.f, ay3 = 0.f;
    int e = s0;
    for (; e + 4 <= s1; e += 4) {
      int i0 = eidx[e], i1 = eidx[e + 1], i2 = eidx[e + 2], i3 = eidx[e + 3];
      float2 v0 = x2[(size_t)i0 * 64 + lane];
      float2 v1 = x2[(size_t)i1 * 64 + lane];
      float2 v2 = x2[(size_t)i2 * 64 + lane];
      float2 v3 = x2[(size_t)i3 * 64 + lane];
      ax0 += v0.x; ay0 += v0.y;
      ax1 += v1.x; ay1 += v1.y;
      ax2 += v2.x; ay2 += v2.y;
      ax3 += v3.x; ay3 += v3.y;
    }
    for (; e < s1; ++e) {
      int i0 = eidx[e];
      float2 v0 = x2[(size_t)i0 * 64 + lane];
      ax0 += v0.x; ay0 += v0.y;
    }
    float2 r;
    r.x = ((ax0 + ax1) + (ax2 + ax3)) * inv;
    r.y = ((ay0 + ay1) + (ay2 + ay3)) * inv;
    ((float2*)agg)[(size_t)w * 64 + lane] = r;
  } else {  // D == 64
    float a0 = 0.f, a1 = 0.f, a2 = 0.f, a3 = 0.f;
    int e = s0;
    for (; e + 4 <= s1; e += 4) {
      int i0 = eidx[e], i1 = eidx[e + 1], i2 = eidx[e + 2], i3 = eidx[e + 3];
      float v0 = xsrc[(size_t)i0 * 64 + lane];
      float v1 = xsrc[(size_t)i1 * 64 + lane];
      float v2 = xsrc[(size_t)i2 * 64 + lane];
      float v3 = xsrc[(size_t)i3 * 64 + lane];
      a0 += v0; a1 += v1; a2 += v2; a3 += v3;
    }
    for (; e < s1; ++e) {
      int i0 = eidx[e];
      a0 += xsrc[(size_t)i0 * 64 + lane];
    }
    agg[(size_t)w * 64 + lane] = ((a0 + a1) + (a2 + a3)) * inv;
  }
}

// ---------------- fused dense: out = act(sum_seg A_i @ W_i + b0 (+b1) + add0 (+add1)) ----------------

__device__ __forceinline__ void gemm_seg(const float* __restrict__ A, const float* __restrict__ W,
                                         int K, int ldo, int N, int m0, int n0,
                                         int tid, int tx, int ty,
                                         float (*At)[36], float (*Bt)[64], float acc[4][4]) {
  for (int k0 = 0; k0 < K; k0 += 32) {
#pragma unroll
    for (int i = 0; i < 2; ++i) {
      int fid = tid * 2 + i;
      int row = fid >> 3, q = fid & 7;
      int gr = m0 + row;
      if (gr > N - 1) gr = N - 1;
      float4 v = *(const float4*)(A + (size_t)gr * K + k0 + q * 4);
      *(float4*)&At[row][q * 4] = v;
    }
#pragma unroll
    for (int i = 0; i < 2; ++i) {
      int fid = tid * 2 + i;
      int kr = fid >> 4, q = fid & 15;
      float4 v = *(const float4*)(W + (size_t)(k0 + kr) * ldo + n0 + q * 4);
      *(float4*)&Bt[kr][q * 4] = v;
    }
    __syncthreads();
#pragma unroll
    for (int kk = 0; kk < 32; ++kk) {
      float4 b4 = *(const float4*)&Bt[kk][tx * 4];
      float a0 = At[ty * 4 + 0][kk];
      float a1 = At[ty * 4 + 1][kk];
      float a2 = At[ty * 4 + 2][kk];
      float a3 = At[ty * 4 + 3][kk];
      acc[0][0] += a0 * b4.x; acc[0][1] += a0 * b4.y; acc[0][2] += a0 * b4.z; acc[0][3] += a0 * b4.w;
      acc[1][0] += a1 * b4.x; acc[1][1] += a1 * b4.y; acc[1][2] += a1 * b4.z; acc[1][3] += a1 * b4.w;
      acc[2][0] += a2 * b4.x; acc[2][1] += a2 * b4.y; acc[2][2] += a2 * b4.z; acc[2][3] += a2 * b4.w;
      acc[3][0] += a3 * b4.x; acc[3][1] += a3 * b4.y; acc[3][2] += a3 * b4.z; acc[3][3] += a3 * b4.w;
    }
    __syncthreads();
  }
}

__global__ __launch_bounds__(256) void dense_kernel(
    Seg s0, Seg s1, Seg s2, Seg s3, int nseg,
    const float* __restrict__ bias0, const float* __restrict__ bias1,
    const float* __restrict__ add0, const float* __restrict__ add1,
    float* __restrict__ out, int N, int ldo, int relu) {
  __shared__ float At[64][36];
  __shared__ float Bt[32][64];
  int tid = threadIdx.x;
  int tx = tid & 15, ty = tid >> 4;
  int m0 = blockIdx.x * 64;
  int n0 = blockIdx.y * 64;
  float acc[4][4] = {};
  gemm_seg(s0.A, s0.W, s0.K, ldo, N, m0, n0, tid, tx, ty, At, Bt, acc);
  if (nseg > 1) gemm_seg(s1.A, s1.W, s1.K, ldo, N, m0, n0, tid, tx, ty, At, Bt, acc);
  if (nseg > 2) gemm_seg(s2.A, s2.W, s2.K, ldo, N, m0, n0, tid, tx, ty, At, Bt, acc);
  if (nseg > 3) gemm_seg(s3.A, s3.W, s3.K, ldo, N, m0, n0, tid, tx, ty, At, Bt, acc);

  float bb[4];
#pragma unroll
  for (int j = 0; j < 4; ++j) {
    int cidx = n0 + tx * 4 + j;
    float b = bias0 ? bias0[cidx] : 0.f;
    if (bias1) b += bias1[cidx];
    bb[j] = b;
  }
#pragma unroll
  for (int i = 0; i < 4; ++i) {
    int gr = m0 + ty * 4 + i;
    if (gr < N) {
      float4 r;
      r.x = acc[i][0] + bb[0];
      r.y = acc[i][1] + bb[1];
      r.z = acc[i][2] + bb[2];
      r.w = acc[i][3] + bb[3];
      size_t base = (size_t)gr * ldo + n0 + tx * 4;
      if (add0) {
        float4 a4 = *(const float4*)(add0 + base);
        r.x += a4.x; r.y += a4.y; r.z += a4.z; r.w += a4.w;
      }
      if (add1) {
        float4 a4 = *(const float4*)(add1 + base);
        r.x += a4.x; r.y += a4.y; r.z += a4.z; r.w += a4.w;
      }
      if (relu) {
        r.x = fmaxf(r.x, 0.f); r.y = fmaxf(r.y, 0.f);
        r.z = fmaxf(r.z, 0.f); r.w = fmaxf(r.w, 0.f);
      }
      *(float4*)(out + base) = r;
    }
  }
}

// ---------------- launch ----------------

extern "C" void kernel_launch(void* const* d_in, const int* in_sizes, int n_in,
                              void* d_out, int out_size, void* d_ws, size_t ws_size,
                              hipStream_t stream) {
  const float* x_user  = (const float*)d_in[0];
  const float* x_job   = (const float*)d_in[1];
  const float* x_skill = (const float*)d_in[2];

  const float* l1_uj_Wl = (const float*)d_in[3];
  const float* l1_uj_bl = (const float*)d_in[4];
  const float* l1_uj_Wr = (const float*)d_in[5];
  const float* l2_uj_Wl = (const float*)d_in[6];
  const float* l2_uj_bl = (const float*)d_in[7];
  const float* l2_uj_Wr = (const float*)d_in[8];

  const float* l1_ju_Wl = (const float*)d_in[9];
  const float* l1_ju_bl = (const float*)d_in[10];
  const float* l1_ju_Wr = (const float*)d_in[11];
  const float* l2_ju_Wl = (const float*)d_in[12];
  const float* l2_ju_bl = (const float*)d_in[13];
  const float* l2_ju_Wr = (const float*)d_in[14];

  const float* l1_js_Wl = (const float*)d_in[15];
  const float* l1_js_bl = (const float*)d_in[16];
  const float* l1_js_Wr = (const float*)d_in[17];
  const float* l2_js_Wl = (const float*)d_in[18];
  const float* l2_js_bl = (const float*)d_in[19];
  const float* l2_js_Wr = (const float*)d_in[20];

  const float* l1_sj_Wl = (const float*)d_in[21];
  const float* l1_sj_bl = (const float*)d_in[22];
  const float* l1_sj_Wr = (const float*)d_in[23];
  const float* l2_sj_Wl = (const float*)d_in[24];
  const float* l2_sj_bl = (const float*)d_in[25];
  const float* l2_sj_Wr = (const float*)d_in[26];

  const int* e1_src = (const int*)d_in[27];
  const int* e1_dst = (const int*)d_in[28];
  const int* e2_src = (const int*)d_in[29];
  const int* e2_dst = (const int*)d_in[30];
  const int* e3_src = (const int*)d_in[31];
  const int* e3_dst = (const int*)d_in[32];
  const int* e4_src = (const int*)d_in[33];
  const int* e4_dst = (const int*)d_in[34];

  const int N_U = in_sizes[0] / 128;
  const int N_J = in_sizes[1] / 128;
  const int N_S = in_sizes[2] / 64;
  const int E1 = in_sizes[27], E2 = in_sizes[29], E3 = in_sizes[31], E4 = in_sizes[33];

  char* wsp = (char*)d_ws;
  size_t off = 0;
  auto alloc = [&](size_t bytes) -> void* {
    void* p = wsp + off;
    off += (bytes + 255) & ~(size_t)255;
    return p;
  };

  int* starts1 = (int*)alloc((size_t)(N_J + 1) * 4);
  int* starts2 = (int*)alloc((size_t)(N_U + 1) * 4);
  int* starts3 = (int*)alloc((size_t)(N_S + 1) * 4);
  int* starts4 = (int*)alloc((size_t)(N_J + 1) * 4);
  int* idx1 = (int*)alloc((size_t)E1 * 4);
  int* idx2 = (int*)alloc((size_t)E2 * 4);
  int* idx3 = (int*)alloc((size_t)E3 * 4);
  int* idx4 = (int*)alloc((size_t)E4 * 4);
  int* cur  = (int*)alloc((size_t)N_U * 4);

  float* h_u  = (float*)alloc((size_t)N_U * 128 * 4);
  float* h_j  = (float*)alloc((size_t)N_J * 128 * 4);
  float* h_s  = (float*)alloc((size_t)N_S * 128 * 4);
  float* aggA = (float*)alloc((size_t)N_U * 128 * 4);  // dst=user aggregations
  float* aggB = (float*)alloc((size_t)N_J * 128 * 4);  // dst=job (uj)
  float* aggC = (float*)alloc((size_t)N_J * 128 * 4);  // dst=job (sj)
  float* aggD = (float*)alloc((size_t)N_S * 128 * 4);  // dst=skill
  float* t_uj = (float*)alloc((size_t)N_U * 64 * 4);   // h_u @ l2_uj_Wl
  float* t_ju = (float*)alloc((size_t)N_J * 64 * 4);   // h_j @ l2_ju_Wl
  float* t_js = (float*)alloc((size_t)N_J * 64 * 4);   // h_j @ l2_js_Wl
  float* t_sj = (float*)alloc((size_t)N_S * 64 * 4);   // h_s @ l2_sj_Wl
  float* Wsum = (float*)alloc((size_t)128 * 64 * 4);   // l2_uj_Wr + l2_sj_Wr

  float* o_u = (float*)d_out;
  float* o_j = o_u + (size_t)N_U * 64;
  float* o_s = o_j + (size_t)N_J * 64;

  auto build_csr = [&](const int* esrc, const int* edst, int E, int Nd, int* starts, int* eidx) {
    hipMemsetAsync(cur, 0, (size_t)Nd * 4, stream);
    hist_kernel<<<(E + 255) / 256, 256, 0, stream>>>(edst, E, cur);
    exscan_kernel<<<1, 1024, 0, stream>>>(cur, starts, Nd);
    hipMemsetAsync(cur, 0, (size_t)Nd * 4, stream);
    scatter_kernel<<<(E + 255) / 256, 256, 0, stream>>>(esrc, edst, E, starts, cur, eidx);
  };
  build_csr(e1_src, e1_dst, E1, N_J, starts1, idx1);
  build_csr(e2_src, e2_dst, E2, N_U, starts2, idx2);
  build_csr(e3_src, e3_dst, E3, N_S, starts3, idx3);
  build_csr(e4_src, e4_dst, E4, N_J, starts4, idx4);

  // ---- layer 1 aggregations (raw features) ----
  aggregate_kernel<128><<<(N_J + 3) / 4, 256, 0, stream>>>(x_user, idx1, starts1, N_J, aggB);
  aggregate_kernel<128><<<(N_U + 3) / 4, 256, 0, stream>>>(x_job, idx2, starts2, N_U, aggA);
  aggregate_kernel<128><<<(N_S + 3) / 4, 256, 0, stream>>>(x_job, idx3, starts3, N_S, aggD);
  aggregate_kernel<64><<<(N_J + 3) / 4, 256, 0, stream>>>(x_skill, idx4, starts4, N_J, aggC);

  Seg z{nullptr, nullptr, 0};

  // ---- layer 1 dense (+ReLU), DOUT=128 ----
  dense_kernel<<<dim3((N_U + 63) / 64, 2), 256, 0, stream>>>(
      Seg{aggA, l1_ju_Wl, 128}, Seg{x_user, l1_ju_Wr, 128}, z, z, 2,
      l1_ju_bl, nullptr, nullptr, nullptr, h_u, N_U, 128, 1);
  dense_kernel<<<dim3((N_J + 63) / 64, 2), 256, 0, stream>>>(
      Seg{aggB, l1_uj_Wl, 128}, Seg{aggC, l1_sj_Wl, 64},
      Seg{x_job, l1_uj_Wr, 128}, Seg{x_job, l1_sj_Wr, 128}, 4,
      l1_uj_bl, l1_sj_bl, nullptr, nullptr, h_j, N_J, 128, 1);
  dense_kernel<<<dim3((N_S + 63) / 64, 2), 256, 0, stream>>>(
      Seg{aggD, l1_js_Wl, 128}, Seg{x_skill, l1_js_Wr, 64}, z, z, 2,
      l1_js_bl, nullptr, nullptr, nullptr, h_s, N_S, 128, 1);

  // ---- layer 2: transform sources FIRST (linearity), then gather width 64 ----
  dense_kernel<<<dim3((N_U + 63) / 64, 1), 256, 0, stream>>>(
      Seg{h_u, l2_uj_Wl, 128}, z, z, z, 1,
      nullptr, nullptr, nullptr, nullptr, t_uj, N_U, 64, 0);
  dense_kernel<<<dim3((N_J + 63) / 64, 1), 256, 0, stream>>>(
      Seg{h_j, l2_ju_Wl, 128}, z, z, z, 1,
      nullptr, nullptr, nullptr, nullptr, t_ju, N_J, 64, 0);
  dense_kernel<<<dim3((N_J + 63) / 64, 1), 256, 0, stream>>>(
      Seg{h_j, l2_js_Wl, 128}, z, z, z, 1,
      nullptr, nullptr, nullptr, nullptr, t_js, N_J, 64, 0);
  dense_kernel<<<dim3((N_S + 63) / 64, 1), 256, 0, stream>>>(
      Seg{h_s, l2_sj_Wl, 128}, z, z, z, 1,
      nullptr, nullptr, nullptr, nullptr, t_sj, N_S, 64, 0);

  // width-64 gathers of transformed features
  aggregate_kernel<64><<<(N_J + 3) / 4, 256, 0, stream>>>(t_uj, idx1, starts1, N_J, aggB);
  aggregate_kernel<64><<<(N_U + 3) / 4, 256, 0, stream>>>(t_ju, idx2, starts2, N_U, aggA);
  aggregate_kernel<64><<<(N_S + 3) / 4, 256, 0, stream>>>(t_js, idx3, starts3, N_S, aggD);
  aggregate_kernel<64><<<(N_J + 3) / 4, 256, 0, stream>>>(t_sj, idx4, starts4, N_J, aggC);

  // combine the two Wr matrices feeding o_j (both applied to h_j)
  addmat_kernel<<<(128 * 64 + 255) / 256, 256, 0, stream>>>(l2_uj_Wr, l2_sj_Wr, Wsum, 128 * 64);

  // ---- layer 2 final dense, DOUT=64, no ReLU ----
  dense_kernel<<<dim3((N_U + 63) / 64, 1), 256, 0, stream>>>(
      Seg{h_u, l2_ju_Wr, 128}, z, z, z, 1,
      l2_ju_bl, nullptr, aggA, nullptr, o_u, N_U, 64, 0);
  dense_kernel<<<dim3((N_J + 63) / 64, 1), 256, 0, stream>>>(
      Seg{h_j, Wsum, 128}, z, z, z, 1,
      l2_uj_bl, l2_sj_bl, aggB, aggC, o_j, N_J, 64, 0);
  dense_kernel<<<dim3((N_S + 63) / 64, 1), 256, 0, stream>>>(
      Seg{h_s, l2_js_Wr, 128}, z, z, z, 1,
      l2_js_bl, nullptr, aggD, nullptr, o_s, N_S, 64, 0);
}

// Round 4
// 729.081 us; speedup vs baseline: 1.3901x; 1.0700x over previous
//
#include <hip/hip_runtime.h>

struct Seg { const float* A; const float* W; int K; };

__device__ __forceinline__ unsigned f2bf(float f) {
  unsigned u = __builtin_bit_cast(unsigned, f);
  return (u + 0x7fffu + ((u >> 16) & 1u)) >> 16;
}
__device__ __forceinline__ float bflo(unsigned u) {
  return __builtin_bit_cast(float, u << 16);
}
__device__ __forceinline__ float bfhi(unsigned u) {
  return __builtin_bit_cast(float, u & 0xffff0000u);
}

// ---------------- CSR build ----------------

__global__ void hist_kernel(const int* __restrict__ dst, int E, int* __restrict__ cnt) {
  int i = blockIdx.x * 256 + threadIdx.x;
  if (i < E) atomicAdd(&cnt[dst[i]], 1);
}

__global__ void exscan_kernel(const int* __restrict__ cnt, int* __restrict__ starts, int n) {
  __shared__ int wsum[16];
  __shared__ int wpre[16];
  __shared__ int tot_s;
  __shared__ int carry_s;
  int tid = threadIdx.x, lane = tid & 63, wv = tid >> 6;
  if (tid == 0) carry_s = 0;
  for (int base = 0; base < n; base += 1024) {
    __syncthreads();
    int carry = carry_s;
    int i = base + tid;
    int v = (i < n) ? cnt[i] : 0;
    int inc = v;
#pragma unroll
    for (int off = 1; off < 64; off <<= 1) {
      int t = __shfl_up(inc, off, 64);
      if (lane >= off) inc += t;
    }
    if (lane == 63) wsum[wv] = inc;
    __syncthreads();
    if (tid < 16) {
      int x = wsum[tid];
      int p = x;
#pragma unroll
      for (int off = 1; off < 16; off <<= 1) {
        int t = __shfl_up(p, off, 64);
        if (tid >= off) p += t;
      }
      wpre[tid] = p - x;
      if (tid == 15) tot_s = p;
    }
    __syncthreads();
    if (i < n) starts[i] = carry + wpre[wv] + (inc - v);
    if (tid == 0) carry_s = carry + tot_s;
  }
  __syncthreads();
  if (tid == 0) starts[n] = carry_s;
}

__global__ void scatter_kernel(const int* __restrict__ src, const int* __restrict__ dst, int E,
                               const int* __restrict__ starts, int* __restrict__ cur,
                               int* __restrict__ eidx) {
  int i = blockIdx.x * 256 + threadIdx.x;
  if (i >= E) return;
  int d = dst[i];
  int p = starts[d] + atomicAdd(&cur[d], 1);
  eidx[p] = src[i];
}

__global__ void addmat_kernel(const float* __restrict__ a, const float* __restrict__ b,
                              float* __restrict__ o, int n) {
  int i = blockIdx.x * 256 + threadIdx.x;
  if (i < n) o[i] = a[i] + b[i];
}

__global__ void tobf16_kernel(const float* __restrict__ in, unsigned* __restrict__ out, int n4) {
  int i = blockIdx.x * 256 + threadIdx.x;
  if (i >= n4) return;
  float4 v = ((const float4*)in)[i];
  uint2 r;
  r.x = f2bf(v.x) | (f2bf(v.y) << 16);
  r.y = f2bf(v.z) | (f2bf(v.w) << 16);
  ((uint2*)out)[i] = r;
}

// ---------------- bf16 gather-mean: one wave per dst, half-wave edge pairing ----------------

// D = feature width (elements). D=128: uint2/lane over 32 lanes. D=64: uint/lane over 32 lanes.
template <int D>
__global__ __launch_bounds__(256) void aggregate_bf16_kernel(
    const unsigned* __restrict__ xsrc, const int* __restrict__ eidx,
    const int* __restrict__ starts, int n_dst, float* __restrict__ agg) {
  int w = blockIdx.x * 4 + (threadIdx.x >> 6);
  int lane = threadIdx.x & 63;
  if (w >= n_dst) return;
  int sub = lane >> 5, sl = lane & 31;
  int s0 = starts[w], s1 = starts[w + 1];
  int c = s1 - s0;
  float inv = 1.0f / (float)(c > 0 ? c : 1);

  if constexpr (D == 128) {
    const uint2* x2 = (const uint2*)xsrc;  // 32 uint2 per row
    float a0 = 0.f, a1 = 0.f, a2 = 0.f, a3 = 0.f;
    float b0 = 0.f, b1 = 0.f, b2 = 0.f, b3 = 0.f;
    int e = s0;
    for (; e + 8 <= s1; e += 8) {
      int i0 = eidx[e + sub];
      int i1 = eidx[e + 2 + sub];
      int i2 = eidx[e + 4 + sub];
      int i3 = eidx[e + 6 + sub];
      uint2 u0 = x2[(size_t)i0 * 32 + sl];
      uint2 u1 = x2[(size_t)i1 * 32 + sl];
      uint2 u2 = x2[(size_t)i2 * 32 + sl];
      uint2 u3 = x2[(size_t)i3 * 32 + sl];
      a0 += bflo(u0.x); a1 += bfhi(u0.x); a2 += bflo(u0.y); a3 += bfhi(u0.y);
      b0 += bflo(u1.x); b1 += bfhi(u1.x); b2 += bflo(u1.y); b3 += bfhi(u1.y);
      a0 += bflo(u2.x); a1 += bfhi(u2.x); a2 += bflo(u2.y); a3 += bfhi(u2.y);
      b0 += bflo(u3.x); b1 += bfhi(u3.x); b2 += bflo(u3.y); b3 += bfhi(u3.y);
    }
    for (; e + 2 <= s1; e += 2) {
      int i0 = eidx[e + sub];
      uint2 u0 = x2[(size_t)i0 * 32 + sl];
      a0 += bflo(u0.x); a1 += bfhi(u0.x); a2 += bflo(u0.y); a3 += bfhi(u0.y);
    }
    if (e < s1 && sub == 0) {
      uint2 u0 = x2[(size_t)eidx[e] * 32 + sl];
      a0 += bflo(u0.x); a1 += bfhi(u0.x); a2 += bflo(u0.y); a3 += bfhi(u0.y);
    }
    a0 += b0; a1 += b1; a2 += b2; a3 += b3;
    a0 += __shfl_xor(a0, 32);
    a1 += __shfl_xor(a1, 32);
    a2 += __shfl_xor(a2, 32);
    a3 += __shfl_xor(a3, 32);
    if (sub == 0) {
      float4 r; r.x = a0 * inv; r.y = a1 * inv; r.z = a2 * inv; r.w = a3 * inv;
      *(float4*)&agg[(size_t)w * 128 + sl * 4] = r;
    }
  } else {  // D == 64: 32 uints per row
    float a0 = 0.f, a1 = 0.f, b0 = 0.f, b1 = 0.f;
    int e = s0;
    for (; e + 8 <= s1; e += 8) {
      int i0 = eidx[e + sub];
      int i1 = eidx[e + 2 + sub];
      int i2 = eidx[e + 4 + sub];
      int i3 = eidx[e + 6 + sub];
      unsigned u0 = xsrc[(size_t)i0 * 32 + sl];
      unsigned u1 = xsrc[(size_t)i1 * 32 + sl];
      unsigned u2 = xsrc[(size_t)i2 * 32 + sl];
      unsigned u3 = xsrc[(size_t)i3 * 32 + sl];
      a0 += bflo(u0); a1 += bfhi(u0);
      b0 += bflo(u1); b1 += bfhi(u1);
      a0 += bflo(u2); a1 += bfhi(u2);
      b0 += bflo(u3); b1 += bfhi(u3);
    }
    for (; e + 2 <= s1; e += 2) {
      unsigned u0 = xsrc[(size_t)eidx[e + sub] * 32 + sl];
      a0 += bflo(u0); a1 += bfhi(u0);
    }
    if (e < s1 && sub == 0) {
      unsigned u0 = xsrc[(size_t)eidx[e] * 32 + sl];
      a0 += bflo(u0); a1 += bfhi(u0);
    }
    a0 += b0; a1 += b1;
    a0 += __shfl_xor(a0, 32);
    a1 += __shfl_xor(a1, 32);
    if (sub == 0) {
      float2 r; r.x = a0 * inv; r.y = a1 * inv;
      *(float2*)&agg[(size_t)w * 64 + sl * 2] = r;
    }
  }
}

// ---------------- fused dense: out = act(sum_seg A_i @ W_i + b0 (+b1) + add0 (+add1)) ----------------
// 128x64 tile, 256 threads, 4x8 micro-tile, BK=32. At padded to 37 floats (conflict-free scalar reads).

__device__ __forceinline__ void gemm_seg2(const float* __restrict__ A, const float* __restrict__ W,
                                          int K, int ldo, int N, int m0, int n0,
                                          int tid, int tx, int ty,
                                          float (*At)[37], float (*Bt)[64], float acc[4][8]) {
  for (int k0 = 0; k0 < K; k0 += 32) {
#pragma unroll
    for (int i = 0; i < 4; ++i) {
      int c = i * 256 + tid;           // 1024 float4 chunks: 128 rows x 8 q
      int row = c >> 3, q = c & 7;
      int gr = m0 + row;
      if (gr > N - 1) gr = N - 1;
      float4 v = *(const float4*)(A + (size_t)gr * K + k0 + q * 4);
      At[row][q * 4 + 0] = v.x;
      At[row][q * 4 + 1] = v.y;
      At[row][q * 4 + 2] = v.z;
      At[row][q * 4 + 3] = v.w;
    }
#pragma unroll
    for (int i = 0; i < 2; ++i) {
      int c = i * 256 + tid;           // 512 float4 chunks: 32 k x 16 q
      int kr = c >> 4, qb = c & 15;
      float4 v = *(const float4*)(W + (size_t)(k0 + kr) * ldo + n0 + qb * 4);
      *(float4*)&Bt[kr][qb * 4] = v;
    }
    __syncthreads();
#pragma unroll
    for (int kk = 0; kk < 32; ++kk) {
      float4 w0 = *(const float4*)&Bt[kk][tx * 8];
      float4 w1 = *(const float4*)&Bt[kk][tx * 8 + 4];
      float a0 = At[ty * 4 + 0][kk];
      float a1 = At[ty * 4 + 1][kk];
      float a2 = At[ty * 4 + 2][kk];
      float a3 = At[ty * 4 + 3][kk];
      acc[0][0] += a0 * w0.x; acc[0][1] += a0 * w0.y; acc[0][2] += a0 * w0.z; acc[0][3] += a0 * w0.w;
      acc[0][4] += a0 * w1.x; acc[0][5] += a0 * w1.y; acc[0][6] += a0 * w1.z; acc[0][7] += a0 * w1.w;
      acc[1][0] += a1 * w0.x; acc[1][1] += a1 * w0.y; acc[1][2] += a1 * w0.z; acc[1][3] += a1 * w0.w;
      acc[1][4] += a1 * w1.x; acc[1][5] += a1 * w1.y; acc[1][6] += a1 * w1.z; acc[1][7] += a1 * w1.w;
      acc[2][0] += a2 * w0.x; acc[2][1] += a2 * w0.y; acc[2][2] += a2 * w0.z; acc[2][3] += a2 * w0.w;
      acc[2][4] += a2 * w1.x; acc[2][5] += a2 * w1.y; acc[2][6] += a2 * w1.z; acc[2][7] += a2 * w1.w;
      acc[3][0] += a3 * w0.x; acc[3][1] += a3 * w0.y; acc[3][2] += a3 * w0.z; acc[3][3] += a3 * w0.w;
      acc[3][4] += a3 * w1.x; acc[3][5] += a3 * w1.y; acc[3][6] += a3 * w1.z; acc[3][7] += a3 * w1.w;
    }
    __syncthreads();
  }
}

__global__ __launch_bounds__(256) void dense_kernel(
    Seg s0, Seg s1, Seg s2, int nseg,
    const float* __restrict__ bias0, const float* __restrict__ bias1,
    const float* __restrict__ add0, const float* __restrict__ add1,
    float* __restrict__ out_f32, unsigned short* __restrict__ out_bf16,
    int N, int ldo, int relu) {
  __shared__ float At[128][37];
  __shared__ float Bt[32][64];
  int tid = threadIdx.x;
  int tx = tid & 7, ty = tid >> 3;
  int m0 = blockIdx.x * 128;
  int n0 = blockIdx.y * 64;
  float acc[4][8] = {};
  gemm_seg2(s0.A, s0.W, s0.K, ldo, N, m0, n0, tid, tx, ty, At, Bt, acc);
  if (nseg > 1) gemm_seg2(s1.A, s1.W, s1.K, ldo, N, m0, n0, tid, tx, ty, At, Bt, acc);
  if (nseg > 2) gemm_seg2(s2.A, s2.W, s2.K, ldo, N, m0, n0, tid, tx, ty, At, Bt, acc);

  float bb[8];
#pragma unroll
  for (int j = 0; j < 8; ++j) {
    int cidx = n0 + tx * 8 + j;
    float b = bias0 ? bias0[cidx] : 0.f;
    if (bias1) b += bias1[cidx];
    bb[j] = b;
  }
#pragma unroll
  for (int i = 0; i < 4; ++i) {
    int gr = m0 + ty * 4 + i;
    if (gr >= N) continue;
    size_t base = (size_t)gr * ldo + n0 + tx * 8;
    float r[8];
#pragma unroll
    for (int j = 0; j < 8; ++j) r[j] = acc[i][j] + bb[j];
    if (add0) {
      float4 a0 = *(const float4*)(add0 + base);
      float4 a1 = *(const float4*)(add0 + base + 4);
      r[0] += a0.x; r[1] += a0.y; r[2] += a0.z; r[3] += a0.w;
      r[4] += a1.x; r[5] += a1.y; r[6] += a1.z; r[7] += a1.w;
    }
    if (add1) {
      float4 a0 = *(const float4*)(add1 + base);
      float4 a1 = *(const float4*)(add1 + base + 4);
      r[0] += a0.x; r[1] += a0.y; r[2] += a0.z; r[3] += a0.w;
      r[4] += a1.x; r[5] += a1.y; r[6] += a1.z; r[7] += a1.w;
    }
    if (relu) {
#pragma unroll
      for (int j = 0; j < 8; ++j) r[j] = fmaxf(r[j], 0.f);
    }
    if (out_bf16) {
      uint4 p;
      p.x = f2bf(r[0]) | (f2bf(r[1]) << 16);
      p.y = f2bf(r[2]) | (f2bf(r[3]) << 16);
      p.z = f2bf(r[4]) | (f2bf(r[5]) << 16);
      p.w = f2bf(r[6]) | (f2bf(r[7]) << 16);
      *(uint4*)(out_bf16 + base) = p;
    } else {
      float4 o0; o0.x = r[0]; o0.y = r[1]; o0.z = r[2]; o0.w = r[3];
      float4 o1; o1.x = r[4]; o1.y = r[5]; o1.z = r[6]; o1.w = r[7];
      *(float4*)(out_f32 + base) = o0;
      *(float4*)(out_f32 + base + 4) = o1;
    }
  }
}

// ---------------- launch ----------------

extern "C" void kernel_launch(void* const* d_in, const int* in_sizes, int n_in,
                              void* d_out, int out_size, void* d_ws, size_t ws_size,
                              hipStream_t stream) {
  const float* x_user  = (const float*)d_in[0];
  const float* x_job   = (const float*)d_in[1];
  const float* x_skill = (const float*)d_in[2];

  const float* l1_uj_Wl = (const float*)d_in[3];
  const float* l1_uj_bl = (const float*)d_in[4];
  const float* l1_uj_Wr = (const float*)d_in[5];
  const float* l2_uj_Wl = (const float*)d_in[6];
  const float* l2_uj_bl = (const float*)d_in[7];
  const float* l2_uj_Wr = (const float*)d_in[8];

  const float* l1_ju_Wl = (const float*)d_in[9];
  const float* l1_ju_bl = (const float*)d_in[10];
  const float* l1_ju_Wr = (const float*)d_in[11];
  const float* l2_ju_Wl = (const float*)d_in[12];
  const float* l2_ju_bl = (const float*)d_in[13];
  const float* l2_ju_Wr = (const float*)d_in[14];

  const float* l1_js_Wl = (const float*)d_in[15];
  const float* l1_js_bl = (const float*)d_in[16];
  const float* l1_js_Wr = (const float*)d_in[17];
  const float* l2_js_Wl = (const float*)d_in[18];
  const float* l2_js_bl = (const float*)d_in[19];
  const float* l2_js_Wr = (const float*)d_in[20];

  const float* l1_sj_Wl = (const float*)d_in[21];
  const float* l1_sj_bl = (const float*)d_in[22];
  const float* l1_sj_Wr = (const float*)d_in[23];
  const float* l2_sj_Wl = (const float*)d_in[24];
  const float* l2_sj_bl = (const float*)d_in[25];
  const float* l2_sj_Wr = (const float*)d_in[26];

  const int* e1_src = (const int*)d_in[27];
  const int* e1_dst = (const int*)d_in[28];
  const int* e2_src = (const int*)d_in[29];
  const int* e2_dst = (const int*)d_in[30];
  const int* e3_src = (const int*)d_in[31];
  const int* e3_dst = (const int*)d_in[32];
  const int* e4_src = (const int*)d_in[33];
  const int* e4_dst = (const int*)d_in[34];

  const int N_U = in_sizes[0] / 128;
  const int N_J = in_sizes[1] / 128;
  const int N_S = in_sizes[2] / 64;
  const int E1 = in_sizes[27], E2 = in_sizes[29], E3 = in_sizes[31], E4 = in_sizes[33];

  char* wsp = (char*)d_ws;
  size_t off = 0;
  auto alloc = [&](size_t bytes) -> void* {
    void* p = wsp + off;
    off += (bytes + 255) & ~(size_t)255;
    return p;
  };

  int* starts1 = (int*)alloc((size_t)(N_J + 1) * 4);
  int* starts2 = (int*)alloc((size_t)(N_U + 1) * 4);
  int* starts3 = (int*)alloc((size_t)(N_S + 1) * 4);
  int* starts4 = (int*)alloc((size_t)(N_J + 1) * 4);
  int* idx1 = (int*)alloc((size_t)E1 * 4);
  int* idx2 = (int*)alloc((size_t)E2 * 4);
  int* idx3 = (int*)alloc((size_t)E3 * 4);
  int* idx4 = (int*)alloc((size_t)E4 * 4);
  int* cur  = (int*)alloc((size_t)N_U * 4);

  float* h_u  = (float*)alloc((size_t)N_U * 128 * 4);
  float* h_j  = (float*)alloc((size_t)N_J * 128 * 4);
  float* h_s  = (float*)alloc((size_t)N_S * 128 * 4);
  float* aggA = (float*)alloc((size_t)N_U * 128 * 4);
  float* aggB = (float*)alloc((size_t)N_J * 128 * 4);
  float* aggC = (float*)alloc((size_t)N_J * 128 * 4);
  float* aggD = (float*)alloc((size_t)N_S * 128 * 4);

  unsigned* xu_bf = (unsigned*)alloc((size_t)N_U * 128 * 2);
  unsigned* xj_bf = (unsigned*)alloc((size_t)N_J * 128 * 2);
  unsigned* xs_bf = (unsigned*)alloc((size_t)N_S * 64 * 2);
  unsigned* t_uj  = (unsigned*)alloc((size_t)N_U * 64 * 2);   // bf16: h_u @ l2_uj_Wl
  unsigned* t_ju  = (unsigned*)alloc((size_t)N_J * 64 * 2);   // bf16: h_j @ l2_ju_Wl
  unsigned* t_js  = (unsigned*)alloc((size_t)N_J * 64 * 2);   // bf16: h_j @ l2_js_Wl
  unsigned* t_sj  = (unsigned*)alloc((size_t)N_S * 64 * 2);   // bf16: h_s @ l2_sj_Wl
  float* Wr1sum = (float*)alloc((size_t)128 * 128 * 4);       // l1_uj_Wr + l1_sj_Wr
  float* Wr2sum = (float*)alloc((size_t)128 * 64 * 4);        // l2_uj_Wr + l2_sj_Wr

  float* o_u = (float*)d_out;
  float* o_j = o_u + (size_t)N_U * 64;
  float* o_s = o_j + (size_t)N_J * 64;

  auto build_csr = [&](const int* esrc, const int* edst, int E, int Nd, int* starts, int* eidx) {
    hipMemsetAsync(cur, 0, (size_t)Nd * 4, stream);
    hist_kernel<<<(E + 255) / 256, 256, 0, stream>>>(edst, E, cur);
    exscan_kernel<<<1, 1024, 0, stream>>>(cur, starts, Nd);
    hipMemsetAsync(cur, 0, (size_t)Nd * 4, stream);
    scatter_kernel<<<(E + 255) / 256, 256, 0, stream>>>(esrc, edst, E, starts, cur, eidx);
  };
  build_csr(e1_src, e1_dst, E1, N_J, starts1, idx1);
  build_csr(e2_src, e2_dst, E2, N_U, starts2, idx2);
  build_csr(e3_src, e3_dst, E3, N_S, starts3, idx3);
  build_csr(e4_src, e4_dst, E4, N_J, starts4, idx4);

  // bf16 copies of gather sources + pre-summed Wr matrices
  tobf16_kernel<<<(N_U * 32 + 255) / 256, 256, 0, stream>>>(x_user, xu_bf, N_U * 32);
  tobf16_kernel<<<(N_J * 32 + 255) / 256, 256, 0, stream>>>(x_job, xj_bf, N_J * 32);
  tobf16_kernel<<<(N_S * 16 + 255) / 256, 256, 0, stream>>>(x_skill, xs_bf, N_S * 16);
  addmat_kernel<<<(128 * 128 + 255) / 256, 256, 0, stream>>>(l1_uj_Wr, l1_sj_Wr, Wr1sum, 128 * 128);
  addmat_kernel<<<(128 * 64 + 255) / 256, 256, 0, stream>>>(l2_uj_Wr, l2_sj_Wr, Wr2sum, 128 * 64);

  // ---- layer 1 aggregations (bf16 sources, fp32 out) ----
  aggregate_bf16_kernel<128><<<(N_J + 3) / 4, 256, 0, stream>>>(xu_bf, idx1, starts1, N_J, aggB);
  aggregate_bf16_kernel<128><<<(N_U + 3) / 4, 256, 0, stream>>>(xj_bf, idx2, starts2, N_U, aggA);
  aggregate_bf16_kernel<128><<<(N_S + 3) / 4, 256, 0, stream>>>(xj_bf, idx3, starts3, N_S, aggD);
  aggregate_bf16_kernel<64><<<(N_J + 3) / 4, 256, 0, stream>>>(xs_bf, idx4, starts4, N_J, aggC);

  Seg z{nullptr, nullptr, 0};

  // ---- layer 1 dense (+ReLU), out 128 cols fp32 ----
  dense_kernel<<<dim3((N_U + 127) / 128, 2), 256, 0, stream>>>(
      Seg{aggA, l1_ju_Wl, 128}, Seg{x_user, l1_ju_Wr, 128}, z, 2,
      l1_ju_bl, nullptr, nullptr, nullptr, h_u, nullptr, N_U, 128, 1);
  dense_kernel<<<dim3((N_J + 127) / 128, 2), 256, 0, stream>>>(
      Seg{aggB, l1_uj_Wl, 128}, Seg{aggC, l1_sj_Wl, 64}, Seg{x_job, Wr1sum, 128}, 3,
      l1_uj_bl, l1_sj_bl, nullptr, nullptr, h_j, nullptr, N_J, 128, 1);
  dense_kernel<<<dim3((N_S + 127) / 128, 2), 256, 0, stream>>>(
      Seg{aggD, l1_js_Wl, 128}, Seg{x_skill, l1_js_Wr, 64}, z, 2,
      l1_js_bl, nullptr, nullptr, nullptr, h_s, nullptr, N_S, 128, 1);

  // ---- layer 2: transform-then-gather (bf16 transformed tables) ----
  dense_kernel<<<dim3((N_U + 127) / 128, 1), 256, 0, stream>>>(
      Seg{h_u, l2_uj_Wl, 128}, z, z, 1,
      nullptr, nullptr, nullptr, nullptr, nullptr, (unsigned short*)t_uj, N_U, 64, 0);
  dense_kernel<<<dim3((N_J + 127) / 128, 1), 256, 0, stream>>>(
      Seg{h_j, l2_ju_Wl, 128}, z, z, 1,
      nullptr, nullptr, nullptr, nullptr, nullptr, (unsigned short*)t_ju, N_J, 64, 0);
  dense_kernel<<<dim3((N_J + 127) / 128, 1), 256, 0, stream>>>(
      Seg{h_j, l2_js_Wl, 128}, z, z, 1,
      nullptr, nullptr, nullptr, nullptr, nullptr, (unsigned short*)t_js, N_J, 64, 0);
  dense_kernel<<<dim3((N_S + 127) / 128, 1), 256, 0, stream>>>(
      Seg{h_s, l2_sj_Wl, 128}, z, z, 1,
      nullptr, nullptr, nullptr, nullptr, nullptr, (unsigned short*)t_sj, N_S, 64, 0);

  // width-64 bf16 gathers
  aggregate_bf16_kernel<64><<<(N_J + 3) / 4, 256, 0, stream>>>(t_uj, idx1, starts1, N_J, aggB);
  aggregate_bf16_kernel<64><<<(N_U + 3) / 4, 256, 0, stream>>>(t_ju, idx2, starts2, N_U, aggA);
  aggregate_bf16_kernel<64><<<(N_S + 3) / 4, 256, 0, stream>>>(t_js, idx3, starts3, N_S, aggD);
  aggregate_bf16_kernel<64><<<(N_J + 3) / 4, 256, 0, stream>>>(t_sj, idx4, starts4, N_J, aggC);

  // ---- layer 2 final dense, out 64 cols fp32 + aggregated addends ----
  dense_kernel<<<dim3((N_U + 127) / 128, 1), 256, 0, stream>>>(
      Seg{h_u, l2_ju_Wr, 128}, z, z, 1,
      l2_ju_bl, nullptr, aggA, nullptr, o_u, nullptr, N_U, 64, 0);
  dense_kernel<<<dim3((N_J + 127) / 128, 1), 256, 0, stream>>>(
      Seg{h_j, Wr2sum, 128}, z, z, 1,
      l2_uj_bl, l2_sj_bl, aggB, aggC, o_j, nullptr, N_J, 64, 0);
  dense_kernel<<<dim3((N_S + 127) / 128, 1), 256, 0, stream>>>(
      Seg{h_s, l2_js_Wr, 128}, z, z, 1,
      l2_js_bl, nullptr, aggD, nullptr, o_s, nullptr, N_S, 64, 0);
}

// Round 5
// 682.046 us; speedup vs baseline: 1.4860x; 1.0690x over previous
//
#include <hip/hip_runtime.h>

typedef short short8 __attribute__((ext_vector_type(8)));
typedef float floatx4 __attribute__((ext_vector_type(4)));

__device__ __forceinline__ unsigned f2bf(float f) {
  unsigned u = __builtin_bit_cast(unsigned, f);
  return (u + 0x7fffu + ((u >> 16) & 1u)) >> 16;
}
__device__ __forceinline__ float bflo(unsigned u) { return __builtin_bit_cast(float, u << 16); }
__device__ __forceinline__ float bfhi(unsigned u) { return __builtin_bit_cast(float, u & 0xffff0000u); }

// ---------------- fused CSR build (all 4 edge types) ----------------

__global__ void hist4_kernel(const int* d0, const int* d1, const int* d2, const int* d3,
                             int E0, int E1, int E2, int E3,
                             int b0, int b1, int b2, int b3, int* __restrict__ cnt) {
  int t = blockIdx.y;
  const int* d; int E, b;
  if (t == 0) { d = d0; E = E0; b = b0; }
  else if (t == 1) { d = d1; E = E1; b = b1; }
  else if (t == 2) { d = d2; E = E2; b = b2; }
  else { d = d3; E = E3; b = b3; }
  int i = blockIdx.x * 256 + threadIdx.x;
  if (i < E) atomicAdd(&cnt[b + d[i]], 1);
}

__global__ void exscan_kernel(const int* __restrict__ cnt, int* __restrict__ starts, int n) {
  __shared__ int wsum[16];
  __shared__ int wpre[16];
  __shared__ int tot_s;
  __shared__ int carry_s;
  int tid = threadIdx.x, lane = tid & 63, wv = tid >> 6;
  if (tid == 0) carry_s = 0;
  for (int base = 0; base < n; base += 1024) {
    __syncthreads();
    int carry = carry_s;
    int i = base + tid;
    int v = (i < n) ? cnt[i] : 0;
    int inc = v;
#pragma unroll
    for (int off = 1; off < 64; off <<= 1) {
      int t = __shfl_up(inc, off, 64);
      if (lane >= off) inc += t;
    }
    if (lane == 63) wsum[wv] = inc;
    __syncthreads();
    if (tid < 16) {
      int x = wsum[tid];
      int p = x;
#pragma unroll
      for (int off = 1; off < 16; off <<= 1) {
        int t = __shfl_up(p, off, 64);
        if (tid >= off) p += t;
      }
      wpre[tid] = p - x;
      if (tid == 15) tot_s = p;
    }
    __syncthreads();
    if (i < n) starts[i] = carry + wpre[wv] + (inc - v);
    if (tid == 0) carry_s = carry + tot_s;
  }
  __syncthreads();
  if (tid == 0) starts[n] = carry_s;
}

__global__ void scatter4_kernel(const int* s0p, const int* s1p, const int* s2p, const int* s3p,
                                const int* d0, const int* d1, const int* d2, const int* d3,
                                int E0, int E1, int E2, int E3,
                                int b0, int b1, int b2, int b3,
                                const int* __restrict__ starts, int* __restrict__ cur,
                                int* __restrict__ eidx_all) {
  int t = blockIdx.y;
  const int* sp; const int* d; int E, b;
  if (t == 0) { sp = s0p; d = d0; E = E0; b = b0; }
  else if (t == 1) { sp = s1p; d = d1; E = E1; b = b1; }
  else if (t == 2) { sp = s2p; d = d2; E = E2; b = b2; }
  else { sp = s3p; d = d3; E = E3; b = b3; }
  int i = blockIdx.x * 256 + threadIdx.x;
  if (i >= E) return;
  int dd = b + d[i];
  int p = starts[dd] + atomicAdd(&cur[dd], 1);
  eidx_all[p] = sp[i];
}

// ---------------- fp32 -> bf16 table copy ----------------

__global__ void tobf16_kernel(const float* __restrict__ in, unsigned* __restrict__ out, int n4) {
  int i = blockIdx.x * 256 + threadIdx.x;
  if (i >= n4) return;
  float4 v = ((const float4*)in)[i];
  uint2 r;
  r.x = f2bf(v.x) | (f2bf(v.y) << 16);
  r.y = f2bf(v.z) | (f2bf(v.w) << 16);
  ((uint2*)out)[i] = r;
}

// ---------------- weight prep: transpose (+optional sum) to bf16 [N][K] ----------------

struct WDesc { const float* s1; const float* s2; unsigned short* dst; int K; int lgN; };
struct WPack { WDesc d[14]; };

__global__ void wprep_kernel(WPack p) {
  WDesc w = p.d[blockIdx.x];
  int NN = 1 << w.lgN;
  int tot = w.K << w.lgN;
  for (int i = threadIdx.x; i < tot; i += 256) {
    int k = i >> w.lgN, n = i & (NN - 1);
    float v = w.s1[((size_t)k << w.lgN) + n];
    if (w.s2) v += w.s2[((size_t)k << w.lgN) + n];
    w.dst[(size_t)n * w.K + k] = (unsigned short)f2bf(v);
  }
}

// ---------------- gather-mean: one wave per dst, half-wave edge pairing ----------------
// D = row width in elements; rs = row stride in uints. OBF: bf16 output else fp32.

template <int D, int OBF>
__global__ __launch_bounds__(256) void gather_mean(
    const unsigned* __restrict__ xsrc, int rs,
    const int* __restrict__ eidx, const int* __restrict__ starts,
    int n_dst, void* __restrict__ aggv) {
  int w = blockIdx.x * 4 + (threadIdx.x >> 6);
  int lane = threadIdx.x & 63;
  if (w >= n_dst) return;
  int sub = lane >> 5, sl = lane & 31;
  int s0 = starts[w], s1 = starts[w + 1];
  int c = s1 - s0;
  float inv = 1.0f / (float)(c > 0 ? c : 1);

  if constexpr (D == 128) {
    const uint2* x2 = (const uint2*)xsrc;
    int rs2 = rs >> 1;
    float a0 = 0.f, a1 = 0.f, a2 = 0.f, a3 = 0.f;
    float b0 = 0.f, b1 = 0.f, b2 = 0.f, b3 = 0.f;
    int e = s0;
    for (; e + 8 <= s1; e += 8) {
      int i0 = eidx[e + sub];
      int i1 = eidx[e + 2 + sub];
      int i2 = eidx[e + 4 + sub];
      int i3 = eidx[e + 6 + sub];
      uint2 u0 = x2[(size_t)i0 * rs2 + sl];
      uint2 u1 = x2[(size_t)i1 * rs2 + sl];
      uint2 u2 = x2[(size_t)i2 * rs2 + sl];
      uint2 u3 = x2[(size_t)i3 * rs2 + sl];
      a0 += bflo(u0.x); a1 += bfhi(u0.x); a2 += bflo(u0.y); a3 += bfhi(u0.y);
      b0 += bflo(u1.x); b1 += bfhi(u1.x); b2 += bflo(u1.y); b3 += bfhi(u1.y);
      a0 += bflo(u2.x); a1 += bfhi(u2.x); a2 += bflo(u2.y); a3 += bfhi(u2.y);
      b0 += bflo(u3.x); b1 += bfhi(u3.x); b2 += bflo(u3.y); b3 += bfhi(u3.y);
    }
    for (; e + 2 <= s1; e += 2) {
      int i0 = eidx[e + sub];
      uint2 u0 = x2[(size_t)i0 * rs2 + sl];
      a0 += bflo(u0.x); a1 += bfhi(u0.x); a2 += bflo(u0.y); a3 += bfhi(u0.y);
    }
    if (e < s1 && sub == 0) {
      uint2 u0 = x2[(size_t)eidx[e] * rs2 + sl];
      a0 += bflo(u0.x); a1 += bfhi(u0.x); a2 += bflo(u0.y); a3 += bfhi(u0.y);
    }
    a0 += b0; a1 += b1; a2 += b2; a3 += b3;
    a0 += __shfl_xor(a0, 32);
    a1 += __shfl_xor(a1, 32);
    a2 += __shfl_xor(a2, 32);
    a3 += __shfl_xor(a3, 32);
    if (sub == 0) {
      a0 *= inv; a1 *= inv; a2 *= inv; a3 *= inv;
      if (OBF) {
        uint2 r;
        r.x = f2bf(a0) | (f2bf(a1) << 16);
        r.y = f2bf(a2) | (f2bf(a3) << 16);
        ((uint2*)aggv)[(size_t)w * 32 + sl] = r;
      } else {
        float4 r; r.x = a0; r.y = a1; r.z = a2; r.w = a3;
        ((float4*)aggv)[(size_t)w * 32 + sl] = r;
      }
    }
  } else {  // D == 64
    float a0 = 0.f, a1 = 0.f, b0 = 0.f, b1 = 0.f;
    int e = s0;
    for (; e + 8 <= s1; e += 8) {
      int i0 = eidx[e + sub];
      int i1 = eidx[e + 2 + sub];
      int i2 = eidx[e + 4 + sub];
      int i3 = eidx[e + 6 + sub];
      unsigned u0 = xsrc[(size_t)i0 * rs + sl];
      unsigned u1 = xsrc[(size_t)i1 * rs + sl];
      unsigned u2 = xsrc[(size_t)i2 * rs + sl];
      unsigned u3 = xsrc[(size_t)i3 * rs + sl];
      a0 += bflo(u0); a1 += bfhi(u0);
      b0 += bflo(u1); b1 += bfhi(u1);
      a0 += bflo(u2); a1 += bfhi(u2);
      b0 += bflo(u3); b1 += bfhi(u3);
    }
    for (; e + 2 <= s1; e += 2) {
      unsigned u0 = xsrc[(size_t)eidx[e + sub] * rs + sl];
      a0 += bflo(u0); a1 += bfhi(u0);
    }
    if (e < s1 && sub == 0) {
      unsigned u0 = xsrc[(size_t)eidx[e] * rs + sl];
      a0 += bflo(u0); a1 += bfhi(u0);
    }
    a0 += b0; a1 += b1;
    a0 += __shfl_xor(a0, 32);
    a1 += __shfl_xor(a1, 32);
    if (sub == 0) {
      a0 *= inv; a1 *= inv;
      if (OBF) {
        ((unsigned*)aggv)[(size_t)w * 32 + sl] = f2bf(a0) | (f2bf(a1) << 16);
      } else {
        float2 r; r.x = a0; r.y = a1;
        ((float2*)aggv)[(size_t)w * 32 + sl] = r;
      }
    }
  }
}

// ---------------- MFMA dense: out = act(sum_seg A_i @ W_i + b0 (+b1) + add0 (+add1)) ----------------
// 128 x (NT*32) tile, 4 waves (2x2), 16x16x32 bf16 MFMA, XOR-swizzled LDS.

struct SegB { const unsigned short* A; const unsigned short* Wt; int K; };

template <int NT>  // NT = n-frags per wave; N_TILE = NT*32 (64 or 128)
__global__ __launch_bounds__(256) void dense_mfma(
    SegB s0, SegB s1, SegB s2, int nseg,
    const float* __restrict__ bias0, const float* __restrict__ bias1,
    const float* __restrict__ add0, const float* __restrict__ add1,
    float* __restrict__ out_f32, unsigned short* __restrict__ out_bf16,
    int M, int ldo, int relu) {
  __shared__ unsigned short A_s[128 * 128];      // 128 rows x 256B, swizzled
  __shared__ unsigned short B_s[NT * 32 * 128];  // N_TILE rows x 256B (Wt rows = out cols)
  int tid = threadIdx.x;
  int lane = tid & 63, wid = tid >> 6;
  int wr = wid >> 1, wc = wid & 1;
  int m0 = blockIdx.x * 128;
  floatx4 acc[4][NT] = {};

  for (int sg = 0; sg < nseg; ++sg) {
    SegB s = (sg == 0) ? s0 : ((sg == 1) ? s1 : s2);
    const int K = s.K;
    const int lsh = (K == 128) ? 4 : 3;      // 16B slots per row
    const int slots = 1 << lsh;
    if (sg) __syncthreads();
    for (int c = tid; c < (128 << lsh); c += 256) {
      int row = c >> lsh, sl = c & (slots - 1);
      int gr = m0 + row; if (gr >= M) gr = M - 1;
      uint4 v = *(const uint4*)(s.A + (size_t)gr * K + sl * 8);
      *(uint4*)((char*)A_s + row * 256 + ((sl * 16) ^ ((row & 7) << 4))) = v;
    }
    for (int c = tid; c < ((NT * 32) << lsh); c += 256) {
      int row = c >> lsh, sl = c & (slots - 1);
      uint4 v = *(const uint4*)(s.Wt + (size_t)row * K + sl * 8);
      *(uint4*)((char*)B_s + row * 256 + ((sl * 16) ^ ((row & 7) << 4))) = v;
    }
    __syncthreads();
    const int nks = K >> 5;
    for (int ks = 0; ks < nks; ++ks) {
      int kb = ks * 64 + ((lane >> 4) << 4);  // byte offset of this lane's k-pack
      short8 a[4], b[NT];
#pragma unroll
      for (int fm = 0; fm < 4; ++fm) {
        int row = wr * 64 + fm * 16 + (lane & 15);
        a[fm] = *(const short8*)((const char*)A_s + row * 256 + (kb ^ ((row & 7) << 4)));
      }
#pragma unroll
      for (int fn = 0; fn < NT; ++fn) {
        int row = wc * (NT * 16) + fn * 16 + (lane & 15);
        b[fn] = *(const short8*)((const char*)B_s + row * 256 + (kb ^ ((row & 7) << 4)));
      }
#pragma unroll
      for (int fm = 0; fm < 4; ++fm)
#pragma unroll
        for (int fn = 0; fn < NT; ++fn)
          acc[fm][fn] = __builtin_amdgcn_mfma_f32_16x16x32_bf16(a[fm], b[fn], acc[fm][fn], 0, 0, 0);
    }
  }

  int lr = (lane >> 4) * 4, lc = lane & 15;
#pragma unroll
  for (int fm = 0; fm < 4; ++fm) {
#pragma unroll
    for (int i = 0; i < 4; ++i) {
      int grow = m0 + wr * 64 + fm * 16 + lr + i;
      if (grow >= M) continue;
#pragma unroll
      for (int fn = 0; fn < NT; ++fn) {
        int gcol = wc * (NT * 16) + fn * 16 + lc;
        float v = acc[fm][fn][i];
        if (bias0) v += bias0[gcol];
        if (bias1) v += bias1[gcol];
        size_t oidx = (size_t)grow * ldo + gcol;
        if (add0) v += add0[oidx];
        if (add1) v += add1[oidx];
        if (relu) v = fmaxf(v, 0.f);
        if (out_bf16) out_bf16[oidx] = (unsigned short)f2bf(v);
        else out_f32[oidx] = v;
      }
    }
  }
}

// ---------------- launch ----------------

extern "C" void kernel_launch(void* const* d_in, const int* in_sizes, int n_in,
                              void* d_out, int out_size, void* d_ws, size_t ws_size,
                              hipStream_t stream) {
  const float* x_user  = (const float*)d_in[0];
  const float* x_job   = (const float*)d_in[1];
  const float* x_skill = (const float*)d_in[2];

  const float* l1_uj_Wl = (const float*)d_in[3];
  const float* l1_uj_bl = (const float*)d_in[4];
  const float* l1_uj_Wr = (const float*)d_in[5];
  const float* l2_uj_Wl = (const float*)d_in[6];
  const float* l2_uj_bl = (const float*)d_in[7];
  const float* l2_uj_Wr = (const float*)d_in[8];

  const float* l1_ju_Wl = (const float*)d_in[9];
  const float* l1_ju_bl = (const float*)d_in[10];
  const float* l1_ju_Wr = (const float*)d_in[11];
  const float* l2_ju_Wl = (const float*)d_in[12];
  const float* l2_ju_bl = (const float*)d_in[13];
  const float* l2_ju_Wr = (const float*)d_in[14];

  const float* l1_js_Wl = (const float*)d_in[15];
  const float* l1_js_bl = (const float*)d_in[16];
  const float* l1_js_Wr = (const float*)d_in[17];
  const float* l2_js_Wl = (const float*)d_in[18];
  const float* l2_js_bl = (const float*)d_in[19];
  const float* l2_js_Wr = (const float*)d_in[20];

  const float* l1_sj_Wl = (const float*)d_in[21];
  const float* l1_sj_bl = (const float*)d_in[22];
  const float* l1_sj_Wr = (const float*)d_in[23];
  const float* l2_sj_Wl = (const float*)d_in[24];
  const float* l2_sj_bl = (const float*)d_in[25];
  const float* l2_sj_Wr = (const float*)d_in[26];

  const int* e1_src = (const int*)d_in[27];
  const int* e1_dst = (const int*)d_in[28];
  const int* e2_src = (const int*)d_in[29];
  const int* e2_dst = (const int*)d_in[30];
  const int* e3_src = (const int*)d_in[31];
  const int* e3_dst = (const int*)d_in[32];
  const int* e4_src = (const int*)d_in[33];
  const int* e4_dst = (const int*)d_in[34];

  const int N_U = in_sizes[0] / 128;
  const int N_J = in_sizes[1] / 128;
  const int N_S = in_sizes[2] / 64;
  const int E1 = in_sizes[27], E2 = in_sizes[29], E3 = in_sizes[31], E4 = in_sizes[33];
  const int Etot = E1 + E2 + E3 + E4;
  // cnt/starts layout: [e1 dst=job N_J][e2 dst=user N_U][e3 dst=skill N_S][e4 dst=job N_J]
  const int b1 = 0, b2 = N_J, b3 = N_J + N_U, b4 = N_J + N_U + N_S;
  const int ntot = b4 + N_J;

  char* wsp = (char*)d_ws;
  size_t off = 0;
  auto alloc = [&](size_t bytes) -> void* {
    void* p = wsp + off;
    off += (bytes + 255) & ~(size_t)255;
    return p;
  };

  int* cnt_all    = (int*)alloc((size_t)ntot * 4);        // also reused as cur
  int* starts_all = (int*)alloc((size_t)(ntot + 1) * 4);
  int* eidx_all   = (int*)alloc((size_t)Etot * 4);

  unsigned* xu_bf = (unsigned*)alloc((size_t)N_U * 128 * 2);
  unsigned* xj_bf = (unsigned*)alloc((size_t)N_J * 128 * 2);
  unsigned* xs_bf = (unsigned*)alloc((size_t)N_S * 64 * 2);

  unsigned short* aggA_bf = (unsigned short*)alloc((size_t)N_U * 128 * 2);
  unsigned short* aggB_bf = (unsigned short*)alloc((size_t)N_J * 128 * 2);
  unsigned short* aggC_bf = (unsigned short*)alloc((size_t)N_J * 64 * 2);
  unsigned short* aggD_bf = (unsigned short*)alloc((size_t)N_S * 128 * 2);

  unsigned short* h_u = (unsigned short*)alloc((size_t)N_U * 128 * 2);
  unsigned short* h_j = (unsigned short*)alloc((size_t)N_J * 128 * 2);
  unsigned short* h_s = (unsigned short*)alloc((size_t)N_S * 128 * 2);

  unsigned short* t_uj = (unsigned short*)alloc((size_t)N_U * 64 * 2);
  unsigned short* t_jx = (unsigned short*)alloc((size_t)N_J * 128 * 2);  // [t_ju | t_js]
  unsigned short* t_sj = (unsigned short*)alloc((size_t)N_S * 64 * 2);

  float* aggA_f = (float*)alloc((size_t)N_U * 64 * 4);
  float* aggB_f = (float*)alloc((size_t)N_J * 64 * 4);
  float* aggC_f = (float*)alloc((size_t)N_J * 64 * 4);
  float* aggD_f = (float*)alloc((size_t)N_S * 64 * 4);

  auto walloc = [&](int n, int k) { return (unsigned short*)alloc((size_t)n * k * 2); };
  unsigned short* wt_l1juWl = walloc(128, 128);
  unsigned short* wt_l1juWr = walloc(128, 128);
  unsigned short* wt_l1ujWl = walloc(128, 128);
  unsigned short* wt_l1sjWl = walloc(128, 64);
  unsigned short* wt_wr1sum = walloc(128, 128);
  unsigned short* wt_l1jsWl = walloc(128, 128);
  unsigned short* wt_l1jsWr = walloc(128, 64);
  unsigned short* wt_l2ujWl = walloc(64, 128);
  unsigned short* wt_tjx    = walloc(128, 128);
  unsigned short* wt_l2sjWl = walloc(64, 128);
  unsigned short* wt_l2juWr = walloc(64, 128);
  unsigned short* wt_wr2sum = walloc(64, 128);
  unsigned short* wt_l2jsWr = walloc(64, 128);

  float* o_u = (float*)d_out;
  float* o_j = o_u + (size_t)N_U * 64;
  float* o_s = o_j + (size_t)N_J * 64;

  // ---- CSR build (fused) ----
  const int maxE = 800000;
  hipMemsetAsync(cnt_all, 0, (size_t)ntot * 4, stream);
  hist4_kernel<<<dim3((maxE + 255) / 256, 4), 256, 0, stream>>>(
      e1_dst, e2_dst, e3_dst, e4_dst, E1, E2, E3, E4, b1, b2, b3, b4, cnt_all);
  exscan_kernel<<<1, 1024, 0, stream>>>(cnt_all, starts_all, ntot);
  hipMemsetAsync(cnt_all, 0, (size_t)ntot * 4, stream);
  scatter4_kernel<<<dim3((maxE + 255) / 256, 4), 256, 0, stream>>>(
      e1_src, e2_src, e3_src, e4_src, e1_dst, e2_dst, e3_dst, e4_dst,
      E1, E2, E3, E4, b1, b2, b3, b4, starts_all, cnt_all, eidx_all);

  // ---- bf16 feature tables + bf16 transposed weights ----
  tobf16_kernel<<<(N_U * 32 + 255) / 256, 256, 0, stream>>>(x_user, xu_bf, N_U * 32);
  tobf16_kernel<<<(N_J * 32 + 255) / 256, 256, 0, stream>>>(x_job, xj_bf, N_J * 32);
  tobf16_kernel<<<(N_S * 16 + 255) / 256, 256, 0, stream>>>(x_skill, xs_bf, N_S * 16);

  WPack wp;
  wp.d[0]  = {l1_ju_Wl, nullptr,   wt_l1juWl, 128, 7};
  wp.d[1]  = {l1_ju_Wr, nullptr,   wt_l1juWr, 128, 7};
  wp.d[2]  = {l1_uj_Wl, nullptr,   wt_l1ujWl, 128, 7};
  wp.d[3]  = {l1_sj_Wl, nullptr,   wt_l1sjWl, 64,  7};
  wp.d[4]  = {l1_uj_Wr, l1_sj_Wr,  wt_wr1sum, 128, 7};
  wp.d[5]  = {l1_js_Wl, nullptr,   wt_l1jsWl, 128, 7};
  wp.d[6]  = {l1_js_Wr, nullptr,   wt_l1jsWr, 64,  7};
  wp.d[7]  = {l2_uj_Wl, nullptr,   wt_l2ujWl, 128, 6};
  wp.d[8]  = {l2_ju_Wl, nullptr,   wt_tjx,             128, 6};  // t_jx cols 0-63
  wp.d[9]  = {l2_js_Wl, nullptr,   wt_tjx + 64 * 128,  128, 6};  // t_jx cols 64-127
  wp.d[10] = {l2_sj_Wl, nullptr,   wt_l2sjWl, 128, 6};
  wp.d[11] = {l2_ju_Wr, nullptr,   wt_l2juWr, 128, 6};
  wp.d[12] = {l2_uj_Wr, l2_sj_Wr,  wt_wr2sum, 128, 6};
  wp.d[13] = {l2_js_Wr, nullptr,   wt_l2jsWr, 128, 6};
  wprep_kernel<<<14, 256, 0, stream>>>(wp);

  // ---- layer 1 gathers (bf16 in, bf16 out) ----
  gather_mean<128, 1><<<(N_J + 3) / 4, 256, 0, stream>>>(xu_bf, 64, eidx_all, starts_all + b1, N_J, aggB_bf);
  gather_mean<128, 1><<<(N_U + 3) / 4, 256, 0, stream>>>(xj_bf, 64, eidx_all, starts_all + b2, N_U, aggA_bf);
  gather_mean<128, 1><<<(N_S + 3) / 4, 256, 0, stream>>>(xj_bf, 64, eidx_all, starts_all + b3, N_S, aggD_bf);
  gather_mean<64, 1><<<(N_J + 3) / 4, 256, 0, stream>>>(xs_bf, 32, eidx_all, starts_all + b4, N_J, aggC_bf);

  SegB z{nullptr, nullptr, 0};

  // ---- layer 1 dense (+ReLU), N=128, bf16 out ----
  dense_mfma<4><<<(N_U + 127) / 128, 256, 0, stream>>>(
      SegB{aggA_bf, wt_l1juWl, 128}, SegB{(const unsigned short*)xu_bf, wt_l1juWr, 128}, z, 2,
      l1_ju_bl, nullptr, nullptr, nullptr, nullptr, h_u, N_U, 128, 1);
  dense_mfma<4><<<(N_J + 127) / 128, 256, 0, stream>>>(
      SegB{aggB_bf, wt_l1ujWl, 128}, SegB{aggC_bf, wt_l1sjWl, 64},
      SegB{(const unsigned short*)xj_bf, wt_wr1sum, 128}, 3,
      l1_uj_bl, l1_sj_bl, nullptr, nullptr, nullptr, h_j, N_J, 128, 1);
  dense_mfma<4><<<(N_S + 127) / 128, 256, 0, stream>>>(
      SegB{aggD_bf, wt_l1jsWl, 128}, SegB{(const unsigned short*)xs_bf, wt_l1jsWr, 64}, z, 2,
      l1_js_bl, nullptr, nullptr, nullptr, nullptr, h_s, N_S, 128, 1);

  // ---- layer 2 transforms (bf16 out) ----
  dense_mfma<2><<<(N_U + 127) / 128, 256, 0, stream>>>(
      SegB{h_u, wt_l2ujWl, 128}, z, z, 1,
      nullptr, nullptr, nullptr, nullptr, nullptr, t_uj, N_U, 64, 0);
  dense_mfma<4><<<(N_J + 127) / 128, 256, 0, stream>>>(
      SegB{h_j, wt_tjx, 128}, z, z, 1,
      nullptr, nullptr, nullptr, nullptr, nullptr, t_jx, N_J, 128, 0);
  dense_mfma<2><<<(N_S + 127) / 128, 256, 0, stream>>>(
      SegB{h_s, wt_l2sjWl, 128}, z, z, 1,
      nullptr, nullptr, nullptr, nullptr, nullptr, t_sj, N_S, 64, 0);

  // ---- layer 2 gathers (bf16 in, fp32 out) ----
  gather_mean<64, 0><<<(N_J + 3) / 4, 256, 0, stream>>>((const unsigned*)t_uj, 32, eidx_all, starts_all + b1, N_J, aggB_f);
  gather_mean<64, 0><<<(N_U + 3) / 4, 256, 0, stream>>>((const unsigned*)t_jx, 64, eidx_all, starts_all + b2, N_U, aggA_f);
  gather_mean<64, 0><<<(N_S + 3) / 4, 256, 0, stream>>>((const unsigned*)t_jx + 32, 64, eidx_all, starts_all + b3, N_S, aggD_f);
  gather_mean<64, 0><<<(N_J + 3) / 4, 256, 0, stream>>>((const unsigned*)t_sj, 32, eidx_all, starts_all + b4, N_J, aggC_f);

  // ---- layer 2 final dense (fp32 out to d_out) ----
  dense_mfma<2><<<(N_U + 127) / 128, 256, 0, stream>>>(
      SegB{h_u, wt_l2juWr, 128}, z, z, 1,
      l2_ju_bl, nullptr, aggA_f, nullptr, o_u, nullptr, N_U, 64, 0);
  dense_mfma<2><<<(N_J + 127) / 128, 256, 0, stream>>>(
      SegB{h_j, wt_wr2sum, 128}, z, z, 1,
      l2_uj_bl, l2_sj_bl, aggB_f, aggC_f, o_j, nullptr, N_J, 64, 0);
  dense_mfma<2><<<(N_S + 127) / 128, 256, 0, stream>>>(
      SegB{h_s, wt_l2jsWr, 128}, z, z, 1,
      l2_js_bl, nullptr, aggD_f, nullptr, o_s, nullptr, N_S, 64, 0);
}

// Round 6
// 624.801 us; speedup vs baseline: 1.6222x; 1.0916x over previous
//
#include <hip/hip_runtime.h>

typedef short short8 __attribute__((ext_vector_type(8)));
typedef float floatx4 __attribute__((ext_vector_type(4)));

__device__ __forceinline__ unsigned f2bf(float f) {
  unsigned u = __builtin_bit_cast(unsigned, f);
  return (u + 0x7fffu + ((u >> 16) & 1u)) >> 16;
}
__device__ __forceinline__ float bflo(unsigned u) { return __builtin_bit_cast(float, u << 16); }
__device__ __forceinline__ float bfhi(unsigned u) { return __builtin_bit_cast(float, u & 0xffff0000u); }

// ---------------- fused CSR build (all 4 edge types) ----------------

__global__ void hist4_kernel(const int* d0, const int* d1, const int* d2, const int* d3,
                             int E0, int E1, int E2, int E3,
                             int b0, int b1, int b2, int b3, int* __restrict__ cnt) {
  int t = blockIdx.y;
  const int* d; int E, b;
  if (t == 0) { d = d0; E = E0; b = b0; }
  else if (t == 1) { d = d1; E = E1; b = b1; }
  else if (t == 2) { d = d2; E = E2; b = b2; }
  else { d = d3; E = E3; b = b3; }
  int i = blockIdx.x * 256 + threadIdx.x;
  if (i < E) atomicAdd(&cnt[b + d[i]], 1);
}

__global__ void exscan_kernel(const int* __restrict__ cnt, int* __restrict__ starts, int n) {
  __shared__ int wsum[16];
  __shared__ int wpre[16];
  __shared__ int tot_s;
  __shared__ int carry_s;
  int tid = threadIdx.x, lane = tid & 63, wv = tid >> 6;
  if (tid == 0) carry_s = 0;
  for (int base = 0; base < n; base += 1024) {
    __syncthreads();
    int carry = carry_s;
    int i = base + tid;
    int v = (i < n) ? cnt[i] : 0;
    int inc = v;
#pragma unroll
    for (int off = 1; off < 64; off <<= 1) {
      int t = __shfl_up(inc, off, 64);
      if (lane >= off) inc += t;
    }
    if (lane == 63) wsum[wv] = inc;
    __syncthreads();
    if (tid < 16) {
      int x = wsum[tid];
      int p = x;
#pragma unroll
      for (int off = 1; off < 16; off <<= 1) {
        int t = __shfl_up(p, off, 64);
        if (tid >= off) p += t;
      }
      wpre[tid] = p - x;
      if (tid == 15) tot_s = p;
    }
    __syncthreads();
    if (i < n) starts[i] = carry + wpre[wv] + (inc - v);
    if (tid == 0) carry_s = carry + tot_s;
  }
  __syncthreads();
  if (tid == 0) starts[n] = carry_s;
}

__global__ void scatter4_kernel(const int* s0p, const int* s1p, const int* s2p, const int* s3p,
                                const int* d0, const int* d1, const int* d2, const int* d3,
                                int E0, int E1, int E2, int E3,
                                int b0, int b1, int b2, int b3,
                                const int* __restrict__ starts, int* __restrict__ cur,
                                unsigned short* __restrict__ eidx_all) {
  int t = blockIdx.y;
  const int* sp; const int* d; int E, b;
  if (t == 0) { sp = s0p; d = d0; E = E0; b = b0; }
  else if (t == 1) { sp = s1p; d = d1; E = E1; b = b1; }
  else if (t == 2) { sp = s2p; d = d2; E = E2; b = b2; }
  else { sp = s3p; d = d3; E = E3; b = b3; }
  int i = blockIdx.x * 256 + threadIdx.x;
  if (i >= E) return;
  int dd = b + d[i];
  int p = starts[dd] + atomicAdd(&cur[dd], 1);
  eidx_all[p] = (unsigned short)sp[i];
}

// ---------------- fp32 -> bf16 table copies (fused x3) ----------------

struct CTask { const float* in; unsigned* out; int n4; };

__global__ void tobf16x3_kernel(CTask t0, CTask t1, CTask t2) {
  CTask t = (blockIdx.y == 0) ? t0 : ((blockIdx.y == 1) ? t1 : t2);
  int i = blockIdx.x * 256 + threadIdx.x;
  if (i >= t.n4) return;
  float4 v = ((const float4*)t.in)[i];
  uint2 r;
  r.x = f2bf(v.x) | (f2bf(v.y) << 16);
  r.y = f2bf(v.z) | (f2bf(v.w) << 16);
  ((uint2*)t.out)[i] = r;
}

// ---------------- weight prep: transpose (+optional sum) to bf16 [N][K] ----------------

struct WDesc { const float* s1; const float* s2; unsigned short* dst; int K; int lgN; };
struct WPack { WDesc d[14]; };

__global__ void wprep_kernel(WPack p) {
  WDesc w = p.d[blockIdx.x];
  int NN = 1 << w.lgN;
  int tot = w.K << w.lgN;
  for (int i = threadIdx.x + 256 * blockIdx.y; i < tot; i += 256 * 8) {
    int k = i >> w.lgN, n = i & (NN - 1);
    float v = w.s1[((size_t)k << w.lgN) + n];
    if (w.s2) v += w.s2[((size_t)k << w.lgN) + n];
    w.dst[(size_t)n * w.K + k] = (unsigned short)f2bf(v);
  }
}

// ---------------- fused gather-mean (4 tasks / dispatch): one wave per dst ----------------
// 16-edge unroll -> 8 independent row loads in flight. u16 edge indices.

struct GTask { const unsigned* src; int rs; const int* starts; int n_dst; void* out; int d128; int blk0; };

template <int OBF>
__global__ __launch_bounds__(256) void gather4(GTask t0, GTask t1, GTask t2, GTask t3,
                                               const unsigned short* __restrict__ eidx) {
  GTask t;
  int bx = blockIdx.x;
  if (bx >= t3.blk0) t = t3;
  else if (bx >= t2.blk0) t = t2;
  else if (bx >= t1.blk0) t = t1;
  else t = t0;
  int w = (bx - t.blk0) * 4 + (threadIdx.x >> 6);
  if (w >= t.n_dst) return;
  int lane = threadIdx.x & 63;
  int sub = lane >> 5, sl = lane & 31;
  int s0 = t.starts[w], s1 = t.starts[w + 1];
  int c = s1 - s0;
  float inv = 1.0f / (float)(c > 0 ? c : 1);

  if (t.d128) {
    const uint2* x2 = (const uint2*)t.src;
    int rs2 = t.rs >> 1;
    float a0 = 0.f, a1 = 0.f, a2 = 0.f, a3 = 0.f;
    float b0 = 0.f, b1 = 0.f, b2 = 0.f, b3 = 0.f;
    int e = s0;
    for (; e + 16 <= s1; e += 16) {
      int i0 = eidx[e + sub];
      int i1 = eidx[e + 2 + sub];
      int i2 = eidx[e + 4 + sub];
      int i3 = eidx[e + 6 + sub];
      int i4 = eidx[e + 8 + sub];
      int i5 = eidx[e + 10 + sub];
      int i6 = eidx[e + 12 + sub];
      int i7 = eidx[e + 14 + sub];
      uint2 u0 = x2[(size_t)i0 * rs2 + sl];
      uint2 u1 = x2[(size_t)i1 * rs2 + sl];
      uint2 u2 = x2[(size_t)i2 * rs2 + sl];
      uint2 u3 = x2[(size_t)i3 * rs2 + sl];
      uint2 u4 = x2[(size_t)i4 * rs2 + sl];
      uint2 u5 = x2[(size_t)i5 * rs2 + sl];
      uint2 u6 = x2[(size_t)i6 * rs2 + sl];
      uint2 u7 = x2[(size_t)i7 * rs2 + sl];
      a0 += bflo(u0.x); a1 += bfhi(u0.x); a2 += bflo(u0.y); a3 += bfhi(u0.y);
      b0 += bflo(u1.x); b1 += bfhi(u1.x); b2 += bflo(u1.y); b3 += bfhi(u1.y);
      a0 += bflo(u2.x); a1 += bfhi(u2.x); a2 += bflo(u2.y); a3 += bfhi(u2.y);
      b0 += bflo(u3.x); b1 += bfhi(u3.x); b2 += bflo(u3.y); b3 += bfhi(u3.y);
      a0 += bflo(u4.x); a1 += bfhi(u4.x); a2 += bflo(u4.y); a3 += bfhi(u4.y);
      b0 += bflo(u5.x); b1 += bfhi(u5.x); b2 += bflo(u5.y); b3 += bfhi(u5.y);
      a0 += bflo(u6.x); a1 += bfhi(u6.x); a2 += bflo(u6.y); a3 += bfhi(u6.y);
      b0 += bflo(u7.x); b1 += bfhi(u7.x); b2 += bflo(u7.y); b3 += bfhi(u7.y);
    }
    for (; e + 2 <= s1; e += 2) {
      int i0 = eidx[e + sub];
      uint2 u0 = x2[(size_t)i0 * rs2 + sl];
      a0 += bflo(u0.x); a1 += bfhi(u0.x); a2 += bflo(u0.y); a3 += bfhi(u0.y);
    }
    if (e < s1 && sub == 0) {
      uint2 u0 = x2[(size_t)eidx[e] * rs2 + sl];
      a0 += bflo(u0.x); a1 += bfhi(u0.x); a2 += bflo(u0.y); a3 += bfhi(u0.y);
    }
    a0 += b0; a1 += b1; a2 += b2; a3 += b3;
    a0 += __shfl_xor(a0, 32);
    a1 += __shfl_xor(a1, 32);
    a2 += __shfl_xor(a2, 32);
    a3 += __shfl_xor(a3, 32);
    if (sub == 0) {
      a0 *= inv; a1 *= inv; a2 *= inv; a3 *= inv;
      if (OBF) {
        uint2 r;
        r.x = f2bf(a0) | (f2bf(a1) << 16);
        r.y = f2bf(a2) | (f2bf(a3) << 16);
        ((uint2*)t.out)[(size_t)w * 32 + sl] = r;
      } else {
        float4 r; r.x = a0; r.y = a1; r.z = a2; r.w = a3;
        ((float4*)t.out)[(size_t)w * 32 + sl] = r;
      }
    }
  } else {  // D == 64
    const unsigned* xs = t.src;
    int rs = t.rs;
    float a0 = 0.f, a1 = 0.f, b0 = 0.f, b1 = 0.f;
    int e = s0;
    for (; e + 16 <= s1; e += 16) {
      int i0 = eidx[e + sub];
      int i1 = eidx[e + 2 + sub];
      int i2 = eidx[e + 4 + sub];
      int i3 = eidx[e + 6 + sub];
      int i4 = eidx[e + 8 + sub];
      int i5 = eidx[e + 10 + sub];
      int i6 = eidx[e + 12 + sub];
      int i7 = eidx[e + 14 + sub];
      unsigned u0 = xs[(size_t)i0 * rs + sl];
      unsigned u1 = xs[(size_t)i1 * rs + sl];
      unsigned u2 = xs[(size_t)i2 * rs + sl];
      unsigned u3 = xs[(size_t)i3 * rs + sl];
      unsigned u4 = xs[(size_t)i4 * rs + sl];
      unsigned u5 = xs[(size_t)i5 * rs + sl];
      unsigned u6 = xs[(size_t)i6 * rs + sl];
      unsigned u7 = xs[(size_t)i7 * rs + sl];
      a0 += bflo(u0); a1 += bfhi(u0);
      b0 += bflo(u1); b1 += bfhi(u1);
      a0 += bflo(u2); a1 += bfhi(u2);
      b0 += bflo(u3); b1 += bfhi(u3);
      a0 += bflo(u4); a1 += bfhi(u4);
      b0 += bflo(u5); b1 += bfhi(u5);
      a0 += bflo(u6); a1 += bfhi(u6);
      b0 += bflo(u7); b1 += bfhi(u7);
    }
    for (; e + 2 <= s1; e += 2) {
      unsigned u0 = xs[(size_t)eidx[e + sub] * rs + sl];
      a0 += bflo(u0); a1 += bfhi(u0);
    }
    if (e < s1 && sub == 0) {
      unsigned u0 = xs[(size_t)eidx[e] * rs + sl];
      a0 += bflo(u0); a1 += bfhi(u0);
    }
    a0 += b0; a1 += b1;
    a0 += __shfl_xor(a0, 32);
    a1 += __shfl_xor(a1, 32);
    if (sub == 0) {
      a0 *= inv; a1 *= inv;
      if (OBF) {
        ((unsigned*)t.out)[(size_t)w * 32 + sl] = f2bf(a0) | (f2bf(a1) << 16);
      } else {
        float2 r; r.x = a0; r.y = a1;
        ((float2*)t.out)[(size_t)w * 32 + sl] = r;
      }
    }
  }
}

// ---------------- MFMA dense: out = act(sum_seg A_i @ W_i + b0 (+b1) + add0 (+add1)) ----------------

struct SegB { const unsigned short* A; const unsigned short* Wt; int K; };

template <int NT>  // NT = n-frags per wave; N_TILE = NT*32 (64 or 128)
__global__ __launch_bounds__(256) void dense_mfma(
    SegB s0, SegB s1, SegB s2, int nseg,
    const float* __restrict__ bias0, const float* __restrict__ bias1,
    const float* __restrict__ add0, const float* __restrict__ add1,
    float* __restrict__ out_f32, unsigned short* __restrict__ out_bf16,
    int M, int ldo, int relu) {
  __shared__ unsigned short A_s[128 * 128];      // 128 rows x 256B, swizzled
  __shared__ unsigned short B_s[NT * 32 * 128];  // N_TILE rows x 256B (Wt rows = out cols)
  int tid = threadIdx.x;
  int lane = tid & 63, wid = tid >> 6;
  int wr = wid >> 1, wc = wid & 1;
  int m0 = blockIdx.x * 128;
  floatx4 acc[4][NT] = {};

  for (int sg = 0; sg < nseg; ++sg) {
    SegB s = (sg == 0) ? s0 : ((sg == 1) ? s1 : s2);
    const int K = s.K;
    const int lsh = (K == 128) ? 4 : 3;      // 16B slots per row
    const int slots = 1 << lsh;
    if (sg) __syncthreads();
    for (int c = tid; c < (128 << lsh); c += 256) {
      int row = c >> lsh, sl = c & (slots - 1);
      int gr = m0 + row; if (gr >= M) gr = M - 1;
      uint4 v = *(const uint4*)(s.A + (size_t)gr * K + sl * 8);
      *(uint4*)((char*)A_s + row * 256 + ((sl * 16) ^ ((row & 7) << 4))) = v;
    }
    for (int c = tid; c < ((NT * 32) << lsh); c += 256) {
      int row = c >> lsh, sl = c & (slots - 1);
      uint4 v = *(const uint4*)(s.Wt + (size_t)row * K + sl * 8);
      *(uint4*)((char*)B_s + row * 256 + ((sl * 16) ^ ((row & 7) << 4))) = v;
    }
    __syncthreads();
    const int nks = K >> 5;
    for (int ks = 0; ks < nks; ++ks) {
      int kb = ks * 64 + ((lane >> 4) << 4);
      short8 a[4], b[NT];
#pragma unroll
      for (int fm = 0; fm < 4; ++fm) {
        int row = wr * 64 + fm * 16 + (lane & 15);
        a[fm] = *(const short8*)((const char*)A_s + row * 256 + (kb ^ ((row & 7) << 4)));
      }
#pragma unroll
      for (int fn = 0; fn < NT; ++fn) {
        int row = wc * (NT * 16) + fn * 16 + (lane & 15);
        b[fn] = *(const short8*)((const char*)B_s + row * 256 + (kb ^ ((row & 7) << 4)));
      }
#pragma unroll
      for (int fm = 0; fm < 4; ++fm)
#pragma unroll
        for (int fn = 0; fn < NT; ++fn)
          acc[fm][fn] = __builtin_amdgcn_mfma_f32_16x16x32_bf16(a[fm], b[fn], acc[fm][fn], 0, 0, 0);
    }
  }

  int lr = (lane >> 4) * 4, lc = lane & 15;
#pragma unroll
  for (int fm = 0; fm < 4; ++fm) {
#pragma unroll
    for (int i = 0; i < 4; ++i) {
      int grow = m0 + wr * 64 + fm * 16 + lr + i;
      if (grow >= M) continue;
#pragma unroll
      for (int fn = 0; fn < NT; ++fn) {
        int gcol = wc * (NT * 16) + fn * 16 + lc;
        float v = acc[fm][fn][i];
        if (bias0) v += bias0[gcol];
        if (bias1) v += bias1[gcol];
        size_t oidx = (size_t)grow * ldo + gcol;
        if (add0) v += add0[oidx];
        if (add1) v += add1[oidx];
        if (relu) v = fmaxf(v, 0.f);
        if (out_bf16) out_bf16[oidx] = (unsigned short)f2bf(v);
        else out_f32[oidx] = v;
      }
    }
  }
}

// ---------------- launch ----------------

extern "C" void kernel_launch(void* const* d_in, const int* in_sizes, int n_in,
                              void* d_out, int out_size, void* d_ws, size_t ws_size,
                              hipStream_t stream) {
  const float* x_user  = (const float*)d_in[0];
  const float* x_job   = (const float*)d_in[1];
  const float* x_skill = (const float*)d_in[2];

  const float* l1_uj_Wl = (const float*)d_in[3];
  const float* l1_uj_bl = (const float*)d_in[4];
  const float* l1_uj_Wr = (const float*)d_in[5];
  const float* l2_uj_Wl = (const float*)d_in[6];
  const float* l2_uj_bl = (const float*)d_in[7];
  const float* l2_uj_Wr = (const float*)d_in[8];

  const float* l1_ju_Wl = (const float*)d_in[9];
  const float* l1_ju_bl = (const float*)d_in[10];
  const float* l1_ju_Wr = (const float*)d_in[11];
  const float* l2_ju_Wl = (const float*)d_in[12];
  const float* l2_ju_bl = (const float*)d_in[13];
  const float* l2_ju_Wr = (const float*)d_in[14];

  const float* l1_js_Wl = (const float*)d_in[15];
  const float* l1_js_bl = (const float*)d_in[16];
  const float* l1_js_Wr = (const float*)d_in[17];
  const float* l2_js_Wl = (const float*)d_in[18];
  const float* l2_js_bl = (const float*)d_in[19];
  const float* l2_js_Wr = (const float*)d_in[20];

  const float* l1_sj_Wl = (const float*)d_in[21];
  const float* l1_sj_bl = (const float*)d_in[22];
  const float* l1_sj_Wr = (const float*)d_in[23];
  const float* l2_sj_Wl = (const float*)d_in[24];
  const float* l2_sj_bl = (const float*)d_in[25];
  const float* l2_sj_Wr = (const float*)d_in[26];

  const int* e1_src = (const int*)d_in[27];
  const int* e1_dst = (const int*)d_in[28];
  const int* e2_src = (const int*)d_in[29];
  const int* e2_dst = (const int*)d_in[30];
  const int* e3_src = (const int*)d_in[31];
  const int* e3_dst = (const int*)d_in[32];
  const int* e4_src = (const int*)d_in[33];
  const int* e4_dst = (const int*)d_in[34];

  const int N_U = in_sizes[0] / 128;
  const int N_J = in_sizes[1] / 128;
  const int N_S = in_sizes[2] / 64;
  const int E1 = in_sizes[27], E2 = in_sizes[29], E3 = in_sizes[31], E4 = in_sizes[33];
  const int Etot = E1 + E2 + E3 + E4;
  // cnt/starts layout: [e1 dst=job N_J][e2 dst=user N_U][e3 dst=skill N_S][e4 dst=job N_J]
  const int b1 = 0, b2 = N_J, b3 = N_J + N_U, b4 = N_J + N_U + N_S;
  const int ntot = b4 + N_J;

  char* wsp = (char*)d_ws;
  size_t off = 0;
  auto alloc = [&](size_t bytes) -> void* {
    void* p = wsp + off;
    off += (bytes + 255) & ~(size_t)255;
    return p;
  };

  int* cnt_all    = (int*)alloc((size_t)ntot * 4);        // also reused as cur
  int* starts_all = (int*)alloc((size_t)(ntot + 1) * 4);
  unsigned short* eidx_all = (unsigned short*)alloc((size_t)Etot * 2);

  unsigned* xu_bf = (unsigned*)alloc((size_t)N_U * 128 * 2);
  unsigned* xj_bf = (unsigned*)alloc((size_t)N_J * 128 * 2);
  unsigned* xs_bf = (unsigned*)alloc((size_t)N_S * 64 * 2);

  unsigned short* aggA_bf = (unsigned short*)alloc((size_t)N_U * 128 * 2);
  unsigned short* aggB_bf = (unsigned short*)alloc((size_t)N_J * 128 * 2);
  unsigned short* aggC_bf = (unsigned short*)alloc((size_t)N_J * 64 * 2);
  unsigned short* aggD_bf = (unsigned short*)alloc((size_t)N_S * 128 * 2);

  unsigned short* h_u = (unsigned short*)alloc((size_t)N_U * 128 * 2);
  unsigned short* h_j = (unsigned short*)alloc((size_t)N_J * 128 * 2);
  unsigned short* h_s = (unsigned short*)alloc((size_t)N_S * 128 * 2);

  unsigned short* t_uj = (unsigned short*)alloc((size_t)N_U * 64 * 2);
  unsigned short* t_jx = (unsigned short*)alloc((size_t)N_J * 128 * 2);  // [t_ju | t_js]
  unsigned short* t_sj = (unsigned short*)alloc((size_t)N_S * 64 * 2);

  float* aggA_f = (float*)alloc((size_t)N_U * 64 * 4);
  float* aggB_f = (float*)alloc((size_t)N_J * 64 * 4);
  float* aggC_f = (float*)alloc((size_t)N_J * 64 * 4);
  float* aggD_f = (float*)alloc((size_t)N_S * 64 * 4);

  auto walloc = [&](int n, int k) { return (unsigned short*)alloc((size_t)n * k * 2); };
  unsigned short* wt_l1juWl = walloc(128, 128);
  unsigned short* wt_l1juWr = walloc(128, 128);
  unsigned short* wt_l1ujWl = walloc(128, 128);
  unsigned short* wt_l1sjWl = walloc(128, 64);
  unsigned short* wt_wr1sum = walloc(128, 128);
  unsigned short* wt_l1jsWl = walloc(128, 128);
  unsigned short* wt_l1jsWr = walloc(128, 64);
  unsigned short* wt_l2ujWl = walloc(64, 128);
  unsigned short* wt_tjx    = walloc(128, 128);
  unsigned short* wt_l2sjWl = walloc(64, 128);
  unsigned short* wt_l2juWr = walloc(64, 128);
  unsigned short* wt_wr2sum = walloc(64, 128);
  unsigned short* wt_l2jsWr = walloc(64, 128);

  float* o_u = (float*)d_out;
  float* o_j = o_u + (size_t)N_U * 64;
  float* o_s = o_j + (size_t)N_J * 64;

  // ---- CSR build (fused, u16 edge indices) ----
  const int maxE = 800000;
  hipMemsetAsync(cnt_all, 0, (size_t)ntot * 4, stream);
  hist4_kernel<<<dim3((maxE + 255) / 256, 4), 256, 0, stream>>>(
      e1_dst, e2_dst, e3_dst, e4_dst, E1, E2, E3, E4, b1, b2, b3, b4, cnt_all);
  exscan_kernel<<<1, 1024, 0, stream>>>(cnt_all, starts_all, ntot);
  hipMemsetAsync(cnt_all, 0, (size_t)ntot * 4, stream);
  scatter4_kernel<<<dim3((maxE + 255) / 256, 4), 256, 0, stream>>>(
      e1_src, e2_src, e3_src, e4_src, e1_dst, e2_dst, e3_dst, e4_dst,
      E1, E2, E3, E4, b1, b2, b3, b4, starts_all, cnt_all, eidx_all);

  // ---- bf16 feature tables + bf16 transposed weights ----
  {
    CTask c0{x_user, xu_bf, N_U * 32};
    CTask c1{x_job, xj_bf, N_J * 32};
    CTask c2{x_skill, xs_bf, N_S * 16};
    int mx = c0.n4 > c1.n4 ? c0.n4 : c1.n4;
    if (c2.n4 > mx) mx = c2.n4;
    tobf16x3_kernel<<<dim3((mx + 255) / 256, 3), 256, 0, stream>>>(c0, c1, c2);
  }

  WPack wp;
  wp.d[0]  = {l1_ju_Wl, nullptr,   wt_l1juWl, 128, 7};
  wp.d[1]  = {l1_ju_Wr, nullptr,   wt_l1juWr, 128, 7};
  wp.d[2]  = {l1_uj_Wl, nullptr,   wt_l1ujWl, 128, 7};
  wp.d[3]  = {l1_sj_Wl, nullptr,   wt_l1sjWl, 64,  7};
  wp.d[4]  = {l1_uj_Wr, l1_sj_Wr,  wt_wr1sum, 128, 7};
  wp.d[5]  = {l1_js_Wl, nullptr,   wt_l1jsWl, 128, 7};
  wp.d[6]  = {l1_js_Wr, nullptr,   wt_l1jsWr, 64,  7};
  wp.d[7]  = {l2_uj_Wl, nullptr,   wt_l2ujWl, 128, 6};
  wp.d[8]  = {l2_ju_Wl, nullptr,   wt_tjx,             128, 6};
  wp.d[9]  = {l2_js_Wl, nullptr,   wt_tjx + 64 * 128,  128, 6};
  wp.d[10] = {l2_sj_Wl, nullptr,   wt_l2sjWl, 128, 6};
  wp.d[11] = {l2_ju_Wr, nullptr,   wt_l2juWr, 128, 6};
  wp.d[12] = {l2_uj_Wr, l2_sj_Wr,  wt_wr2sum, 128, 6};
  wp.d[13] = {l2_js_Wr, nullptr,   wt_l2jsWr, 128, 6};
  wprep_kernel<<<dim3(14, 8), 256, 0, stream>>>(wp);

  auto nb = [](int n) { return (n + 3) / 4; };

  // ---- layer 1 gathers fused (bf16 in, bf16 out) ----
  {
    GTask g0{xu_bf, 64, starts_all + b1, N_J, aggB_bf, 1, 0};
    GTask g1{xj_bf, 64, starts_all + b2, N_U, aggA_bf, 1, g0.blk0 + nb(N_J)};
    GTask g2{xj_bf, 64, starts_all + b3, N_S, aggD_bf, 1, g1.blk0 + nb(N_U)};
    GTask g3{xs_bf, 32, starts_all + b4, N_J, aggC_bf, 0, g2.blk0 + nb(N_S)};
    int gtot = g3.blk0 + nb(N_J);
    gather4<1><<<gtot, 256, 0, stream>>>(g0, g1, g2, g3, eidx_all);
  }

  SegB z{nullptr, nullptr, 0};

  // ---- layer 1 dense (+ReLU), N=128, bf16 out ----
  dense_mfma<4><<<(N_U + 127) / 128, 256, 0, stream>>>(
      SegB{aggA_bf, wt_l1juWl, 128}, SegB{(const unsigned short*)xu_bf, wt_l1juWr, 128}, z, 2,
      l1_ju_bl, nullptr, nullptr, nullptr, nullptr, h_u, N_U, 128, 1);
  dense_mfma<4><<<(N_J + 127) / 128, 256, 0, stream>>>(
      SegB{aggB_bf, wt_l1ujWl, 128}, SegB{aggC_bf, wt_l1sjWl, 64},
      SegB{(const unsigned short*)xj_bf, wt_wr1sum, 128}, 3,
      l1_uj_bl, l1_sj_bl, nullptr, nullptr, nullptr, h_j, N_J, 128, 1);
  dense_mfma<4><<<(N_S + 127) / 128, 256, 0, stream>>>(
      SegB{aggD_bf, wt_l1jsWl, 128}, SegB{(const unsigned short*)xs_bf, wt_l1jsWr, 64}, z, 2,
      l1_js_bl, nullptr, nullptr, nullptr, nullptr, h_s, N_S, 128, 1);

  // ---- layer 2 transforms (bf16 out) ----
  dense_mfma<2><<<(N_U + 127) / 128, 256, 0, stream>>>(
      SegB{h_u, wt_l2ujWl, 128}, z, z, 1,
      nullptr, nullptr, nullptr, nullptr, nullptr, t_uj, N_U, 64, 0);
  dense_mfma<4><<<(N_J + 127) / 128, 256, 0, stream>>>(
      SegB{h_j, wt_tjx, 128}, z, z, 1,
      nullptr, nullptr, nullptr, nullptr, nullptr, t_jx, N_J, 128, 0);
  dense_mfma<2><<<(N_S + 127) / 128, 256, 0, stream>>>(
      SegB{h_s, wt_l2sjWl, 128}, z, z, 1,
      nullptr, nullptr, nullptr, nullptr, nullptr, t_sj, N_S, 64, 0);

  // ---- layer 2 gathers fused (bf16 in, fp32 out), all width-64 ----
  {
    GTask g0{(const unsigned*)t_uj, 32, starts_all + b1, N_J, aggB_f, 0, 0};
    GTask g1{(const unsigned*)t_jx, 64, starts_all + b2, N_U, aggA_f, 0, g0.blk0 + nb(N_J)};
    GTask g2{(const unsigned*)t_jx + 32, 64, starts_all + b3, N_S, aggD_f, 0, g1.blk0 + nb(N_U)};
    GTask g3{(const unsigned*)t_sj, 32, starts_all + b4, N_J, aggC_f, 0, g2.blk0 + nb(N_S)};
    int gtot = g3.blk0 + nb(N_J);
    gather4<0><<<gtot, 256, 0, stream>>>(g0, g1, g2, g3, eidx_all);
  }

  // ---- layer 2 final dense (fp32 out to d_out) ----
  dense_mfma<2><<<(N_U + 127) / 128, 256, 0, stream>>>(
      SegB{h_u, wt_l2juWr, 128}, z, z, 1,
      l2_ju_bl, nullptr, aggA_f, nullptr, o_u, nullptr, N_U, 64, 0);
  dense_mfma<2><<<(N_J + 127) / 128, 256, 0, stream>>>(
      SegB{h_j, wt_wr2sum, 128}, z, z, 1,
      l2_uj_bl, l2_sj_bl, aggB_f, aggC_f, o_j, nullptr, N_J, 64, 0);
  dense_mfma<2><<<(N_S + 127) / 128, 256, 0, stream>>>(
      SegB{h_s, wt_l2jsWr, 128}, z, z, 1,
      l2_js_bl, nullptr, aggD_f, nullptr, o_s, nullptr, N_S, 64, 0);
}

// Round 7
// 562.199 us; speedup vs baseline: 1.8028x; 1.1114x over previous
//
#include <hip/hip_runtime.h>

typedef short short8 __attribute__((ext_vector_type(8)));
typedef float floatx4 __attribute__((ext_vector_type(4)));

__device__ __forceinline__ unsigned f2bf(float f) {
  unsigned u = __builtin_bit_cast(unsigned, f);
  return (u + 0x7fffu + ((u >> 16) & 1u)) >> 16;
}
__device__ __forceinline__ float bflo(unsigned u) { return __builtin_bit_cast(float, u << 16); }
__device__ __forceinline__ float bfhi(unsigned u) { return __builtin_bit_cast(float, u & 0xffff0000u); }

// ---------------- fused CSR build (all 4 edge types) ----------------

__global__ void hist4_kernel(const int* d0, const int* d1, const int* d2, const int* d3,
                             int E0, int E1, int E2, int E3,
                             int b0, int b1, int b2, int b3, int* __restrict__ cnt) {
  int t = blockIdx.y;
  const int* d; int E, b;
  if (t == 0) { d = d0; E = E0; b = b0; }
  else if (t == 1) { d = d1; E = E1; b = b1; }
  else if (t == 2) { d = d2; E = E2; b = b2; }
  else { d = d3; E = E3; b = b3; }
  int i = blockIdx.x * 256 + threadIdx.x;
  if (i < E) {
    int dd = __builtin_nontemporal_load(d + i);
    atomicAdd(&cnt[b + dd], 1);
  }
}

__global__ void exscan_kernel(const int* __restrict__ cnt, int* __restrict__ starts, int n) {
  __shared__ int wsum[16];
  __shared__ int wpre[16];
  __shared__ int tot_s;
  __shared__ int carry_s;
  int tid = threadIdx.x, lane = tid & 63, wv = tid >> 6;
  if (tid == 0) carry_s = 0;
  for (int base = 0; base < n; base += 1024) {
    __syncthreads();
    int carry = carry_s;
    int i = base + tid;
    int v = (i < n) ? cnt[i] : 0;
    int inc = v;
#pragma unroll
    for (int off = 1; off < 64; off <<= 1) {
      int t = __shfl_up(inc, off, 64);
      if (lane >= off) inc += t;
    }
    if (lane == 63) wsum[wv] = inc;
    __syncthreads();
    if (tid < 16) {
      int x = wsum[tid];
      int p = x;
#pragma unroll
      for (int off = 1; off < 16; off <<= 1) {
        int t = __shfl_up(p, off, 64);
        if (tid >= off) p += t;
      }
      wpre[tid] = p - x;
      if (tid == 15) tot_s = p;
    }
    __syncthreads();
    if (i < n) starts[i] = carry + wpre[wv] + (inc - v);
    if (tid == 0) carry_s = carry + tot_s;
  }
  __syncthreads();
  if (tid == 0) starts[n] = carry_s;
}

__global__ void scatter4_kernel(const int* s0p, const int* s1p, const int* s2p, const int* s3p,
                                const int* d0, const int* d1, const int* d2, const int* d3,
                                int E0, int E1, int E2, int E3,
                                int b0, int b1, int b2, int b3,
                                const int* __restrict__ starts, int* __restrict__ cur,
                                unsigned short* __restrict__ eidx_all) {
  int t = blockIdx.y;
  const int* sp; const int* d; int E, b;
  if (t == 0) { sp = s0p; d = d0; E = E0; b = b0; }
  else if (t == 1) { sp = s1p; d = d1; E = E1; b = b1; }
  else if (t == 2) { sp = s2p; d = d2; E = E2; b = b2; }
  else { sp = s3p; d = d3; E = E3; b = b3; }
  int i = blockIdx.x * 256 + threadIdx.x;
  if (i >= E) return;
  int dd = b + __builtin_nontemporal_load(d + i);
  int sv = __builtin_nontemporal_load(sp + i);
  int p = starts[dd] + atomicAdd(&cur[dd], 1);
  eidx_all[p] = (unsigned short)sv;
}

// ---------------- fp32 -> bf16 table copies (fused x3) ----------------

struct CTask { const float* in; unsigned* out; int n4; };

__global__ void tobf16x3_kernel(CTask t0, CTask t1, CTask t2) {
  CTask t = (blockIdx.y == 0) ? t0 : ((blockIdx.y == 1) ? t1 : t2);
  int i = blockIdx.x * 256 + threadIdx.x;
  if (i >= t.n4) return;
  float4 v = ((const float4*)t.in)[i];
  uint2 r;
  r.x = f2bf(v.x) | (f2bf(v.y) << 16);
  r.y = f2bf(v.z) | (f2bf(v.w) << 16);
  ((uint2*)t.out)[i] = r;
}

// ---------------- weight prep: transpose (+optional sum) to bf16 [N][K] ----------------

struct WDesc { const float* s1; const float* s2; unsigned short* dst; int K; int lgN; };
struct WPack { WDesc d[14]; };

__global__ void wprep_kernel(WPack p) {
  WDesc w = p.d[blockIdx.x];
  int NN = 1 << w.lgN;
  int tot = w.K << w.lgN;
  for (int i = threadIdx.x + 256 * blockIdx.y; i < tot; i += 256 * 8) {
    int k = i >> w.lgN, n = i & (NN - 1);
    float v = w.s1[((size_t)k << w.lgN) + n];
    if (w.s2) v += w.s2[((size_t)k << w.lgN) + n];
    w.dst[(size_t)n * w.K + k] = (unsigned short)f2bf(v);
  }
}

// ---------------- fused gather-mean (4 tasks / dispatch): one wave per dst ----------------

struct GTask { const unsigned* src; int rs; const int* starts; int n_dst; void* out; int d128; int blk0; };

template <int OBF>
__global__ __launch_bounds__(256) void gather4(GTask t0, GTask t1, GTask t2, GTask t3,
                                               const unsigned short* __restrict__ eidx) {
  GTask t;
  int bx = blockIdx.x;
  if (bx >= t3.blk0) t = t3;
  else if (bx >= t2.blk0) t = t2;
  else if (bx >= t1.blk0) t = t1;
  else t = t0;
  int w = (bx - t.blk0) * 4 + (threadIdx.x >> 6);
  if (w >= t.n_dst) return;
  int lane = threadIdx.x & 63;
  int sub = lane >> 5, sl = lane & 31;
  int s0 = t.starts[w], s1 = t.starts[w + 1];
  int c = s1 - s0;
  float inv = 1.0f / (float)(c > 0 ? c : 1);

  if (t.d128) {
    const uint2* x2 = (const uint2*)t.src;
    int rs2 = t.rs >> 1;
    float a0 = 0.f, a1 = 0.f, a2 = 0.f, a3 = 0.f;
    float b0 = 0.f, b1 = 0.f, b2 = 0.f, b3 = 0.f;
    int e = s0;
    for (; e + 16 <= s1; e += 16) {
      int i0 = eidx[e + sub];
      int i1 = eidx[e + 2 + sub];
      int i2 = eidx[e + 4 + sub];
      int i3 = eidx[e + 6 + sub];
      int i4 = eidx[e + 8 + sub];
      int i5 = eidx[e + 10 + sub];
      int i6 = eidx[e + 12 + sub];
      int i7 = eidx[e + 14 + sub];
      uint2 u0 = x2[(size_t)i0 * rs2 + sl];
      uint2 u1 = x2[(size_t)i1 * rs2 + sl];
      uint2 u2 = x2[(size_t)i2 * rs2 + sl];
      uint2 u3 = x2[(size_t)i3 * rs2 + sl];
      uint2 u4 = x2[(size_t)i4 * rs2 + sl];
      uint2 u5 = x2[(size_t)i5 * rs2 + sl];
      uint2 u6 = x2[(size_t)i6 * rs2 + sl];
      uint2 u7 = x2[(size_t)i7 * rs2 + sl];
      a0 += bflo(u0.x); a1 += bfhi(u0.x); a2 += bflo(u0.y); a3 += bfhi(u0.y);
      b0 += bflo(u1.x); b1 += bfhi(u1.x); b2 += bflo(u1.y); b3 += bfhi(u1.y);
      a0 += bflo(u2.x); a1 += bfhi(u2.x); a2 += bflo(u2.y); a3 += bfhi(u2.y);
      b0 += bflo(u3.x); b1 += bfhi(u3.x); b2 += bflo(u3.y); b3 += bfhi(u3.y);
      a0 += bflo(u4.x); a1 += bfhi(u4.x); a2 += bflo(u4.y); a3 += bfhi(u4.y);
      b0 += bflo(u5.x); b1 += bfhi(u5.x); b2 += bflo(u5.y); b3 += bfhi(u5.y);
      a0 += bflo(u6.x); a1 += bfhi(u6.x); a2 += bflo(u6.y); a3 += bfhi(u6.y);
      b0 += bflo(u7.x); b1 += bfhi(u7.x); b2 += bflo(u7.y); b3 += bfhi(u7.y);
    }
    for (; e + 2 <= s1; e += 2) {
      int i0 = eidx[e + sub];
      uint2 u0 = x2[(size_t)i0 * rs2 + sl];
      a0 += bflo(u0.x); a1 += bfhi(u0.x); a2 += bflo(u0.y); a3 += bfhi(u0.y);
    }
    if (e < s1 && sub == 0) {
      uint2 u0 = x2[(size_t)eidx[e] * rs2 + sl];
      a0 += bflo(u0.x); a1 += bfhi(u0.x); a2 += bflo(u0.y); a3 += bfhi(u0.y);
    }
    a0 += b0; a1 += b1; a2 += b2; a3 += b3;
    a0 += __shfl_xor(a0, 32);
    a1 += __shfl_xor(a1, 32);
    a2 += __shfl_xor(a2, 32);
    a3 += __shfl_xor(a3, 32);
    if (sub == 0) {
      a0 *= inv; a1 *= inv; a2 *= inv; a3 *= inv;
      if (OBF) {
        uint2 r;
        r.x = f2bf(a0) | (f2bf(a1) << 16);
        r.y = f2bf(a2) | (f2bf(a3) << 16);
        ((uint2*)t.out)[(size_t)w * 32 + sl] = r;
      } else {
        float4 r; r.x = a0; r.y = a1; r.z = a2; r.w = a3;
        ((float4*)t.out)[(size_t)w * 32 + sl] = r;
      }
    }
  } else {  // D == 64
    const unsigned* xs = t.src;
    int rs = t.rs;
    float a0 = 0.f, a1 = 0.f, b0 = 0.f, b1 = 0.f;
    int e = s0;
    for (; e + 16 <= s1; e += 16) {
      int i0 = eidx[e + sub];
      int i1 = eidx[e + 2 + sub];
      int i2 = eidx[e + 4 + sub];
      int i3 = eidx[e + 6 + sub];
      int i4 = eidx[e + 8 + sub];
      int i5 = eidx[e + 10 + sub];
      int i6 = eidx[e + 12 + sub];
      int i7 = eidx[e + 14 + sub];
      unsigned u0 = xs[(size_t)i0 * rs + sl];
      unsigned u1 = xs[(size_t)i1 * rs + sl];
      unsigned u2 = xs[(size_t)i2 * rs + sl];
      unsigned u3 = xs[(size_t)i3 * rs + sl];
      unsigned u4 = xs[(size_t)i4 * rs + sl];
      unsigned u5 = xs[(size_t)i5 * rs + sl];
      unsigned u6 = xs[(size_t)i6 * rs + sl];
      unsigned u7 = xs[(size_t)i7 * rs + sl];
      a0 += bflo(u0); a1 += bfhi(u0);
      b0 += bflo(u1); b1 += bfhi(u1);
      a0 += bflo(u2); a1 += bfhi(u2);
      b0 += bflo(u3); b1 += bfhi(u3);
      a0 += bflo(u4); a1 += bfhi(u4);
      b0 += bflo(u5); b1 += bfhi(u5);
      a0 += bflo(u6); a1 += bfhi(u6);
      b0 += bflo(u7); b1 += bfhi(u7);
    }
    for (; e + 2 <= s1; e += 2) {
      unsigned u0 = xs[(size_t)eidx[e + sub] * rs + sl];
      a0 += bflo(u0); a1 += bfhi(u0);
    }
    if (e < s1 && sub == 0) {
      unsigned u0 = xs[(size_t)eidx[e] * rs + sl];
      a0 += bflo(u0); a1 += bfhi(u0);
    }
    a0 += b0; a1 += b1;
    a0 += __shfl_xor(a0, 32);
    a1 += __shfl_xor(a1, 32);
    if (sub == 0) {
      a0 *= inv; a1 *= inv;
      if (OBF) {
        ((unsigned*)t.out)[(size_t)w * 32 + sl] = f2bf(a0) | (f2bf(a1) << 16);
      } else {
        float2 r; r.x = a0; r.y = a1;
        ((float2*)t.out)[(size_t)w * 32 + sl] = r;
      }
    }
  }
}

// ---------------- fused MFMA dense (up to 3 tasks / dispatch) ----------------

struct SegB { const unsigned short* A; const unsigned short* Wt; int K; };

struct DTask {
  SegB s0, s1, s2; int nseg;
  const float* bias0; const float* bias1; const float* add0; const float* add1;
  float* of32; unsigned short* obf16;
  int M, ldo, relu, nt, blk0;
};
struct DPack { DTask d[3]; int n; };

template <int NTMAX>
__global__ __launch_bounds__(256) void dense_multi(DPack p) {
  __shared__ unsigned short A_s[128 * 128];
  __shared__ unsigned short B_s[NTMAX * 32 * 128];
  int bx = blockIdx.x;
  int ti = 0;
#pragma unroll
  for (int i = 1; i < 3; ++i)
    if (i < p.n && bx >= p.d[i].blk0) ti = i;
  DTask t = p.d[ti];
  int tid = threadIdx.x;
  int lane = tid & 63, wid = tid >> 6;
  int wr = wid >> 1, wc = wid & 1;
  int m0 = (bx - t.blk0) * 128;
  const int nt = t.nt;
  floatx4 acc[4][NTMAX] = {};

  for (int sg = 0; sg < t.nseg; ++sg) {
    SegB s = (sg == 0) ? t.s0 : ((sg == 1) ? t.s1 : t.s2);
    const int K = s.K;
    const int lsh = (K == 128) ? 4 : 3;
    const int slots = 1 << lsh;
    if (sg) __syncthreads();
    for (int c = tid; c < (128 << lsh); c += 256) {
      int row = c >> lsh, sl = c & (slots - 1);
      int gr = m0 + row; if (gr >= t.M) gr = t.M - 1;
      uint4 v = *(const uint4*)(s.A + (size_t)gr * K + sl * 8);
      *(uint4*)((char*)A_s + row * 256 + ((sl * 16) ^ ((row & 7) << 4))) = v;
    }
    for (int c = tid; c < ((nt * 32) << lsh); c += 256) {
      int row = c >> lsh, sl = c & (slots - 1);
      uint4 v = *(const uint4*)(s.Wt + (size_t)row * K + sl * 8);
      *(uint4*)((char*)B_s + row * 256 + ((sl * 16) ^ ((row & 7) << 4))) = v;
    }
    __syncthreads();
    const int nks = K >> 5;
    for (int ks = 0; ks < nks; ++ks) {
      int kb = ks * 64 + ((lane >> 4) << 4);
      short8 a[4], b[NTMAX];
#pragma unroll
      for (int fm = 0; fm < 4; ++fm) {
        int row = wr * 64 + fm * 16 + (lane & 15);
        a[fm] = *(const short8*)((const char*)A_s + row * 256 + (kb ^ ((row & 7) << 4)));
      }
#pragma unroll
      for (int fn = 0; fn < NTMAX; ++fn)
        if (fn < nt) {
          int row = wc * (nt * 16) + fn * 16 + (lane & 15);
          b[fn] = *(const short8*)((const char*)B_s + row * 256 + (kb ^ ((row & 7) << 4)));
        }
#pragma unroll
      for (int fm = 0; fm < 4; ++fm)
#pragma unroll
        for (int fn = 0; fn < NTMAX; ++fn)
          if (fn < nt)
            acc[fm][fn] = __builtin_amdgcn_mfma_f32_16x16x32_bf16(a[fm], b[fn], acc[fm][fn], 0, 0, 0);
    }
  }

  int lr = (lane >> 4) * 4, lc = lane & 15;
#pragma unroll
  for (int fm = 0; fm < 4; ++fm) {
#pragma unroll
    for (int i = 0; i < 4; ++i) {
      int grow = m0 + wr * 64 + fm * 16 + lr + i;
      if (grow >= t.M) continue;
#pragma unroll
      for (int fn = 0; fn < NTMAX; ++fn)
        if (fn < nt) {
          int gcol = wc * (nt * 16) + fn * 16 + lc;
          float v = acc[fm][fn][i];
          if (t.bias0) v += t.bias0[gcol];
          if (t.bias1) v += t.bias1[gcol];
          size_t oidx = (size_t)grow * t.ldo + gcol;
          if (t.add0) v += t.add0[oidx];
          if (t.add1) v += t.add1[oidx];
          if (t.relu) v = fmaxf(v, 0.f);
          if (t.obf16) t.obf16[oidx] = (unsigned short)f2bf(v);
          else t.of32[oidx] = v;
        }
    }
  }
}

// ---------------- launch ----------------

extern "C" void kernel_launch(void* const* d_in, const int* in_sizes, int n_in,
                              void* d_out, int out_size, void* d_ws, size_t ws_size,
                              hipStream_t stream) {
  const float* x_user  = (const float*)d_in[0];
  const float* x_job   = (const float*)d_in[1];
  const float* x_skill = (const float*)d_in[2];

  const float* l1_uj_Wl = (const float*)d_in[3];
  const float* l1_uj_bl = (const float*)d_in[4];
  const float* l1_uj_Wr = (const float*)d_in[5];
  const float* l2_uj_Wl = (const float*)d_in[6];
  const float* l2_uj_bl = (const float*)d_in[7];
  const float* l2_uj_Wr = (const float*)d_in[8];

  const float* l1_ju_Wl = (const float*)d_in[9];
  const float* l1_ju_bl = (const float*)d_in[10];
  const float* l1_ju_Wr = (const float*)d_in[11];
  const float* l2_ju_Wl = (const float*)d_in[12];
  const float* l2_ju_bl = (const float*)d_in[13];
  const float* l2_ju_Wr = (const float*)d_in[14];

  const float* l1_js_Wl = (const float*)d_in[15];
  const float* l1_js_bl = (const float*)d_in[16];
  const float* l1_js_Wr = (const float*)d_in[17];
  const float* l2_js_Wl = (const float*)d_in[18];
  const float* l2_js_bl = (const float*)d_in[19];
  const float* l2_js_Wr = (const float*)d_in[20];

  const float* l1_sj_Wl = (const float*)d_in[21];
  const float* l1_sj_bl = (const float*)d_in[22];
  const float* l1_sj_Wr = (const float*)d_in[23];
  const float* l2_sj_Wl = (const float*)d_in[24];
  const float* l2_sj_bl = (const float*)d_in[25];
  const float* l2_sj_Wr = (const float*)d_in[26];

  const int* e1_src = (const int*)d_in[27];
  const int* e1_dst = (const int*)d_in[28];
  const int* e2_src = (const int*)d_in[29];
  const int* e2_dst = (const int*)d_in[30];
  const int* e3_src = (const int*)d_in[31];
  const int* e3_dst = (const int*)d_in[32];
  const int* e4_src = (const int*)d_in[33];
  const int* e4_dst = (const int*)d_in[34];

  const int N_U = in_sizes[0] / 128;
  const int N_J = in_sizes[1] / 128;
  const int N_S = in_sizes[2] / 64;
  const int E1 = in_sizes[27], E2 = in_sizes[29], E3 = in_sizes[31], E4 = in_sizes[33];
  const int Etot = E1 + E2 + E3 + E4;
  const int b1 = 0, b2 = N_J, b3 = N_J + N_U, b4 = N_J + N_U + N_S;
  const int ntot = b4 + N_J;

  char* wsp = (char*)d_ws;
  size_t off = 0;
  auto alloc = [&](size_t bytes) -> void* {
    void* p = wsp + off;
    off += (bytes + 255) & ~(size_t)255;
    return p;
  };

  int* cnt_all    = (int*)alloc((size_t)ntot * 4);
  int* starts_all = (int*)alloc((size_t)(ntot + 1) * 4);
  unsigned short* eidx_all = (unsigned short*)alloc((size_t)Etot * 2);

  unsigned* xu_bf = (unsigned*)alloc((size_t)N_U * 128 * 2);
  unsigned* xj_bf = (unsigned*)alloc((size_t)N_J * 128 * 2);
  unsigned* xs_bf = (unsigned*)alloc((size_t)N_S * 64 * 2);

  unsigned short* aggA_bf = (unsigned short*)alloc((size_t)N_U * 128 * 2);
  unsigned short* aggB_bf = (unsigned short*)alloc((size_t)N_J * 128 * 2);
  unsigned short* aggC_bf = (unsigned short*)alloc((size_t)N_J * 64 * 2);
  unsigned short* aggD_bf = (unsigned short*)alloc((size_t)N_S * 128 * 2);

  unsigned short* h_u = (unsigned short*)alloc((size_t)N_U * 128 * 2);
  unsigned short* h_j = (unsigned short*)alloc((size_t)N_J * 128 * 2);
  unsigned short* h_s = (unsigned short*)alloc((size_t)N_S * 128 * 2);

  unsigned short* t_uj = (unsigned short*)alloc((size_t)N_U * 64 * 2);
  unsigned short* t_jx = (unsigned short*)alloc((size_t)N_J * 128 * 2);
  unsigned short* t_sj = (unsigned short*)alloc((size_t)N_S * 64 * 2);

  float* aggA_f = (float*)alloc((size_t)N_U * 64 * 4);
  float* aggB_f = (float*)alloc((size_t)N_J * 64 * 4);
  float* aggC_f = (float*)alloc((size_t)N_J * 64 * 4);
  float* aggD_f = (float*)alloc((size_t)N_S * 64 * 4);

  auto walloc = [&](int n, int k) { return (unsigned short*)alloc((size_t)n * k * 2); };
  unsigned short* wt_l1juWl = walloc(128, 128);
  unsigned short* wt_l1juWr = walloc(128, 128);
  unsigned short* wt_l1ujWl = walloc(128, 128);
  unsigned short* wt_l1sjWl = walloc(128, 64);
  unsigned short* wt_wr1sum = walloc(128, 128);
  unsigned short* wt_l1jsWl = walloc(128, 128);
  unsigned short* wt_l1jsWr = walloc(128, 64);
  unsigned short* wt_l2ujWl = walloc(64, 128);
  unsigned short* wt_tjx    = walloc(128, 128);
  unsigned short* wt_l2sjWl = walloc(64, 128);
  unsigned short* wt_l2juWr = walloc(64, 128);
  unsigned short* wt_wr2sum = walloc(64, 128);
  unsigned short* wt_l2jsWr = walloc(64, 128);

  float* o_u = (float*)d_out;
  float* o_j = o_u + (size_t)N_U * 64;
  float* o_s = o_j + (size_t)N_J * 64;

  // ---- CSR build (fused, u16 edge indices, nontemporal edge streams) ----
  const int maxE = 800000;
  hipMemsetAsync(cnt_all, 0, (size_t)ntot * 4, stream);
  hist4_kernel<<<dim3((maxE + 255) / 256, 4), 256, 0, stream>>>(
      e1_dst, e2_dst, e3_dst, e4_dst, E1, E2, E3, E4, b1, b2, b3, b4, cnt_all);
  exscan_kernel<<<1, 1024, 0, stream>>>(cnt_all, starts_all, ntot);
  hipMemsetAsync(cnt_all, 0, (size_t)ntot * 4, stream);
  scatter4_kernel<<<dim3((maxE + 255) / 256, 4), 256, 0, stream>>>(
      e1_src, e2_src, e3_src, e4_src, e1_dst, e2_dst, e3_dst, e4_dst,
      E1, E2, E3, E4, b1, b2, b3, b4, starts_all, cnt_all, eidx_all);

  // ---- bf16 feature tables + bf16 transposed weights ----
  {
    CTask c0{x_user, xu_bf, N_U * 32};
    CTask c1{x_job, xj_bf, N_J * 32};
    CTask c2{x_skill, xs_bf, N_S * 16};
    int mx = c0.n4 > c1.n4 ? c0.n4 : c1.n4;
    if (c2.n4 > mx) mx = c2.n4;
    tobf16x3_kernel<<<dim3((mx + 255) / 256, 3), 256, 0, stream>>>(c0, c1, c2);
  }

  WPack wp;
  wp.d[0]  = {l1_ju_Wl, nullptr,   wt_l1juWl, 128, 7};
  wp.d[1]  = {l1_ju_Wr, nullptr,   wt_l1juWr, 128, 7};
  wp.d[2]  = {l1_uj_Wl, nullptr,   wt_l1ujWl, 128, 7};
  wp.d[3]  = {l1_sj_Wl, nullptr,   wt_l1sjWl, 64,  7};
  wp.d[4]  = {l1_uj_Wr, l1_sj_Wr,  wt_wr1sum, 128, 7};
  wp.d[5]  = {l1_js_Wl, nullptr,   wt_l1jsWl, 128, 7};
  wp.d[6]  = {l1_js_Wr, nullptr,   wt_l1jsWr, 64,  7};
  wp.d[7]  = {l2_uj_Wl, nullptr,   wt_l2ujWl, 128, 6};
  wp.d[8]  = {l2_ju_Wl, nullptr,   wt_tjx,             128, 6};
  wp.d[9]  = {l2_js_Wl, nullptr,   wt_tjx + 64 * 128,  128, 6};
  wp.d[10] = {l2_sj_Wl, nullptr,   wt_l2sjWl, 128, 6};
  wp.d[11] = {l2_ju_Wr, nullptr,   wt_l2juWr, 128, 6};
  wp.d[12] = {l2_uj_Wr, l2_sj_Wr,  wt_wr2sum, 128, 6};
  wp.d[13] = {l2_js_Wr, nullptr,   wt_l2jsWr, 128, 6};
  wprep_kernel<<<dim3(14, 8), 256, 0, stream>>>(wp);

  auto nb = [](int n) { return (n + 3) / 4; };
  auto mb = [](int n) { return (n + 127) / 128; };

  // ---- layer 1 gathers fused (bf16 in, bf16 out) ----
  {
    GTask g0{xu_bf, 64, starts_all + b1, N_J, aggB_bf, 1, 0};
    GTask g1{xj_bf, 64, starts_all + b2, N_U, aggA_bf, 1, g0.blk0 + nb(N_J)};
    GTask g2{xj_bf, 64, starts_all + b3, N_S, aggD_bf, 1, g1.blk0 + nb(N_U)};
    GTask g3{xs_bf, 32, starts_all + b4, N_J, aggC_bf, 0, g2.blk0 + nb(N_S)};
    int gtot = g3.blk0 + nb(N_J);
    gather4<1><<<gtot, 256, 0, stream>>>(g0, g1, g2, g3, eidx_all);
  }

  SegB z{nullptr, nullptr, 0};
  auto mkT = [&](SegB a, SegB b, SegB c, int nseg, const float* bi0, const float* bi1,
                 const float* a0, const float* a1, float* of, unsigned short* ob,
                 int M, int ldo, int relu, int nt, int blk0) {
    DTask t;
    t.s0 = a; t.s1 = b; t.s2 = c; t.nseg = nseg;
    t.bias0 = bi0; t.bias1 = bi1; t.add0 = a0; t.add1 = a1;
    t.of32 = of; t.obf16 = ob;
    t.M = M; t.ldo = ldo; t.relu = relu; t.nt = nt; t.blk0 = blk0;
    return t;
  };

  // ---- layer 1 dense (+ReLU), fused 3 tasks, all nt=4 ----
  {
    DPack p; p.n = 3;
    p.d[0] = mkT(SegB{aggA_bf, wt_l1juWl, 128}, SegB{(const unsigned short*)xu_bf, wt_l1juWr, 128}, z, 2,
                 l1_ju_bl, nullptr, nullptr, nullptr, nullptr, h_u, N_U, 128, 1, 4, 0);
    p.d[1] = mkT(SegB{aggB_bf, wt_l1ujWl, 128}, SegB{aggC_bf, wt_l1sjWl, 64},
                 SegB{(const unsigned short*)xj_bf, wt_wr1sum, 128}, 3,
                 l1_uj_bl, l1_sj_bl, nullptr, nullptr, nullptr, h_j, N_J, 128, 1, 4, mb(N_U));
    p.d[2] = mkT(SegB{aggD_bf, wt_l1jsWl, 128}, SegB{(const unsigned short*)xs_bf, wt_l1jsWr, 64}, z, 2,
                 l1_js_bl, nullptr, nullptr, nullptr, nullptr, h_s, N_S, 128, 1, 4, mb(N_U) + mb(N_J));
    dense_multi<4><<<mb(N_U) + mb(N_J) + mb(N_S), 256, 0, stream>>>(p);
  }

  // ---- layer 2 transforms, fused 3 tasks (nt 2/4/2) ----
  {
    DPack p; p.n = 3;
    p.d[0] = mkT(SegB{h_u, wt_l2ujWl, 128}, z, z, 1,
                 nullptr, nullptr, nullptr, nullptr, nullptr, t_uj, N_U, 64, 0, 2, 0);
    p.d[1] = mkT(SegB{h_j, wt_tjx, 128}, z, z, 1,
                 nullptr, nullptr, nullptr, nullptr, nullptr, t_jx, N_J, 128, 0, 4, mb(N_U));
    p.d[2] = mkT(SegB{h_s, wt_l2sjWl, 128}, z, z, 1,
                 nullptr, nullptr, nullptr, nullptr, nullptr, t_sj, N_S, 64, 0, 2, mb(N_U) + mb(N_J));
    dense_multi<4><<<mb(N_U) + mb(N_J) + mb(N_S), 256, 0, stream>>>(p);
  }

  // ---- layer 2 gathers fused (bf16 in, fp32 out), all width-64 ----
  {
    GTask g0{(const unsigned*)t_uj, 32, starts_all + b1, N_J, aggB_f, 0, 0};
    GTask g1{(const unsigned*)t_jx, 64, starts_all + b2, N_U, aggA_f, 0, g0.blk0 + nb(N_J)};
    GTask g2{(const unsigned*)t_jx + 32, 64, starts_all + b3, N_S, aggD_f, 0, g1.blk0 + nb(N_U)};
    GTask g3{(const unsigned*)t_sj, 32, starts_all + b4, N_J, aggC_f, 0, g2.blk0 + nb(N_S)};
    int gtot = g3.blk0 + nb(N_J);
    gather4<0><<<gtot, 256, 0, stream>>>(g0, g1, g2, g3, eidx_all);
  }

  // ---- layer 2 final dense (fp32 out to d_out), fused 3 tasks, all nt=2 ----
  {
    DPack p; p.n = 3;
    p.d[0] = mkT(SegB{h_u, wt_l2juWr, 128}, z, z, 1,
                 l2_ju_bl, nullptr, aggA_f, nullptr, o_u, nullptr, N_U, 64, 0, 2, 0);
    p.d[1] = mkT(SegB{h_j, wt_wr2sum, 128}, z, z, 1,
                 l2_uj_bl, l2_sj_bl, aggB_f, aggC_f, o_j, nullptr, N_J, 64, 0, 2, mb(N_U));
    p.d[2] = mkT(SegB{h_s, wt_l2jsWr, 128}, z, z, 1,
                 l2_js_bl, nullptr, aggD_f, nullptr, o_s, nullptr, N_S, 64, 0, 2, mb(N_U) + mb(N_J));
    dense_multi<2><<<mb(N_U) + mb(N_J) + mb(N_S), 256, 0, stream>>>(p);
  }
}

// Round 8
// 503.052 us; speedup vs baseline: 2.0147x; 1.1176x over previous
//
#include <hip/hip_runtime.h>

typedef short short8 __attribute__((ext_vector_type(8)));
typedef float floatx4 __attribute__((ext_vector_type(4)));

__device__ __forceinline__ unsigned f2bf(float f) {
  unsigned u = __builtin_bit_cast(unsigned, f);
  return (u + 0x7fffu + ((u >> 16) & 1u)) >> 16;
}
__device__ __forceinline__ float bflo(unsigned u) { return __builtin_bit_cast(float, u << 16); }
__device__ __forceinline__ float bfhi(unsigned u) { return __builtin_bit_cast(float, u & 0xffff0000u); }

// ---------------- fused CSR build (all 4 edge types) ----------------

__global__ void hist4_kernel(const int* d0, const int* d1, const int* d2, const int* d3,
                             int E0, int E1, int E2, int E3,
                             int b0, int b1, int b2, int b3, int* __restrict__ cnt) {
  int t = blockIdx.y;
  const int* d; int E, b;
  if (t == 0) { d = d0; E = E0; b = b0; }
  else if (t == 1) { d = d1; E = E1; b = b1; }
  else if (t == 2) { d = d2; E = E2; b = b2; }
  else { d = d3; E = E3; b = b3; }
  int i = blockIdx.x * 256 + threadIdx.x;
  if (i < E) {
    int dd = __builtin_nontemporal_load(d + i);
    atomicAdd(&cnt[b + dd], 1);
  }
}

// ---- 3-phase multi-block exclusive scan (1024 elems per block) ----

__global__ void scanA_kernel(const int* __restrict__ cnt, int n, int* __restrict__ bsum) {
  __shared__ int ws[4];
  int b = blockIdx.x, tid = threadIdx.x;
  int base = b * 1024 + tid * 4;
  int4 v = {0, 0, 0, 0};
  if (base + 3 < n) v = *(const int4*)(cnt + base);
  else {
    if (base + 0 < n) v.x = cnt[base + 0];
    if (base + 1 < n) v.y = cnt[base + 1];
    if (base + 2 < n) v.z = cnt[base + 2];
  }
  int s = v.x + v.y + v.z + v.w;
#pragma unroll
  for (int o = 1; o < 64; o <<= 1) s += __shfl_xor(s, o);
  if ((tid & 63) == 0) ws[tid >> 6] = s;
  __syncthreads();
  if (tid == 0) bsum[b] = ws[0] + ws[1] + ws[2] + ws[3];
}

__global__ void scanB_kernel(const int* __restrict__ bsum, int nb, int* __restrict__ boff,
                             int* __restrict__ starts, int ntot) {
  __shared__ int sh[257];
  int tid = threadIdx.x;
  if (tid < nb) sh[tid] = bsum[tid];
  __syncthreads();
  if (tid == 0) {
    int acc = 0;
    for (int i = 0; i < nb; ++i) { int t = sh[i]; sh[i] = acc; acc += t; }
    sh[nb] = acc;
  }
  __syncthreads();
  if (tid < nb) boff[tid] = sh[tid];
  if (tid == 0) starts[ntot] = sh[nb];
}

__global__ void scanC_kernel(const int* __restrict__ cnt, int n, const int* __restrict__ boff,
                             int* __restrict__ starts) {
  __shared__ int wsum[4];
  __shared__ int wpre[4];
  int b = blockIdx.x, tid = threadIdx.x, lane = tid & 63, wv = tid >> 6;
  int base = b * 1024 + tid * 4;
  int4 v = {0, 0, 0, 0};
  if (base + 3 < n) v = *(const int4*)(cnt + base);
  else {
    if (base + 0 < n) v.x = cnt[base + 0];
    if (base + 1 < n) v.y = cnt[base + 1];
    if (base + 2 < n) v.z = cnt[base + 2];
  }
  int s = v.x + v.y + v.z + v.w;
  int inc = s;
#pragma unroll
  for (int o = 1; o < 64; o <<= 1) {
    int t = __shfl_up(inc, o, 64);
    if (lane >= o) inc += t;
  }
  if (lane == 63) wsum[wv] = inc;
  __syncthreads();
  if (tid == 0) {
    int acc = 0;
    for (int i = 0; i < 4; ++i) { int t = wsum[i]; wpre[i] = acc; acc += t; }
  }
  __syncthreads();
  int off = boff[b] + wpre[wv] + (inc - s);
  if (base + 0 < n) starts[base + 0] = off;
  if (base + 1 < n) starts[base + 1] = off + v.x;
  if (base + 2 < n) starts[base + 2] = off + v.x + v.y;
  if (base + 3 < n) starts[base + 3] = off + v.x + v.y + v.z;
}

// ---- XCD-partitioned scatter: partition p = blockIdx & 7 owns dst slots [p*psz,(p+1)*psz) ----

__global__ __launch_bounds__(256) void scatter_part(
    const int* s0p, const int* s1p, const int* s2p, const int* s3p,
    const int* d0, const int* d1, const int* d2, const int* d3,
    int E0, int E1, int E2, int E3,
    int b0, int b1, int b2, int b3,
    int psz, const int* __restrict__ starts, int* __restrict__ cur,
    unsigned short* __restrict__ eidx_all) {
  int b = blockIdx.x;
  int p = b & 7;            // partition == XCD (round-robin dispatch assumption; perf-only)
  int slice = b >> 3;
  int nsl = gridDim.x >> 3;
  int lo = p * psz, hi = lo + psz;
#pragma unroll
  for (int t = 0; t < 4; ++t) {
    const int* sp; const int* dp; int E, base;
    if (t == 0) { sp = s0p; dp = d0; E = E0; base = b0; }
    else if (t == 1) { sp = s1p; dp = d1; E = E1; base = b1; }
    else if (t == 2) { sp = s2p; dp = d2; E = E2; base = b2; }
    else { sp = s3p; dp = d3; E = E3; base = b3; }
    for (int i = slice * 256 + (int)threadIdx.x; i < E; i += nsl * 256) {
      int dd = base + __builtin_nontemporal_load(dp + i);
      if (dd >= lo && dd < hi) {
        int sv = __builtin_nontemporal_load(sp + i);
        int pos = starts[dd] + atomicAdd(&cur[dd], 1);
        eidx_all[pos] = (unsigned short)sv;
      }
    }
  }
}

// ---------------- fp32 -> bf16 table copies (fused x3) ----------------

struct CTask { const float* in; unsigned* out; int n4; };

__global__ void tobf16x3_kernel(CTask t0, CTask t1, CTask t2) {
  CTask t = (blockIdx.y == 0) ? t0 : ((blockIdx.y == 1) ? t1 : t2);
  int i = blockIdx.x * 256 + threadIdx.x;
  if (i >= t.n4) return;
  float4 v = ((const float4*)t.in)[i];
  uint2 r;
  r.x = f2bf(v.x) | (f2bf(v.y) << 16);
  r.y = f2bf(v.z) | (f2bf(v.w) << 16);
  ((uint2*)t.out)[i] = r;
}

// ---------------- weight prep: transpose (+optional sum) to bf16 [N][K] ----------------

struct WDesc { const float* s1; const float* s2; unsigned short* dst; int K; int lgN; };
struct WPack { WDesc d[14]; };

__global__ void wprep_kernel(WPack p) {
  WDesc w = p.d[blockIdx.x];
  int NN = 1 << w.lgN;
  int tot = w.K << w.lgN;
  for (int i = threadIdx.x + 256 * blockIdx.y; i < tot; i += 256 * 8) {
    int k = i >> w.lgN, n = i & (NN - 1);
    float v = w.s1[((size_t)k << w.lgN) + n];
    if (w.s2) v += w.s2[((size_t)k << w.lgN) + n];
    w.dst[(size_t)n * w.K + k] = (unsigned short)f2bf(v);
  }
}

// ---------------- fused gather-mean (4 tasks / dispatch): one wave per dst ----------------

struct GTask { const unsigned* src; int rs; const int* starts; int n_dst; void* out; int d128; int blk0; };

template <int OBF>
__global__ __launch_bounds__(256) void gather4(GTask t0, GTask t1, GTask t2, GTask t3,
                                               const unsigned short* __restrict__ eidx) {
  GTask t;
  int bx = blockIdx.x;
  if (bx >= t3.blk0) t = t3;
  else if (bx >= t2.blk0) t = t2;
  else if (bx >= t1.blk0) t = t1;
  else t = t0;
  int w = (bx - t.blk0) * 4 + (threadIdx.x >> 6);
  if (w >= t.n_dst) return;
  int lane = threadIdx.x & 63;
  int sub = lane >> 5, sl = lane & 31;
  int s0 = t.starts[w], s1 = t.starts[w + 1];
  int c = s1 - s0;
  float inv = 1.0f / (float)(c > 0 ? c : 1);

  if (t.d128) {
    const uint2* x2 = (const uint2*)t.src;
    int rs2 = t.rs >> 1;
    float a0 = 0.f, a1 = 0.f, a2 = 0.f, a3 = 0.f;
    float b0 = 0.f, b1 = 0.f, b2 = 0.f, b3 = 0.f;
    int e = s0;
    for (; e + 16 <= s1; e += 16) {
      int i0 = eidx[e + sub];
      int i1 = eidx[e + 2 + sub];
      int i2 = eidx[e + 4 + sub];
      int i3 = eidx[e + 6 + sub];
      int i4 = eidx[e + 8 + sub];
      int i5 = eidx[e + 10 + sub];
      int i6 = eidx[e + 12 + sub];
      int i7 = eidx[e + 14 + sub];
      uint2 u0 = x2[(size_t)i0 * rs2 + sl];
      uint2 u1 = x2[(size_t)i1 * rs2 + sl];
      uint2 u2 = x2[(size_t)i2 * rs2 + sl];
      uint2 u3 = x2[(size_t)i3 * rs2 + sl];
      uint2 u4 = x2[(size_t)i4 * rs2 + sl];
      uint2 u5 = x2[(size_t)i5 * rs2 + sl];
      uint2 u6 = x2[(size_t)i6 * rs2 + sl];
      uint2 u7 = x2[(size_t)i7 * rs2 + sl];
      a0 += bflo(u0.x); a1 += bfhi(u0.x); a2 += bflo(u0.y); a3 += bfhi(u0.y);
      b0 += bflo(u1.x); b1 += bfhi(u1.x); b2 += bflo(u1.y); b3 += bfhi(u1.y);
      a0 += bflo(u2.x); a1 += bfhi(u2.x); a2 += bflo(u2.y); a3 += bfhi(u2.y);
      b0 += bflo(u3.x); b1 += bfhi(u3.x); b2 += bflo(u3.y); b3 += bfhi(u3.y);
      a0 += bflo(u4.x); a1 += bfhi(u4.x); a2 += bflo(u4.y); a3 += bfhi(u4.y);
      b0 += bflo(u5.x); b1 += bfhi(u5.x); b2 += bflo(u5.y); b3 += bfhi(u5.y);
      a0 += bflo(u6.x); a1 += bfhi(u6.x); a2 += bflo(u6.y); a3 += bfhi(u6.y);
      b0 += bflo(u7.x); b1 += bfhi(u7.x); b2 += bflo(u7.y); b3 += bfhi(u7.y);
    }
    for (; e + 2 <= s1; e += 2) {
      int i0 = eidx[e + sub];
      uint2 u0 = x2[(size_t)i0 * rs2 + sl];
      a0 += bflo(u0.x); a1 += bfhi(u0.x); a2 += bflo(u0.y); a3 += bfhi(u0.y);
    }
    if (e < s1 && sub == 0) {
      uint2 u0 = x2[(size_t)eidx[e] * rs2 + sl];
      a0 += bflo(u0.x); a1 += bfhi(u0.x); a2 += bflo(u0.y); a3 += bfhi(u0.y);
    }
    a0 += b0; a1 += b1; a2 += b2; a3 += b3;
    a0 += __shfl_xor(a0, 32);
    a1 += __shfl_xor(a1, 32);
    a2 += __shfl_xor(a2, 32);
    a3 += __shfl_xor(a3, 32);
    if (sub == 0) {
      a0 *= inv; a1 *= inv; a2 *= inv; a3 *= inv;
      if (OBF) {
        uint2 r;
        r.x = f2bf(a0) | (f2bf(a1) << 16);
        r.y = f2bf(a2) | (f2bf(a3) << 16);
        ((uint2*)t.out)[(size_t)w * 32 + sl] = r;
      } else {
        float4 r; r.x = a0; r.y = a1; r.z = a2; r.w = a3;
        ((float4*)t.out)[(size_t)w * 32 + sl] = r;
      }
    }
  } else {  // D == 64
    const unsigned* xs = t.src;
    int rs = t.rs;
    float a0 = 0.f, a1 = 0.f, b0 = 0.f, b1 = 0.f;
    int e = s0;
    for (; e + 16 <= s1; e += 16) {
      int i0 = eidx[e + sub];
      int i1 = eidx[e + 2 + sub];
      int i2 = eidx[e + 4 + sub];
      int i3 = eidx[e + 6 + sub];
      int i4 = eidx[e + 8 + sub];
      int i5 = eidx[e + 10 + sub];
      int i6 = eidx[e + 12 + sub];
      int i7 = eidx[e + 14 + sub];
      unsigned u0 = xs[(size_t)i0 * rs + sl];
      unsigned u1 = xs[(size_t)i1 * rs + sl];
      unsigned u2 = xs[(size_t)i2 * rs + sl];
      unsigned u3 = xs[(size_t)i3 * rs + sl];
      unsigned u4 = xs[(size_t)i4 * rs + sl];
      unsigned u5 = xs[(size_t)i5 * rs + sl];
      unsigned u6 = xs[(size_t)i6 * rs + sl];
      unsigned u7 = xs[(size_t)i7 * rs + sl];
      a0 += bflo(u0); a1 += bfhi(u0);
      b0 += bflo(u1); b1 += bfhi(u1);
      a0 += bflo(u2); a1 += bfhi(u2);
      b0 += bflo(u3); b1 += bfhi(u3);
      a0 += bflo(u4); a1 += bfhi(u4);
      b0 += bflo(u5); b1 += bfhi(u5);
      a0 += bflo(u6); a1 += bfhi(u6);
      b0 += bflo(u7); b1 += bfhi(u7);
    }
    for (; e + 2 <= s1; e += 2) {
      unsigned u0 = xs[(size_t)eidx[e + sub] * rs + sl];
      a0 += bflo(u0); a1 += bfhi(u0);
    }
    if (e < s1 && sub == 0) {
      unsigned u0 = xs[(size_t)eidx[e] * rs + sl];
      a0 += bflo(u0); a1 += bfhi(u0);
    }
    a0 += b0; a1 += b1;
    a0 += __shfl_xor(a0, 32);
    a1 += __shfl_xor(a1, 32);
    if (sub == 0) {
      a0 *= inv; a1 *= inv;
      if (OBF) {
        ((unsigned*)t.out)[(size_t)w * 32 + sl] = f2bf(a0) | (f2bf(a1) << 16);
      } else {
        float2 r; r.x = a0; r.y = a1;
        ((float2*)t.out)[(size_t)w * 32 + sl] = r;
      }
    }
  }
}

// ---------------- fused MFMA dense (up to 3 tasks / dispatch) ----------------

struct SegB { const unsigned short* A; const unsigned short* Wt; int K; };

struct DTask {
  SegB s0, s1, s2; int nseg;
  const float* bias0; const float* bias1; const float* add0; const float* add1;
  float* of32; unsigned short* obf16;
  int M, ldo, relu, nt, blk0;
};
struct DPack { DTask d[3]; int n; };

template <int NTMAX>
__global__ __launch_bounds__(256) void dense_multi(DPack p) {
  __shared__ unsigned short A_s[128 * 128];
  __shared__ unsigned short B_s[NTMAX * 32 * 128];
  int bx = blockIdx.x;
  int ti = 0;
#pragma unroll
  for (int i = 1; i < 3; ++i)
    if (i < p.n && bx >= p.d[i].blk0) ti = i;
  DTask t = p.d[ti];
  int tid = threadIdx.x;
  int lane = tid & 63, wid = tid >> 6;
  int wr = wid >> 1, wc = wid & 1;
  int m0 = (bx - t.blk0) * 128;
  const int nt = t.nt;
  floatx4 acc[4][NTMAX] = {};

  for (int sg = 0; sg < t.nseg; ++sg) {
    SegB s = (sg == 0) ? t.s0 : ((sg == 1) ? t.s1 : t.s2);
    const int K = s.K;
    const int lsh = (K == 128) ? 4 : 3;
    const int slots = 1 << lsh;
    if (sg) __syncthreads();
    for (int c = tid; c < (128 << lsh); c += 256) {
      int row = c >> lsh, sl = c & (slots - 1);
      int gr = m0 + row; if (gr >= t.M) gr = t.M - 1;
      uint4 v = *(const uint4*)(s.A + (size_t)gr * K + sl * 8);
      *(uint4*)((char*)A_s + row * 256 + ((sl * 16) ^ ((row & 7) << 4))) = v;
    }
    for (int c = tid; c < ((nt * 32) << lsh); c += 256) {
      int row = c >> lsh, sl = c & (slots - 1);
      uint4 v = *(const uint4*)(s.Wt + (size_t)row * K + sl * 8);
      *(uint4*)((char*)B_s + row * 256 + ((sl * 16) ^ ((row & 7) << 4))) = v;
    }
    __syncthreads();
    const int nks = K >> 5;
    for (int ks = 0; ks < nks; ++ks) {
      int kb = ks * 64 + ((lane >> 4) << 4);
      short8 a[4], b[NTMAX];
#pragma unroll
      for (int fm = 0; fm < 4; ++fm) {
        int row = wr * 64 + fm * 16 + (lane & 15);
        a[fm] = *(const short8*)((const char*)A_s + row * 256 + (kb ^ ((row & 7) << 4)));
      }
#pragma unroll
      for (int fn = 0; fn < NTMAX; ++fn)
        if (fn < nt) {
          int row = wc * (nt * 16) + fn * 16 + (lane & 15);
          b[fn] = *(const short8*)((const char*)B_s + row * 256 + (kb ^ ((row & 7) << 4)));
        }
#pragma unroll
      for (int fm = 0; fm < 4; ++fm)
#pragma unroll
        for (int fn = 0; fn < NTMAX; ++fn)
          if (fn < nt)
            acc[fm][fn] = __builtin_amdgcn_mfma_f32_16x16x32_bf16(a[fm], b[fn], acc[fm][fn], 0, 0, 0);
    }
  }

  int lr = (lane >> 4) * 4, lc = lane & 15;
#pragma unroll
  for (int fm = 0; fm < 4; ++fm) {
#pragma unroll
    for (int i = 0; i < 4; ++i) {
      int grow = m0 + wr * 64 + fm * 16 + lr + i;
      if (grow >= t.M) continue;
#pragma unroll
      for (int fn = 0; fn < NTMAX; ++fn)
        if (fn < nt) {
          int gcol = wc * (nt * 16) + fn * 16 + lc;
          float v = acc[fm][fn][i];
          if (t.bias0) v += t.bias0[gcol];
          if (t.bias1) v += t.bias1[gcol];
          size_t oidx = (size_t)grow * t.ldo + gcol;
          if (t.add0) v += t.add0[oidx];
          if (t.add1) v += t.add1[oidx];
          if (t.relu) v = fmaxf(v, 0.f);
          if (t.obf16) t.obf16[oidx] = (unsigned short)f2bf(v);
          else t.of32[oidx] = v;
        }
    }
  }
}

// ---------------- launch ----------------

extern "C" void kernel_launch(void* const* d_in, const int* in_sizes, int n_in,
                              void* d_out, int out_size, void* d_ws, size_t ws_size,
                              hipStream_t stream) {
  const float* x_user  = (const float*)d_in[0];
  const float* x_job   = (const float*)d_in[1];
  const float* x_skill = (const float*)d_in[2];

  const float* l1_uj_Wl = (const float*)d_in[3];
  const float* l1_uj_bl = (const float*)d_in[4];
  const float* l1_uj_Wr = (const float*)d_in[5];
  const float* l2_uj_Wl = (const float*)d_in[6];
  const float* l2_uj_bl = (const float*)d_in[7];
  const float* l2_uj_Wr = (const float*)d_in[8];

  const float* l1_ju_Wl = (const float*)d_in[9];
  const float* l1_ju_bl = (const float*)d_in[10];
  const float* l1_ju_Wr = (const float*)d_in[11];
  const float* l2_ju_Wl = (const float*)d_in[12];
  const float* l2_ju_bl = (const float*)d_in[13];
  const float* l2_ju_Wr = (const float*)d_in[14];

  const float* l1_js_Wl = (const float*)d_in[15];
  const float* l1_js_bl = (const float*)d_in[16];
  const float* l1_js_Wr = (const float*)d_in[17];
  const float* l2_js_Wl = (const float*)d_in[18];
  const float* l2_js_bl = (const float*)d_in[19];
  const float* l2_js_Wr = (const float*)d_in[20];

  const float* l1_sj_Wl = (const float*)d_in[21];
  const float* l1_sj_bl = (const float*)d_in[22];
  const float* l1_sj_Wr = (const float*)d_in[23];
  const float* l2_sj_Wl = (const float*)d_in[24];
  const float* l2_sj_bl = (const float*)d_in[25];
  const float* l2_sj_Wr = (const float*)d_in[26];

  const int* e1_src = (const int*)d_in[27];
  const int* e1_dst = (const int*)d_in[28];
  const int* e2_src = (const int*)d_in[29];
  const int* e2_dst = (const int*)d_in[30];
  const int* e3_src = (const int*)d_in[31];
  const int* e3_dst = (const int*)d_in[32];
  const int* e4_src = (const int*)d_in[33];
  const int* e4_dst = (const int*)d_in[34];

  const int N_U = in_sizes[0] / 128;
  const int N_J = in_sizes[1] / 128;
  const int N_S = in_sizes[2] / 64;
  const int E1 = in_sizes[27], E2 = in_sizes[29], E3 = in_sizes[31], E4 = in_sizes[33];
  const int Etot = E1 + E2 + E3 + E4;
  const int b1 = 0, b2 = N_J, b3 = N_J + N_U, b4 = N_J + N_U + N_S;
  const int ntot = b4 + N_J;

  char* wsp = (char*)d_ws;
  size_t off = 0;
  auto alloc = [&](size_t bytes) -> void* {
    void* p = wsp + off;
    off += (bytes + 255) & ~(size_t)255;
    return p;
  };

  int* cnt_all    = (int*)alloc((size_t)ntot * 4);
  int* starts_all = (int*)alloc((size_t)(ntot + 1) * 4);
  unsigned short* eidx_all = (unsigned short*)alloc((size_t)Etot * 2);
  int* bsum = (int*)alloc(256 * 4);
  int* boff = (int*)alloc(256 * 4);

  unsigned* xu_bf = (unsigned*)alloc((size_t)N_U * 128 * 2);
  unsigned* xj_bf = (unsigned*)alloc((size_t)N_J * 128 * 2);
  unsigned* xs_bf = (unsigned*)alloc((size_t)N_S * 64 * 2);

  unsigned short* aggA_bf = (unsigned short*)alloc((size_t)N_U * 128 * 2);
  unsigned short* aggB_bf = (unsigned short*)alloc((size_t)N_J * 128 * 2);
  unsigned short* aggC_bf = (unsigned short*)alloc((size_t)N_J * 64 * 2);
  unsigned short* aggD_bf = (unsigned short*)alloc((size_t)N_S * 128 * 2);

  unsigned short* h_u = (unsigned short*)alloc((size_t)N_U * 128 * 2);
  unsigned short* h_j = (unsigned short*)alloc((size_t)N_J * 128 * 2);
  unsigned short* h_s = (unsigned short*)alloc((size_t)N_S * 128 * 2);

  unsigned short* t_uj = (unsigned short*)alloc((size_t)N_U * 64 * 2);
  unsigned short* t_jx = (unsigned short*)alloc((size_t)N_J * 128 * 2);
  unsigned short* t_sj = (unsigned short*)alloc((size_t)N_S * 64 * 2);

  float* aggA_f = (float*)alloc((size_t)N_U * 64 * 4);
  float* aggB_f = (float*)alloc((size_t)N_J * 64 * 4);
  float* aggC_f = (float*)alloc((size_t)N_J * 64 * 4);
  float* aggD_f = (float*)alloc((size_t)N_S * 64 * 4);

  auto walloc = [&](int n, int k) { return (unsigned short*)alloc((size_t)n * k * 2); };
  unsigned short* wt_l1juWl = walloc(128, 128);
  unsigned short* wt_l1juWr = walloc(128, 128);
  unsigned short* wt_l1ujWl = walloc(128, 128);
  unsigned short* wt_l1sjWl = walloc(128, 64);
  unsigned short* wt_wr1sum = walloc(128, 128);
  unsigned short* wt_l1jsWl = walloc(128, 128);
  unsigned short* wt_l1jsWr = walloc(128, 64);
  unsigned short* wt_l2ujWl = walloc(64, 128);
  unsigned short* wt_tjx    = walloc(128, 128);
  unsigned short* wt_l2sjWl = walloc(64, 128);
  unsigned short* wt_l2juWr = walloc(64, 128);
  unsigned short* wt_wr2sum = walloc(64, 128);
  unsigned short* wt_l2jsWr = walloc(64, 128);

  float* o_u = (float*)d_out;
  float* o_j = o_u + (size_t)N_U * 64;
  float* o_s = o_j + (size_t)N_J * 64;

  // ---- CSR build: hist -> 3-phase scan -> XCD-partitioned scatter ----
  const int maxE = 800000;
  const int nsb = (ntot + 1023) / 1024;
  const int psz = (ntot + 7) / 8;
  hipMemsetAsync(cnt_all, 0, (size_t)ntot * 4, stream);
  hist4_kernel<<<dim3((maxE + 255) / 256, 4), 256, 0, stream>>>(
      e1_dst, e2_dst, e3_dst, e4_dst, E1, E2, E3, E4, b1, b2, b3, b4, cnt_all);
  scanA_kernel<<<nsb, 256, 0, stream>>>(cnt_all, ntot, bsum);
  scanB_kernel<<<1, 256, 0, stream>>>(bsum, nsb, boff, starts_all, ntot);
  scanC_kernel<<<nsb, 256, 0, stream>>>(cnt_all, ntot, boff, starts_all);
  hipMemsetAsync(cnt_all, 0, (size_t)ntot * 4, stream);
  scatter_part<<<2048, 256, 0, stream>>>(
      e1_src, e2_src, e3_src, e4_src, e1_dst, e2_dst, e3_dst, e4_dst,
      E1, E2, E3, E4, b1, b2, b3, b4, psz, starts_all, cnt_all, eidx_all);

  // ---- bf16 feature tables + bf16 transposed weights ----
  {
    CTask c0{x_user, xu_bf, N_U * 32};
    CTask c1{x_job, xj_bf, N_J * 32};
    CTask c2{x_skill, xs_bf, N_S * 16};
    int mx = c0.n4 > c1.n4 ? c0.n4 : c1.n4;
    if (c2.n4 > mx) mx = c2.n4;
    tobf16x3_kernel<<<dim3((mx + 255) / 256, 3), 256, 0, stream>>>(c0, c1, c2);
  }

  WPack wp;
  wp.d[0]  = {l1_ju_Wl, nullptr,   wt_l1juWl, 128, 7};
  wp.d[1]  = {l1_ju_Wr, nullptr,   wt_l1juWr, 128, 7};
  wp.d[2]  = {l1_uj_Wl, nullptr,   wt_l1ujWl, 128, 7};
  wp.d[3]  = {l1_sj_Wl, nullptr,   wt_l1sjWl, 64,  7};
  wp.d[4]  = {l1_uj_Wr, l1_sj_Wr,  wt_wr1sum, 128, 7};
  wp.d[5]  = {l1_js_Wl, nullptr,   wt_l1jsWl, 128, 7};
  wp.d[6]  = {l1_js_Wr, nullptr,   wt_l1jsWr, 64,  7};
  wp.d[7]  = {l2_uj_Wl, nullptr,   wt_l2ujWl, 128, 6};
  wp.d[8]  = {l2_ju_Wl, nullptr,   wt_tjx,             128, 6};
  wp.d[9]  = {l2_js_Wl, nullptr,   wt_tjx + 64 * 128,  128, 6};
  wp.d[10] = {l2_sj_Wl, nullptr,   wt_l2sjWl, 128, 6};
  wp.d[11] = {l2_ju_Wr, nullptr,   wt_l2juWr, 128, 6};
  wp.d[12] = {l2_uj_Wr, l2_sj_Wr,  wt_wr2sum, 128, 6};
  wp.d[13] = {l2_js_Wr, nullptr,   wt_l2jsWr, 128, 6};
  wprep_kernel<<<dim3(14, 8), 256, 0, stream>>>(wp);

  auto nb = [](int n) { return (n + 3) / 4; };
  auto mb = [](int n) { return (n + 127) / 128; };

  // ---- layer 1 gathers fused (bf16 in, bf16 out) ----
  {
    GTask g0{xu_bf, 64, starts_all + b1, N_J, aggB_bf, 1, 0};
    GTask g1{xj_bf, 64, starts_all + b2, N_U, aggA_bf, 1, g0.blk0 + nb(N_J)};
    GTask g2{xj_bf, 64, starts_all + b3, N_S, aggD_bf, 1, g1.blk0 + nb(N_U)};
    GTask g3{xs_bf, 32, starts_all + b4, N_J, aggC_bf, 0, g2.blk0 + nb(N_S)};
    int gtot = g3.blk0 + nb(N_J);
    gather4<1><<<gtot, 256, 0, stream>>>(g0, g1, g2, g3, eidx_all);
  }

  SegB z{nullptr, nullptr, 0};
  auto mkT = [&](SegB a, SegB b, SegB c, int nseg, const float* bi0, const float* bi1,
                 const float* a0, const float* a1, float* of, unsigned short* ob,
                 int M, int ldo, int relu, int nt, int blk0) {
    DTask t;
    t.s0 = a; t.s1 = b; t.s2 = c; t.nseg = nseg;
    t.bias0 = bi0; t.bias1 = bi1; t.add0 = a0; t.add1 = a1;
    t.of32 = of; t.obf16 = ob;
    t.M = M; t.ldo = ldo; t.relu = relu; t.nt = nt; t.blk0 = blk0;
    return t;
  };

  // ---- layer 1 dense (+ReLU), fused 3 tasks, all nt=4 ----
  {
    DPack p; p.n = 3;
    p.d[0] = mkT(SegB{aggA_bf, wt_l1juWl, 128}, SegB{(const unsigned short*)xu_bf, wt_l1juWr, 128}, z, 2,
                 l1_ju_bl, nullptr, nullptr, nullptr, nullptr, h_u, N_U, 128, 1, 4, 0);
    p.d[1] = mkT(SegB{aggB_bf, wt_l1ujWl, 128}, SegB{aggC_bf, wt_l1sjWl, 64},
                 SegB{(const unsigned short*)xj_bf, wt_wr1sum, 128}, 3,
                 l1_uj_bl, l1_sj_bl, nullptr, nullptr, nullptr, h_j, N_J, 128, 1, 4, mb(N_U));
    p.d[2] = mkT(SegB{aggD_bf, wt_l1jsWl, 128}, SegB{(const unsigned short*)xs_bf, wt_l1jsWr, 64}, z, 2,
                 l1_js_bl, nullptr, nullptr, nullptr, nullptr, h_s, N_S, 128, 1, 4, mb(N_U) + mb(N_J));
    dense_multi<4><<<mb(N_U) + mb(N_J) + mb(N_S), 256, 0, stream>>>(p);
  }

  // ---- layer 2 transforms, fused 3 tasks (nt 2/4/2) ----
  {
    DPack p; p.n = 3;
    p.d[0] = mkT(SegB{h_u, wt_l2ujWl, 128}, z, z, 1,
                 nullptr, nullptr, nullptr, nullptr, nullptr, t_uj, N_U, 64, 0, 2, 0);
    p.d[1] = mkT(SegB{h_j, wt_tjx, 128}, z, z, 1,
                 nullptr, nullptr, nullptr, nullptr, nullptr, t_jx, N_J, 128, 0, 4, mb(N_U));
    p.d[2] = mkT(SegB{h_s, wt_l2sjWl, 128}, z, z, 1,
                 nullptr, nullptr, nullptr, nullptr, nullptr, t_sj, N_S, 64, 0, 2, mb(N_U) + mb(N_J));
    dense_multi<4><<<mb(N_U) + mb(N_J) + mb(N_S), 256, 0, stream>>>(p);
  }

  // ---- layer 2 gathers fused (bf16 in, fp32 out), all width-64 ----
  {
    GTask g0{(const unsigned*)t_uj, 32, starts_all + b1, N_J, aggB_f, 0, 0};
    GTask g1{(const unsigned*)t_jx, 64, starts_all + b2, N_U, aggA_f, 0, g0.blk0 + nb(N_J)};
    GTask g2{(const unsigned*)t_jx + 32, 64, starts_all + b3, N_S, aggD_f, 0, g1.blk0 + nb(N_U)};
    GTask g3{(const unsigned*)t_sj, 32, starts_all + b4, N_J, aggC_f, 0, g2.blk0 + nb(N_S)};
    int gtot = g3.blk0 + nb(N_J);
    gather4<0><<<gtot, 256, 0, stream>>>(g0, g1, g2, g3, eidx_all);
  }

  // ---- layer 2 final dense (fp32 out to d_out), fused 3 tasks, all nt=2 ----
  {
    DPack p; p.n = 3;
    p.d[0] = mkT(SegB{h_u, wt_l2juWr, 128}, z, z, 1,
                 l2_ju_bl, nullptr, aggA_f, nullptr, o_u, nullptr, N_U, 64, 0, 2, 0);
    p.d[1] = mkT(SegB{h_j, wt_wr2sum, 128}, z, z, 1,
                 l2_uj_bl, l2_sj_bl, aggB_f, aggC_f, o_j, nullptr, N_J, 64, 0, 2, mb(N_U));
    p.d[2] = mkT(SegB{h_s, wt_l2jsWr, 128}, z, z, 1,
                 l2_js_bl, nullptr, aggD_f, nullptr, o_s, nullptr, N_S, 64, 0, 2, mb(N_U) + mb(N_J));
    dense_multi<2><<<mb(N_U) + mb(N_J) + mb(N_S), 256, 0, stream>>>(p);
  }
}

// Round 9
// 483.164 us; speedup vs baseline: 2.0977x; 1.0412x over previous
//
#include <hip/hip_runtime.h>

typedef short short8 __attribute__((ext_vector_type(8)));
typedef float floatx4 __attribute__((ext_vector_type(4)));

__device__ __forceinline__ unsigned f2bf(float f) {
  unsigned u = __builtin_bit_cast(unsigned, f);
  return (u + 0x7fffu + ((u >> 16) & 1u)) >> 16;
}
__device__ __forceinline__ float bflo(unsigned u) { return __builtin_bit_cast(float, u << 16); }
__device__ __forceinline__ float bfhi(unsigned u) { return __builtin_bit_cast(float, u & 0xffff0000u); }

// ---------------- fused CSR build: 8-copy XCD-local counters ----------------
// copy c = blockIdx.x & 7 (same mapping in hist and scatter => consistent sub-segment sizing)

__global__ void hist8_kernel(const int* d0, const int* d1, const int* d2, const int* d3,
                             int E0, int E1, int E2, int E3,
                             int b0, int b1, int b2, int b3, int ntot,
                             int* __restrict__ cnt8) {
  int t = blockIdx.y;
  const int* d; int E, b;
  if (t == 0) { d = d0; E = E0; b = b0; }
  else if (t == 1) { d = d1; E = E1; b = b1; }
  else if (t == 2) { d = d2; E = E2; b = b2; }
  else { d = d3; E = E3; b = b3; }
  int i = blockIdx.x * 256 + threadIdx.x;
  if (i < E) {
    int dd = b + __builtin_nontemporal_load(d + i);
    int c = blockIdx.x & 7;
    atomicAdd(&cnt8[c * ntot + dd], 1);
  }
}

// ---- 3-phase multi-block exclusive scan over dst-major view: val(i)=cnt8[(i&7)*ntot+(i>>3)] ----

__global__ void scanA_kernel(const int* __restrict__ cnt8, int ntot, int n, int* __restrict__ bsum) {
  __shared__ int ws[4];
  int b = blockIdx.x, tid = threadIdx.x;
  int base = b * 1024 + tid * 4;
  int s = 0;
#pragma unroll
  for (int q = 0; q < 4; ++q) {
    int i = base + q;
    if (i < n) s += cnt8[(i & 7) * ntot + (i >> 3)];
  }
#pragma unroll
  for (int o = 1; o < 64; o <<= 1) s += __shfl_xor(s, o);
  if ((tid & 63) == 0) ws[tid >> 6] = s;
  __syncthreads();
  if (tid == 0) bsum[b] = ws[0] + ws[1] + ws[2] + ws[3];
}

__global__ void scanB_kernel(const int* __restrict__ bsum, int nb, int* __restrict__ boff,
                             int* __restrict__ starts, int n) {
  __shared__ int sh[1025];
  int tid = threadIdx.x;
  for (int i = tid; i < nb; i += 256) sh[i] = bsum[i];
  __syncthreads();
  if (tid == 0) {
    int acc = 0;
    for (int i = 0; i < nb; ++i) { int t = sh[i]; sh[i] = acc; acc += t; }
    sh[nb] = acc;
  }
  __syncthreads();
  for (int i = tid; i < nb; i += 256) boff[i] = sh[i];
  if (tid == 0) starts[n] = sh[nb];
}

__global__ void scanC_kernel(const int* __restrict__ cnt8, int ntot, int n,
                             const int* __restrict__ boff, int* __restrict__ starts) {
  __shared__ int wsum[4];
  __shared__ int wpre[4];
  int b = blockIdx.x, tid = threadIdx.x, lane = tid & 63, wv = tid >> 6;
  int base = b * 1024 + tid * 4;
  int v[4];
#pragma unroll
  for (int q = 0; q < 4; ++q) {
    int i = base + q;
    v[q] = (i < n) ? cnt8[(i & 7) * ntot + (i >> 3)] : 0;
  }
  int s = v[0] + v[1] + v[2] + v[3];
  int inc = s;
#pragma unroll
  for (int o = 1; o < 64; o <<= 1) {
    int t = __shfl_up(inc, o, 64);
    if (lane >= o) inc += t;
  }
  if (lane == 63) wsum[wv] = inc;
  __syncthreads();
  if (tid == 0) {
    int acc = 0;
    for (int i = 0; i < 4; ++i) { int t = wsum[i]; wpre[i] = acc; acc += t; }
  }
  __syncthreads();
  int off = boff[b] + wpre[wv] + (inc - s);
  int run = 0;
#pragma unroll
  for (int q = 0; q < 4; ++q) {
    int i = base + q;
    if (i < n) starts[i] = off + run;
    run += v[q];
  }
}

// ---- single-pass scatter, XCD-local 8-copy cur ----

__global__ __launch_bounds__(256) void scatter8_kernel(
    const int* s0p, const int* s1p, const int* s2p, const int* s3p,
    const int* d0, const int* d1, const int* d2, const int* d3,
    int E0, int E1, int E2, int E3,
    int b0, int b1, int b2, int b3, int ntot,
    const int* __restrict__ starts, int* __restrict__ cur8,
    unsigned short* __restrict__ eidx_all) {
  int t = blockIdx.y;
  const int* sp; const int* d; int E, b;
  if (t == 0) { sp = s0p; d = d0; E = E0; b = b0; }
  else if (t == 1) { sp = s1p; d = d1; E = E1; b = b1; }
  else if (t == 2) { sp = s2p; d = d2; E = E2; b = b2; }
  else { sp = s3p; d = d3; E = E3; b = b3; }
  int i = blockIdx.x * 256 + threadIdx.x;
  if (i >= E) return;
  int c = blockIdx.x & 7;
  int dd = b + __builtin_nontemporal_load(d + i);
  int sv = __builtin_nontemporal_load(sp + i);
  int pos = starts[dd * 8 + c] + atomicAdd(&cur8[c * ntot + dd], 1);
  eidx_all[pos] = (unsigned short)sv;
}

// ---------------- fp32 -> bf16 table copies (fused x3) ----------------

struct CTask { const float* in; unsigned* out; int n4; };

__global__ void tobf16x3_kernel(CTask t0, CTask t1, CTask t2) {
  CTask t = (blockIdx.y == 0) ? t0 : ((blockIdx.y == 1) ? t1 : t2);
  int i = blockIdx.x * 256 + threadIdx.x;
  if (i >= t.n4) return;
  float4 v = ((const float4*)t.in)[i];
  uint2 r;
  r.x = f2bf(v.x) | (f2bf(v.y) << 16);
  r.y = f2bf(v.z) | (f2bf(v.w) << 16);
  ((uint2*)t.out)[i] = r;
}

// ---------------- weight prep: transpose (+optional sum) to bf16 [N][K] ----------------

struct WDesc { const float* s1; const float* s2; unsigned short* dst; int K; int lgN; };
struct WPack { WDesc d[14]; };

__global__ void wprep_kernel(WPack p) {
  WDesc w = p.d[blockIdx.x];
  int NN = 1 << w.lgN;
  int tot = w.K << w.lgN;
  for (int i = threadIdx.x + 256 * blockIdx.y; i < tot; i += 256 * 8) {
    int k = i >> w.lgN, n = i & (NN - 1);
    float v = w.s1[((size_t)k << w.lgN) + n];
    if (w.s2) v += w.s2[((size_t)k << w.lgN) + n];
    w.dst[(size_t)n * w.K + k] = (unsigned short)f2bf(v);
  }
}

// ---------------- fused gather-mean (4 tasks / dispatch): one wave per dst ----------------
// starts is stride-8 (dst-major sub-segment table): seg = [starts[w*8], starts[(w+1)*8])

struct GTask { const unsigned* src; int rs; const int* starts; int n_dst; void* out; int d128; int blk0; };

template <int OBF>
__global__ __launch_bounds__(256) void gather4(GTask t0, GTask t1, GTask t2, GTask t3,
                                               const unsigned short* __restrict__ eidx) {
  GTask t;
  int bx = blockIdx.x;
  if (bx >= t3.blk0) t = t3;
  else if (bx >= t2.blk0) t = t2;
  else if (bx >= t1.blk0) t = t1;
  else t = t0;
  int w = (bx - t.blk0) * 4 + (threadIdx.x >> 6);
  if (w >= t.n_dst) return;
  int lane = threadIdx.x & 63;
  int sub = lane >> 5, sl = lane & 31;
  int s0 = t.starts[w * 8], s1 = t.starts[w * 8 + 8];
  int c = s1 - s0;
  float inv = 1.0f / (float)(c > 0 ? c : 1);

  if (t.d128) {
    const uint2* x2 = (const uint2*)t.src;
    int rs2 = t.rs >> 1;
    float a0 = 0.f, a1 = 0.f, a2 = 0.f, a3 = 0.f;
    float b0 = 0.f, b1 = 0.f, b2 = 0.f, b3 = 0.f;
    int e = s0;
    for (; e + 16 <= s1; e += 16) {
      int i0 = eidx[e + sub];
      int i1 = eidx[e + 2 + sub];
      int i2 = eidx[e + 4 + sub];
      int i3 = eidx[e + 6 + sub];
      int i4 = eidx[e + 8 + sub];
      int i5 = eidx[e + 10 + sub];
      int i6 = eidx[e + 12 + sub];
      int i7 = eidx[e + 14 + sub];
      uint2 u0 = x2[(size_t)i0 * rs2 + sl];
      uint2 u1 = x2[(size_t)i1 * rs2 + sl];
      uint2 u2 = x2[(size_t)i2 * rs2 + sl];
      uint2 u3 = x2[(size_t)i3 * rs2 + sl];
      uint2 u4 = x2[(size_t)i4 * rs2 + sl];
      uint2 u5 = x2[(size_t)i5 * rs2 + sl];
      uint2 u6 = x2[(size_t)i6 * rs2 + sl];
      uint2 u7 = x2[(size_t)i7 * rs2 + sl];
      a0 += bflo(u0.x); a1 += bfhi(u0.x); a2 += bflo(u0.y); a3 += bfhi(u0.y);
      b0 += bflo(u1.x); b1 += bfhi(u1.x); b2 += bflo(u1.y); b3 += bfhi(u1.y);
      a0 += bflo(u2.x); a1 += bfhi(u2.x); a2 += bflo(u2.y); a3 += bfhi(u2.y);
      b0 += bflo(u3.x); b1 += bfhi(u3.x); b2 += bflo(u3.y); b3 += bfhi(u3.y);
      a0 += bflo(u4.x); a1 += bfhi(u4.x); a2 += bflo(u4.y); a3 += bfhi(u4.y);
      b0 += bflo(u5.x); b1 += bfhi(u5.x); b2 += bflo(u5.y); b3 += bfhi(u5.y);
      a0 += bflo(u6.x); a1 += bfhi(u6.x); a2 += bflo(u6.y); a3 += bfhi(u6.y);
      b0 += bflo(u7.x); b1 += bfhi(u7.x); b2 += bflo(u7.y); b3 += bfhi(u7.y);
    }
    for (; e + 2 <= s1; e += 2) {
      int i0 = eidx[e + sub];
      uint2 u0 = x2[(size_t)i0 * rs2 + sl];
      a0 += bflo(u0.x); a1 += bfhi(u0.x); a2 += bflo(u0.y); a3 += bfhi(u0.y);
    }
    if (e < s1 && sub == 0) {
      uint2 u0 = x2[(size_t)eidx[e] * rs2 + sl];
      a0 += bflo(u0.x); a1 += bfhi(u0.x); a2 += bflo(u0.y); a3 += bfhi(u0.y);
    }
    a0 += b0; a1 += b1; a2 += b2; a3 += b3;
    a0 += __shfl_xor(a0, 32);
    a1 += __shfl_xor(a1, 32);
    a2 += __shfl_xor(a2, 32);
    a3 += __shfl_xor(a3, 32);
    if (sub == 0) {
      a0 *= inv; a1 *= inv; a2 *= inv; a3 *= inv;
      if (OBF) {
        uint2 r;
        r.x = f2bf(a0) | (f2bf(a1) << 16);
        r.y = f2bf(a2) | (f2bf(a3) << 16);
        ((uint2*)t.out)[(size_t)w * 32 + sl] = r;
      } else {
        float4 r; r.x = a0; r.y = a1; r.z = a2; r.w = a3;
        ((float4*)t.out)[(size_t)w * 32 + sl] = r;
      }
    }
  } else {  // D == 64
    const unsigned* xs = t.src;
    int rs = t.rs;
    float a0 = 0.f, a1 = 0.f, b0 = 0.f, b1 = 0.f;
    int e = s0;
    for (; e + 16 <= s1; e += 16) {
      int i0 = eidx[e + sub];
      int i1 = eidx[e + 2 + sub];
      int i2 = eidx[e + 4 + sub];
      int i3 = eidx[e + 6 + sub];
      int i4 = eidx[e + 8 + sub];
      int i5 = eidx[e + 10 + sub];
      int i6 = eidx[e + 12 + sub];
      int i7 = eidx[e + 14 + sub];
      unsigned u0 = xs[(size_t)i0 * rs + sl];
      unsigned u1 = xs[(size_t)i1 * rs + sl];
      unsigned u2 = xs[(size_t)i2 * rs + sl];
      unsigned u3 = xs[(size_t)i3 * rs + sl];
      unsigned u4 = xs[(size_t)i4 * rs + sl];
      unsigned u5 = xs[(size_t)i5 * rs + sl];
      unsigned u6 = xs[(size_t)i6 * rs + sl];
      unsigned u7 = xs[(size_t)i7 * rs + sl];
      a0 += bflo(u0); a1 += bfhi(u0);
      b0 += bflo(u1); b1 += bfhi(u1);
      a0 += bflo(u2); a1 += bfhi(u2);
      b0 += bflo(u3); b1 += bfhi(u3);
      a0 += bflo(u4); a1 += bfhi(u4);
      b0 += bflo(u5); b1 += bfhi(u5);
      a0 += bflo(u6); a1 += bfhi(u6);
      b0 += bflo(u7); b1 += bfhi(u7);
    }
    for (; e + 2 <= s1; e += 2) {
      unsigned u0 = xs[(size_t)eidx[e + sub] * rs + sl];
      a0 += bflo(u0); a1 += bfhi(u0);
    }
    if (e < s1 && sub == 0) {
      unsigned u0 = xs[(size_t)eidx[e] * rs + sl];
      a0 += bflo(u0); a1 += bfhi(u0);
    }
    a0 += b0; a1 += b1;
    a0 += __shfl_xor(a0, 32);
    a1 += __shfl_xor(a1, 32);
    if (sub == 0) {
      a0 *= inv; a1 *= inv;
      if (OBF) {
        ((unsigned*)t.out)[(size_t)w * 32 + sl] = f2bf(a0) | (f2bf(a1) << 16);
      } else {
        float2 r; r.x = a0; r.y = a1;
        ((float2*)t.out)[(size_t)w * 32 + sl] = r;
      }
    }
  }
}

// ---------------- fused MFMA dense (up to 3 tasks / dispatch) ----------------

struct SegB { const unsigned short* A; const unsigned short* Wt; int K; };

struct DTask {
  SegB s0, s1, s2; int nseg;
  const float* bias0; const float* bias1; const float* add0; const float* add1;
  float* of32; unsigned short* obf16;
  int M, ldo, relu, nt, blk0;
};
struct DPack { DTask d[3]; int n; };

template <int NTMAX>
__global__ __launch_bounds__(256) void dense_multi(DPack p) {
  __shared__ unsigned short A_s[128 * 128];
  __shared__ unsigned short B_s[NTMAX * 32 * 128];
  int bx = blockIdx.x;
  int ti = 0;
#pragma unroll
  for (int i = 1; i < 3; ++i)
    if (i < p.n && bx >= p.d[i].blk0) ti = i;
  DTask t = p.d[ti];
  int tid = threadIdx.x;
  int lane = tid & 63, wid = tid >> 6;
  int wr = wid >> 1, wc = wid & 1;
  int m0 = (bx - t.blk0) * 128;
  const int nt = t.nt;
  floatx4 acc[4][NTMAX] = {};

  for (int sg = 0; sg < t.nseg; ++sg) {
    SegB s = (sg == 0) ? t.s0 : ((sg == 1) ? t.s1 : t.s2);
    const int K = s.K;
    const int lsh = (K == 128) ? 4 : 3;
    const int slots = 1 << lsh;
    if (sg) __syncthreads();
    for (int c = tid; c < (128 << lsh); c += 256) {
      int row = c >> lsh, sl = c & (slots - 1);
      int gr = m0 + row; if (gr >= t.M) gr = t.M - 1;
      uint4 v = *(const uint4*)(s.A + (size_t)gr * K + sl * 8);
      *(uint4*)((char*)A_s + row * 256 + ((sl * 16) ^ ((row & 7) << 4))) = v;
    }
    for (int c = tid; c < ((nt * 32) << lsh); c += 256) {
      int row = c >> lsh, sl = c & (slots - 1);
      uint4 v = *(const uint4*)(s.Wt + (size_t)row * K + sl * 8);
      *(uint4*)((char*)B_s + row * 256 + ((sl * 16) ^ ((row & 7) << 4))) = v;
    }
    __syncthreads();
    const int nks = K >> 5;
    for (int ks = 0; ks < nks; ++ks) {
      int kb = ks * 64 + ((lane >> 4) << 4);
      short8 a[4], b[NTMAX];
#pragma unroll
      for (int fm = 0; fm < 4; ++fm) {
        int row = wr * 64 + fm * 16 + (lane & 15);
        a[fm] = *(const short8*)((const char*)A_s + row * 256 + (kb ^ ((row & 7) << 4)));
      }
#pragma unroll
      for (int fn = 0; fn < NTMAX; ++fn)
        if (fn < nt) {
          int row = wc * (nt * 16) + fn * 16 + (lane & 15);
          b[fn] = *(const short8*)((const char*)B_s + row * 256 + (kb ^ ((row & 7) << 4)));
        }
#pragma unroll
      for (int fm = 0; fm < 4; ++fm)
#pragma unroll
        for (int fn = 0; fn < NTMAX; ++fn)
          if (fn < nt)
            acc[fm][fn] = __builtin_amdgcn_mfma_f32_16x16x32_bf16(a[fm], b[fn], acc[fm][fn], 0, 0, 0);
    }
  }

  int lr = (lane >> 4) * 4, lc = lane & 15;
#pragma unroll
  for (int fm = 0; fm < 4; ++fm) {
#pragma unroll
    for (int i = 0; i < 4; ++i) {
      int grow = m0 + wr * 64 + fm * 16 + lr + i;
      if (grow >= t.M) continue;
#pragma unroll
      for (int fn = 0; fn < NTMAX; ++fn)
        if (fn < nt) {
          int gcol = wc * (nt * 16) + fn * 16 + lc;
          float v = acc[fm][fn][i];
          if (t.bias0) v += t.bias0[gcol];
          if (t.bias1) v += t.bias1[gcol];
          size_t oidx = (size_t)grow * t.ldo + gcol;
          if (t.add0) v += t.add0[oidx];
          if (t.add1) v += t.add1[oidx];
          if (t.relu) v = fmaxf(v, 0.f);
          if (t.obf16) t.obf16[oidx] = (unsigned short)f2bf(v);
          else t.of32[oidx] = v;
        }
    }
  }
}

// ---------------- launch ----------------

extern "C" void kernel_launch(void* const* d_in, const int* in_sizes, int n_in,
                              void* d_out, int out_size, void* d_ws, size_t ws_size,
                              hipStream_t stream) {
  const float* x_user  = (const float*)d_in[0];
  const float* x_job   = (const float*)d_in[1];
  const float* x_skill = (const float*)d_in[2];

  const float* l1_uj_Wl = (const float*)d_in[3];
  const float* l1_uj_bl = (const float*)d_in[4];
  const float* l1_uj_Wr = (const float*)d_in[5];
  const float* l2_uj_Wl = (const float*)d_in[6];
  const float* l2_uj_bl = (const float*)d_in[7];
  const float* l2_uj_Wr = (const float*)d_in[8];

  const float* l1_ju_Wl = (const float*)d_in[9];
  const float* l1_ju_bl = (const float*)d_in[10];
  const float* l1_ju_Wr = (const float*)d_in[11];
  const float* l2_ju_Wl = (const float*)d_in[12];
  const float* l2_ju_bl = (const float*)d_in[13];
  const float* l2_ju_Wr = (const float*)d_in[14];

  const float* l1_js_Wl = (const float*)d_in[15];
  const float* l1_js_bl = (const float*)d_in[16];
  const float* l1_js_Wr = (const float*)d_in[17];
  const float* l2_js_Wl = (const float*)d_in[18];
  const float* l2_js_bl = (const float*)d_in[19];
  const float* l2_js_Wr = (const float*)d_in[20];

  const float* l1_sj_Wl = (const float*)d_in[21];
  const float* l1_sj_bl = (const float*)d_in[22];
  const float* l1_sj_Wr = (const float*)d_in[23];
  const float* l2_sj_Wl = (const float*)d_in[24];
  const float* l2_sj_bl = (const float*)d_in[25];
  const float* l2_sj_Wr = (const float*)d_in[26];

  const int* e1_src = (const int*)d_in[27];
  const int* e1_dst = (const int*)d_in[28];
  const int* e2_src = (const int*)d_in[29];
  const int* e2_dst = (const int*)d_in[30];
  const int* e3_src = (const int*)d_in[31];
  const int* e3_dst = (const int*)d_in[32];
  const int* e4_src = (const int*)d_in[33];
  const int* e4_dst = (const int*)d_in[34];

  const int N_U = in_sizes[0] / 128;
  const int N_J = in_sizes[1] / 128;
  const int N_S = in_sizes[2] / 64;
  const int E1 = in_sizes[27], E2 = in_sizes[29], E3 = in_sizes[31], E4 = in_sizes[33];
  const int Etot = E1 + E2 + E3 + E4;
  const int b1 = 0, b2 = N_J, b3 = N_J + N_U, b4 = N_J + N_U + N_S;
  const int ntot = b4 + N_J;
  const int n8 = ntot * 8;

  char* wsp = (char*)d_ws;
  size_t off = 0;
  auto alloc = [&](size_t bytes) -> void* {
    void* p = wsp + off;
    off += (bytes + 255) & ~(size_t)255;
    return p;
  };

  int* cnt8       = (int*)alloc((size_t)n8 * 4);           // hist copies; reused as cur copies
  int* starts_all = (int*)alloc((size_t)(n8 + 1) * 4);     // dst-major: starts[dd*8+c]
  unsigned short* eidx_all = (unsigned short*)alloc((size_t)Etot * 2);
  int* bsum = (int*)alloc(1024 * 4);
  int* boff = (int*)alloc(1024 * 4);

  unsigned* xu_bf = (unsigned*)alloc((size_t)N_U * 128 * 2);
  unsigned* xj_bf = (unsigned*)alloc((size_t)N_J * 128 * 2);
  unsigned* xs_bf = (unsigned*)alloc((size_t)N_S * 64 * 2);

  unsigned short* aggA_bf = (unsigned short*)alloc((size_t)N_U * 128 * 2);
  unsigned short* aggB_bf = (unsigned short*)alloc((size_t)N_J * 128 * 2);
  unsigned short* aggC_bf = (unsigned short*)alloc((size_t)N_J * 64 * 2);
  unsigned short* aggD_bf = (unsigned short*)alloc((size_t)N_S * 128 * 2);

  unsigned short* h_u = (unsigned short*)alloc((size_t)N_U * 128 * 2);
  unsigned short* h_j = (unsigned short*)alloc((size_t)N_J * 128 * 2);
  unsigned short* h_s = (unsigned short*)alloc((size_t)N_S * 128 * 2);

  unsigned short* t_uj = (unsigned short*)alloc((size_t)N_U * 64 * 2);
  unsigned short* t_jx = (unsigned short*)alloc((size_t)N_J * 128 * 2);
  unsigned short* t_sj = (unsigned short*)alloc((size_t)N_S * 64 * 2);

  float* aggA_f = (float*)alloc((size_t)N_U * 64 * 4);
  float* aggB_f = (float*)alloc((size_t)N_J * 64 * 4);
  float* aggC_f = (float*)alloc((size_t)N_J * 64 * 4);
  float* aggD_f = (float*)alloc((size_t)N_S * 64 * 4);

  auto walloc = [&](int n, int k) { return (unsigned short*)alloc((size_t)n * k * 2); };
  unsigned short* wt_l1juWl = walloc(128, 128);
  unsigned short* wt_l1juWr = walloc(128, 128);
  unsigned short* wt_l1ujWl = walloc(128, 128);
  unsigned short* wt_l1sjWl = walloc(128, 64);
  unsigned short* wt_wr1sum = walloc(128, 128);
  unsigned short* wt_l1jsWl = walloc(128, 128);
  unsigned short* wt_l1jsWr = walloc(128, 64);
  unsigned short* wt_l2ujWl = walloc(64, 128);
  unsigned short* wt_tjx    = walloc(128, 128);
  unsigned short* wt_l2sjWl = walloc(64, 128);
  unsigned short* wt_l2juWr = walloc(64, 128);
  unsigned short* wt_wr2sum = walloc(64, 128);
  unsigned short* wt_l2jsWr = walloc(64, 128);

  float* o_u = (float*)d_out;
  float* o_j = o_u + (size_t)N_U * 64;
  float* o_s = o_j + (size_t)N_J * 64;

  // ---- CSR build: 8-copy hist -> scan (dst-major view) -> single-pass scatter ----
  const int maxE = 800000;
  const int nsb = (n8 + 1023) / 1024;
  hipMemsetAsync(cnt8, 0, (size_t)n8 * 4, stream);
  hist8_kernel<<<dim3((maxE + 255) / 256, 4), 256, 0, stream>>>(
      e1_dst, e2_dst, e3_dst, e4_dst, E1, E2, E3, E4, b1, b2, b3, b4, ntot, cnt8);
  scanA_kernel<<<nsb, 256, 0, stream>>>(cnt8, ntot, n8, bsum);
  scanB_kernel<<<1, 256, 0, stream>>>(bsum, nsb, boff, starts_all, n8);
  scanC_kernel<<<nsb, 256, 0, stream>>>(cnt8, ntot, n8, boff, starts_all);
  hipMemsetAsync(cnt8, 0, (size_t)n8 * 4, stream);
  scatter8_kernel<<<dim3((maxE + 255) / 256, 4), 256, 0, stream>>>(
      e1_src, e2_src, e3_src, e4_src, e1_dst, e2_dst, e3_dst, e4_dst,
      E1, E2, E3, E4, b1, b2, b3, b4, ntot, starts_all, cnt8, eidx_all);

  // ---- bf16 feature tables + bf16 transposed weights ----
  {
    CTask c0{x_user, xu_bf, N_U * 32};
    CTask c1{x_job, xj_bf, N_J * 32};
    CTask c2{x_skill, xs_bf, N_S * 16};
    int mx = c0.n4 > c1.n4 ? c0.n4 : c1.n4;
    if (c2.n4 > mx) mx = c2.n4;
    tobf16x3_kernel<<<dim3((mx + 255) / 256, 3), 256, 0, stream>>>(c0, c1, c2);
  }

  WPack wp;
  wp.d[0]  = {l1_ju_Wl, nullptr,   wt_l1juWl, 128, 7};
  wp.d[1]  = {l1_ju_Wr, nullptr,   wt_l1juWr, 128, 7};
  wp.d[2]  = {l1_uj_Wl, nullptr,   wt_l1ujWl, 128, 7};
  wp.d[3]  = {l1_sj_Wl, nullptr,   wt_l1sjWl, 64,  7};
  wp.d[4]  = {l1_uj_Wr, l1_sj_Wr,  wt_wr1sum, 128, 7};
  wp.d[5]  = {l1_js_Wl, nullptr,   wt_l1jsWl, 128, 7};
  wp.d[6]  = {l1_js_Wr, nullptr,   wt_l1jsWr, 64,  7};
  wp.d[7]  = {l2_uj_Wl, nullptr,   wt_l2ujWl, 128, 6};
  wp.d[8]  = {l2_ju_Wl, nullptr,   wt_tjx,             128, 6};
  wp.d[9]  = {l2_js_Wl, nullptr,   wt_tjx + 64 * 128,  128, 6};
  wp.d[10] = {l2_sj_Wl, nullptr,   wt_l2sjWl, 128, 6};
  wp.d[11] = {l2_ju_Wr, nullptr,   wt_l2juWr, 128, 6};
  wp.d[12] = {l2_uj_Wr, l2_sj_Wr,  wt_wr2sum, 128, 6};
  wp.d[13] = {l2_js_Wr, nullptr,   wt_l2jsWr, 128, 6};
  wprep_kernel<<<dim3(14, 8), 256, 0, stream>>>(wp);

  auto nb = [](int n) { return (n + 3) / 4; };
  auto mb = [](int n) { return (n + 127) / 128; };

  // ---- layer 1 gathers fused (bf16 in, bf16 out) ----
  {
    GTask g0{xu_bf, 64, starts_all + b1 * 8, N_J, aggB_bf, 1, 0};
    GTask g1{xj_bf, 64, starts_all + b2 * 8, N_U, aggA_bf, 1, g0.blk0 + nb(N_J)};
    GTask g2{xj_bf, 64, starts_all + b3 * 8, N_S, aggD_bf, 1, g1.blk0 + nb(N_U)};
    GTask g3{xs_bf, 32, starts_all + b4 * 8, N_J, aggC_bf, 0, g2.blk0 + nb(N_S)};
    int gtot = g3.blk0 + nb(N_J);
    gather4<1><<<gtot, 256, 0, stream>>>(g0, g1, g2, g3, eidx_all);
  }

  SegB z{nullptr, nullptr, 0};
  auto mkT = [&](SegB a, SegB b, SegB c, int nseg, const float* bi0, const float* bi1,
                 const float* a0, const float* a1, float* of, unsigned short* ob,
                 int M, int ldo, int relu, int nt, int blk0) {
    DTask t;
    t.s0 = a; t.s1 = b; t.s2 = c; t.nseg = nseg;
    t.bias0 = bi0; t.bias1 = bi1; t.add0 = a0; t.add1 = a1;
    t.of32 = of; t.obf16 = ob;
    t.M = M; t.ldo = ldo; t.relu = relu; t.nt = nt; t.blk0 = blk0;
    return t;
  };

  // ---- layer 1 dense (+ReLU), fused 3 tasks, all nt=4 ----
  {
    DPack p; p.n = 3;
    p.d[0] = mkT(SegB{aggA_bf, wt_l1juWl, 128}, SegB{(const unsigned short*)xu_bf, wt_l1juWr, 128}, z, 2,
                 l1_ju_bl, nullptr, nullptr, nullptr, nullptr, h_u, N_U, 128, 1, 4, 0);
    p.d[1] = mkT(SegB{aggB_bf, wt_l1ujWl, 128}, SegB{aggC_bf, wt_l1sjWl, 64},
                 SegB{(const unsigned short*)xj_bf, wt_wr1sum, 128}, 3,
                 l1_uj_bl, l1_sj_bl, nullptr, nullptr, nullptr, h_j, N_J, 128, 1, 4, mb(N_U));
    p.d[2] = mkT(SegB{aggD_bf, wt_l1jsWl, 128}, SegB{(const unsigned short*)xs_bf, wt_l1jsWr, 64}, z, 2,
                 l1_js_bl, nullptr, nullptr, nullptr, nullptr, h_s, N_S, 128, 1, 4, mb(N_U) + mb(N_J));
    dense_multi<4><<<mb(N_U) + mb(N_J) + mb(N_S), 256, 0, stream>>>(p);
  }

  // ---- layer 2 transforms, fused 3 tasks (nt 2/4/2) ----
  {
    DPack p; p.n = 3;
    p.d[0] = mkT(SegB{h_u, wt_l2ujWl, 128}, z, z, 1,
                 nullptr, nullptr, nullptr, nullptr, nullptr, t_uj, N_U, 64, 0, 2, 0);
    p.d[1] = mkT(SegB{h_j, wt_tjx, 128}, z, z, 1,
                 nullptr, nullptr, nullptr, nullptr, nullptr, t_jx, N_J, 128, 0, 4, mb(N_U));
    p.d[2] = mkT(SegB{h_s, wt_l2sjWl, 128}, z, z, 1,
                 nullptr, nullptr, nullptr, nullptr, nullptr, t_sj, N_S, 64, 0, 2, mb(N_U) + mb(N_J));
    dense_multi<4><<<mb(N_U) + mb(N_J) + mb(N_S), 256, 0, stream>>>(p);
  }

  // ---- layer 2 gathers fused (bf16 in, fp32 out), all width-64 ----
  {
    GTask g0{(const unsigned*)t_uj, 32, starts_all + b1 * 8, N_J, aggB_f, 0, 0};
    GTask g1{(const unsigned*)t_jx, 64, starts_all + b2 * 8, N_U, aggA_f, 0, g0.blk0 + nb(N_J)};
    GTask g2{(const unsigned*)t_jx + 32, 64, starts_all + b3 * 8, N_S, aggD_f, 0, g1.blk0 + nb(N_U)};
    GTask g3{(const unsigned*)t_sj, 32, starts_all + b4 * 8, N_J, aggC_f, 0, g2.blk0 + nb(N_S)};
    int gtot = g3.blk0 + nb(N_J);
    gather4<0><<<gtot, 256, 0, stream>>>(g0, g1, g2, g3, eidx_all);
  }

  // ---- layer 2 final dense (fp32 out to d_out), fused 3 tasks, all nt=2 ----
  {
    DPack p; p.n = 3;
    p.d[0] = mkT(SegB{h_u, wt_l2juWr, 128}, z, z, 1,
                 l2_ju_bl, nullptr, aggA_f, nullptr, o_u, nullptr, N_U, 64, 0, 2, 0);
    p.d[1] = mkT(SegB{h_j, wt_wr2sum, 128}, z, z, 1,
                 l2_uj_bl, l2_sj_bl, aggB_f, aggC_f, o_j, nullptr, N_J, 64, 0, 2, mb(N_U));
    p.d[2] = mkT(SegB{h_s, wt_l2jsWr, 128}, z, z, 1,
                 l2_js_bl, nullptr, aggD_f, nullptr, o_s, nullptr, N_S, 64, 0, 2, mb(N_U) + mb(N_J));
    dense_multi<2><<<mb(N_U) + mb(N_J) + mb(N_S), 256, 0, stream>>>(p);
  }
}